// Round 1
// 1565.091 us; speedup vs baseline: 1.1307x; 1.1307x over previous
//
#include <hip/hip_runtime.h>
#include <math.h>

#define HID 128

typedef __attribute__((ext_vector_type(8))) short short8;
typedef __attribute__((ext_vector_type(4))) float f32x4;
typedef __attribute__((ext_vector_type(2))) float f32x2;

__device__ __forceinline__ float bf2f(unsigned int u16) {
  union { unsigned int i; float f; } x; x.i = u16 << 16; return x.f;
}
__device__ __forceinline__ unsigned short f2bf(float f) {
  union { float f; unsigned int i; } x; x.f = f;
  unsigned int i = x.i;
  unsigned int r = i + 0x7FFFu + ((i >> 16) & 1u);
  return (unsigned short)(r >> 16);
}

// ---- fp8 e4m3 (OCP) helpers -------------------------------------------------
__device__ __forceinline__ unsigned char f2fp8_sw(float f) {
  union { float f; unsigned int u; } v; v.f = f;
  unsigned int s = (v.u >> 24) & 0x80u;
  v.u &= 0x7FFFFFFFu;
  if (v.f != v.f) return (unsigned char)(s | 0x7Fu);
  if (v.f >= 464.f) return (unsigned char)(s | 0x7Eu);          // saturate 448
  if (v.f < 0.0009765625f) return (unsigned char)s;             // < 2^-10 -> 0
  int ebits = (int)(v.u >> 23);
  if (ebits >= 121) {                                           // normal (exp >= -6)
    unsigned int r = v.u + 0x7FFFFu + ((v.u >> 20) & 1u);       // RNE at bit 20
    int E = (int)(r >> 23) - 127 + 7;
    unsigned int m = (r >> 20) & 7u;
    if (E >= 16) return (unsigned char)(s | 0x7Eu);
    return (unsigned char)(s | ((unsigned int)E << 3) | m);
  } else {                                                      // subnormal
    int M = (int)rintf(v.f * 512.f);
    if (M > 8) M = 8;
    return (unsigned char)(s | (unsigned int)M);
  }
}

__device__ __forceinline__ unsigned int pack4_fp8(float a, float b, float c, float d) {
#if __has_builtin(__builtin_amdgcn_cvt_pk_fp8_f32)
  int w = 0;
  w = __builtin_amdgcn_cvt_pk_fp8_f32(a, b, w, false);
  w = __builtin_amdgcn_cvt_pk_fp8_f32(c, d, w, true);
  return (unsigned int)w;
#else
  return (unsigned int)f2fp8_sw(a) | ((unsigned int)f2fp8_sw(b) << 8)
       | ((unsigned int)f2fp8_sw(c) << 16) | ((unsigned int)f2fp8_sw(d) << 24);
#endif
}

#if !__has_builtin(__builtin_amdgcn_cvt_pk_f32_fp8)
__device__ __forceinline__ float dec1_fp8(unsigned int u) {
  unsigned int s = (u & 0x80u) << 24;
  unsigned int em = u & 0x7Fu;
  union { unsigned int i; float f; } t;
  t.i = s | ((em << 20) + 0x3C000000u);
  float sub = (float)(int)(u & 7u) * ((u & 0x80u) ? -0.001953125f : 0.001953125f);
  return (em >= 8u) ? t.f : sub;
}
#endif

__device__ __forceinline__ void dec8_fp8(uint2 w, float* o) {
#if __has_builtin(__builtin_amdgcn_cvt_pk_f32_fp8)
  f32x2 p;
  p = __builtin_amdgcn_cvt_pk_f32_fp8((int)w.x, false); o[0] = p.x; o[1] = p.y;
  p = __builtin_amdgcn_cvt_pk_f32_fp8((int)w.x, true);  o[2] = p.x; o[3] = p.y;
  p = __builtin_amdgcn_cvt_pk_f32_fp8((int)w.y, false); o[4] = p.x; o[5] = p.y;
  p = __builtin_amdgcn_cvt_pk_f32_fp8((int)w.y, true);  o[6] = p.x; o[7] = p.y;
#else
  o[0] = dec1_fp8(w.x & 0xFFu);        o[1] = dec1_fp8((w.x >> 8) & 0xFFu);
  o[2] = dec1_fp8((w.x >> 16) & 0xFFu); o[3] = dec1_fp8(w.x >> 24);
  o[4] = dec1_fp8(w.y & 0xFFu);        o[5] = dec1_fp8((w.y >> 8) & 0xFFu);
  o[6] = dec1_fp8((w.y >> 16) & 0xFFu); o[7] = dec1_fp8(w.y >> 24);
#endif
}

// k-major panel layout for MFMA A/B sides:
//   panel p = row>>7 (128 rows), chunk J = k>>3 (8 elems), slot = J*128 + (row&127)
//   elem addr = p*16384 + slot*8 + (k&7)

// ---------------- weight convert: k-major panels + biascat ----------------
__global__ __launch_bounds__(128) void wcvt_kernel(
    const float* __restrict__ Wq, const float* __restrict__ bq,
    const float* __restrict__ Wk, const float* __restrict__ bk,
    const float* __restrict__ Wv, const float* __restrict__ bv,
    const float* __restrict__ Ws, const float* __restrict__ bs,
    unsigned short* __restrict__ BT, float* __restrict__ biascat)
{
  int id = blockIdx.x;
  int l = id / 1664;
  int n = id - l * 1664;
  int k = threadIdx.x;
  const float* W; const float* bias; int nl, ldb;
  if (n < 512)       { W = Wq + (size_t)l * 65536; bias = bq + (size_t)l * 512; nl = n;        ldb = 512; }
  else if (n < 1024) { W = Wk + (size_t)l * 65536; bias = bk + (size_t)l * 512; nl = n - 512;  ldb = 512; }
  else if (n < 1536) { W = Wv + (size_t)l * 65536; bias = bv + (size_t)l * 512; nl = n - 1024; ldb = 512; }
  else               { W = Ws + (size_t)l * 16384; bias = bs + (size_t)l * 128; nl = n - 1536; ldb = 128; }
  size_t dst = (size_t)l * 212992 + (size_t)(n >> 7) * 16384
             + (size_t)((k >> 3) * 128 + (n & 127)) * 8 + (k & 7);
  BT[dst] = f2bf(W[(size_t)k * ldb + nl]);
  if (k == 0) biascat[(size_t)l * 1664 + n] = bias[nl];
}

// ---------------- lin0: h = x @ W(70x128) + b (fp32 + k-major bf16) ----------
__global__ __launch_bounds__(128) void lin0_kernel(
    const float* __restrict__ x, const float* __restrict__ W,
    const float* __restrict__ b, float* __restrict__ h,
    unsigned short* __restrict__ hb, int N, int inF)
{
  __shared__ float xs[128];
  int n = blockIdx.x;
  int t = threadIdx.x;
  if (t < inF) xs[t] = x[(size_t)n * inF + t];
  __syncthreads();
  float acc = b[t];
  for (int k = 0; k < inF; k++) acc += xs[k] * W[(size_t)k * 128 + t];
  h[(size_t)n * 128 + t] = acc;
  hb[(size_t)(n >> 7) * 16384 + (size_t)((t >> 3) * 128 + (n & 127)) * 8 + (t & 7)] = f2bf(acc);
}

// ---------------- MFMA projection GEMM ----------------
// grid (ceil(M/128), 13); block 256 = 4 waves; per-wave 64x64 via 4x4 16x16 tiles.
// Outputs: q -> bf16 [N,512]; k -> fp8 e4m3 into kv row bytes [0,512);
//          v -> bf16 into kv row bytes [512,1536); skip -> fp32 hn.
__global__ __launch_bounds__(256) void proj_mfma_kernel(
    const unsigned short* __restrict__ A, const unsigned short* __restrict__ BT,
    const float* __restrict__ bias, int M,
    unsigned short* __restrict__ qo, unsigned char* __restrict__ kv,
    float* __restrict__ hn)
{
  __shared__ unsigned short lsA[4096];
  __shared__ unsigned short lsB[4096];
  const int t = threadIdx.x;
  const int wv = t >> 6, ln = t & 63;
  const int wx = wv & 1, wy = wv >> 1;
  const int m0 = blockIdx.x * 128;
  const int nc = blockIdx.y;
  const int fr = ln & 15, quad = ln >> 4;

  const unsigned short* Ap = A + (size_t)blockIdx.x * 16384;
  const unsigned short* Bp = BT + (size_t)nc * 16384;

  f32x4 acc[4][4];
#pragma unroll
  for (int i = 0; i < 4; i++)
#pragma unroll
    for (int j = 0; j < 4; j++) acc[i][j] = (f32x4){0.f, 0.f, 0.f, 0.f};

  for (int kb = 0; kb < 4; kb++) {
    __syncthreads();                          // protect prev iter's ds_reads
#pragma unroll
    for (int it = 0; it < 2; it++) {
      const int c = it * 256 + t;             // 16-B chunk id, linear
      __builtin_amdgcn_global_load_lds(
          (const __attribute__((address_space(1))) void*)(Ap + (size_t)kb * 4096 + c * 8),
          (__attribute__((address_space(3))) void*)((char*)lsA + c * 16), 16, 0, 0);
      __builtin_amdgcn_global_load_lds(
          (const __attribute__((address_space(1))) void*)(Bp + (size_t)kb * 4096 + c * 8),
          (__attribute__((address_space(3))) void*)((char*)lsB + c * 16), 16, 0, 0);
    }
    __syncthreads();

    short8 af[4], bf[4];
#pragma unroll
    for (int i = 0; i < 4; i++)
      af[i] = *(const short8*)(&lsA[(size_t)(quad * 128 + wy * 64 + i * 16 + fr) * 8]);
#pragma unroll
    for (int j = 0; j < 4; j++)
      bf[j] = *(const short8*)(&lsB[(size_t)(quad * 128 + wx * 64 + j * 16 + fr) * 8]);
#pragma unroll
    for (int i = 0; i < 4; i++)
#pragma unroll
      for (int j = 0; j < 4; j++)
        acc[i][j] = __builtin_amdgcn_mfma_f32_16x16x32_bf16(bf[j], af[i], acc[i][j], 0, 0, 0);
  }

  // epilogue: lane holds rows m0+wy*64+i*16+fr, cols nc*128+wx*64+j*16+quad*4+(0..3)
  const int region = nc >> 2;                 // 0=q 1=k 2=v 3=skip
#pragma unroll
  for (int j = 0; j < 4; j++) {
    const int colb = nc * 128 + wx * 64 + j * 16 + quad * 4;
    const float4 b4 = *(const float4*)(&bias[colb]);
    const int col = colb - region * 512;
#pragma unroll
    for (int i = 0; i < 4; i++) {
      const int row = m0 + wy * 64 + i * 16 + fr;
      if (row < M) {
        f32x4 c = acc[i][j];
        float v0 = c[0] + b4.x, v1 = c[1] + b4.y, v2 = c[2] + b4.z, v3 = c[3] + b4.w;
        if (region == 0) {
          uint2 pk;
          pk.x = (unsigned int)f2bf(v0) | ((unsigned int)f2bf(v1) << 16);
          pk.y = (unsigned int)f2bf(v2) | ((unsigned int)f2bf(v3) << 16);
          *(uint2*)(qo + (size_t)row * 512 + col) = pk;
        } else if (region == 1) {
          *(unsigned int*)(kv + (size_t)row * 1536 + col) = pack4_fp8(v0, v1, v2, v3);
        } else if (region == 2) {
          uint2 pk;
          pk.x = (unsigned int)f2bf(v0) | ((unsigned int)f2bf(v1) << 16);
          pk.y = (unsigned int)f2bf(v2) | ((unsigned int)f2bf(v3) << 16);
          *(uint2*)(kv + (size_t)row * 1536 + 512 + (size_t)col * 2) = pk;
        } else {
          *(float4*)(hn + (size_t)row * 128 + col) = make_float4(v0, v1, v2, v3);
        }
      }
    }
  }
}

// ---------------- CSR build ----------------
__global__ __launch_bounds__(256) void hist_kernel(
    const int* __restrict__ dst, int* __restrict__ deg, int E)
{
  int e = blockIdx.x * 256 + threadIdx.x;
  if (e < E) atomicAdd(&deg[dst[e]], 1);
}

__global__ __launch_bounds__(256) void scan_block_kernel(
    const int* __restrict__ in, int* __restrict__ out, int* __restrict__ bsums, int N)
{
  __shared__ int sm[256];
  int i = blockIdx.x * 256 + threadIdx.x;
  int v = (i < N) ? in[i] : 0;
  sm[threadIdx.x] = v; __syncthreads();
  for (int off = 1; off < 256; off <<= 1) {
    int t = (threadIdx.x >= off) ? sm[threadIdx.x - off] : 0;
    __syncthreads();
    sm[threadIdx.x] += t;
    __syncthreads();
  }
  if (i < N) out[i] = sm[threadIdx.x] - v;   // exclusive
  if (threadIdx.x == 255 && bsums) bsums[blockIdx.x] = sm[255];
}

__global__ __launch_bounds__(256) void scan_finish_kernel(
    int* __restrict__ row_start, int* __restrict__ cursor,
    const int* __restrict__ bsums_scan, int N, int E)
{
  int i = blockIdx.x * 256 + threadIdx.x;
  if (i < N) {
    int val = row_start[i] + bsums_scan[blockIdx.x];
    row_start[i] = val;
    cursor[i] = val;
  }
  if (i == 0) row_start[N] = E;
}

__global__ __launch_bounds__(256) void scatter_kernel(
    const int* __restrict__ src, const int* __restrict__ dst,
    int* __restrict__ cursor, int* __restrict__ csr_src, int E)
{
  int e = blockIdx.x * 256 + threadIdx.x;
  if (e < E) {
    int pos = atomicAdd(&cursor[dst[e]], 1);
    csr_src[pos] = src[e];
  }
}

// ---------------- fused per-node attention (one wave per dst node) ----------
// h[d] = relu(h[d] + mean_h(softmax_e * v[src_e,h,:]));  hb = bf16 k-major panel
// kv row: [512 B fp8 k][1024 B bf16 v]; per edge gathers 1.5 KB contiguous.
// Depth-3 software pipeline over edges (6 gathers in flight).
__global__ __launch_bounds__(256) void node_attn_kernel(
    const unsigned short* __restrict__ q, const unsigned char* __restrict__ kv,
    const int* __restrict__ row_start, const int* __restrict__ csr_src,
    float* __restrict__ hn, unsigned short* __restrict__ hb, int N)
{
  int d = (blockIdx.x * 256 + threadIdx.x) >> 6;
  int lane = threadIdx.x & 63;
  if (d >= N) return;
  int beg = row_start[d], end = row_start[d + 1];

  const float scale = 0.08838834764831845f;  // 1/sqrt(128), folded into q
  const uint4 qv = *(const uint4*)(q + (size_t)d * 512 + lane * 8);
  float q0 = bf2f(qv.x & 0xFFFFu) * scale, q1 = bf2f(qv.x >> 16) * scale;
  float q2 = bf2f(qv.y & 0xFFFFu) * scale, q3 = bf2f(qv.y >> 16) * scale;
  float q4 = bf2f(qv.z & 0xFFFFu) * scale, q5 = bf2f(qv.z >> 16) * scale;
  float q6 = bf2f(qv.w & 0xFFFFu) * scale, q7 = bf2f(qv.w >> 16) * scale;

  float num[8] = {0.f,0.f,0.f,0.f,0.f,0.f,0.f,0.f};
  float den = 0.f;

  auto krow = [&](int s) { return *(const uint2*)(kv + (size_t)s * 1536 + lane * 8); };
  auto vrow = [&](int s) { return *(const uint4*)(kv + (size_t)s * 1536 + 512 + lane * 16); };
  auto accum = [&](const uint2& kw, const uint4& vv) {
    float kd[8];
    dec8_fp8(kw, kd);
    float p = q0 * kd[0] + q1 * kd[1] + q2 * kd[2] + q3 * kd[3]
            + q4 * kd[4] + q5 * kd[5] + q6 * kd[6] + q7 * kd[7];
    p += __shfl_xor(p, 1);
    p += __shfl_xor(p, 2);
    p += __shfl_xor(p, 4);
    p += __shfl_xor(p, 8);
    float e = __expf(p);
    den += e;
    num[0] += e * bf2f(vv.x & 0xFFFFu); num[1] += e * bf2f(vv.x >> 16);
    num[2] += e * bf2f(vv.y & 0xFFFFu); num[3] += e * bf2f(vv.y >> 16);
    num[4] += e * bf2f(vv.z & 0xFFFFu); num[5] += e * bf2f(vv.z >> 16);
    num[6] += e * bf2f(vv.w & 0xFFFFu); num[7] += e * bf2f(vv.w >> 16);
  };

  if (beg < end) {
    const int last = end - 1;
    int s0 = csr_src[beg];
    int s1 = csr_src[min(beg + 1, last)];
    int s2 = csr_src[min(beg + 2, last)];
    uint2 k0 = krow(s0); uint4 v0 = vrow(s0);
    uint2 k1 = krow(s1); uint4 v1 = vrow(s1);
    uint2 k2 = krow(s2); uint4 v2 = vrow(s2);
    for (int i = beg; i < end; i += 3) {
      int t0 = csr_src[min(i + 3, last)];
      int t1 = csr_src[min(i + 4, last)];
      int t2 = csr_src[min(i + 5, last)];
      uint2 ka = krow(t0); uint4 va = vrow(t0);
      uint2 kb = krow(t1); uint4 vb = vrow(t1);
      uint2 kc = krow(t2); uint4 vc = vrow(t2);
      accum(k0, v0);
      if (i + 1 < end) accum(k1, v1);
      if (i + 2 < end) accum(k2, v2);
      k0 = ka; v0 = va; k1 = kb; v1 = vb; k2 = kc; v2 = vc;
    }
  }

  float inv = (den > 0.f) ? 0.25f / den : 0.f;
#pragma unroll
  for (int j = 0; j < 8; j++) {
    float r = num[j] * inv;
    r += __shfl_xor(r, 16);   // combine 4 heads
    r += __shfl_xor(r, 32);
    num[j] = r;
  }
  if (lane < 16) {
    float* hp = hn + (size_t)d * 128 + lane * 8;
    float4 o0 = *(const float4*)(hp);
    float4 o1 = *(const float4*)(hp + 4);
    o0.x = fmaxf(o0.x + num[0], 0.f);
    o0.y = fmaxf(o0.y + num[1], 0.f);
    o0.z = fmaxf(o0.z + num[2], 0.f);
    o0.w = fmaxf(o0.w + num[3], 0.f);
    o1.x = fmaxf(o1.x + num[4], 0.f);
    o1.y = fmaxf(o1.y + num[5], 0.f);
    o1.z = fmaxf(o1.z + num[6], 0.f);
    o1.w = fmaxf(o1.w + num[7], 0.f);
    *(float4*)(hp) = o0;
    *(float4*)(hp + 4) = o1;
    uint4 hv;
    hv.x = (unsigned int)f2bf(o0.x) | ((unsigned int)f2bf(o0.y) << 16);
    hv.y = (unsigned int)f2bf(o0.z) | ((unsigned int)f2bf(o0.w) << 16);
    hv.z = (unsigned int)f2bf(o1.x) | ((unsigned int)f2bf(o1.y) << 16);
    hv.w = (unsigned int)f2bf(o1.z) | ((unsigned int)f2bf(o1.w) << 16);
    // k-major panel: chunk J = lane, row = d
    *(uint4*)(hb + (size_t)(d >> 7) * 16384 + (size_t)(lane * 128 + (d & 127)) * 8) = hv;
  }
}

// ---------------- pooling: emb[batch[n]] += h[n] (batch sorted) ----------------
__global__ __launch_bounds__(128) void pool_kernel(
    const float* __restrict__ h, const int* __restrict__ batch,
    float* __restrict__ emb, int N)
{
  int d = threadIdx.x;
  int n0 = blockIdx.x * 128;
  int n1 = min(n0 + 128, N);
  float acc = 0.f; int cur = -1;
  for (int n = n0; n < n1; n++) {
    int g = batch[n];
    if (g != cur) {
      if (cur >= 0) atomicAdd(&emb[(size_t)cur * 128 + d], acc);
      cur = g; acc = 0.f;
    }
    acc += h[(size_t)n * 128 + d];
  }
  if (cur >= 0) atomicAdd(&emb[(size_t)cur * 128 + d], acc);
}

// ---------------- final score ----------------
__global__ __launch_bounds__(128) void score_kernel(
    const float* __restrict__ hemb, const float* __restrict__ temb,
    const int* __restrict__ rels,
    const float* __restrict__ wqW, const float* __restrict__ wqb,
    const float* __restrict__ wkW, const float* __restrict__ wkb,
    const float* __restrict__ rel_emb, float* __restrict__ out)
{
  const int b = blockIdx.x, i = threadIdx.x;
  __shared__ float hs[128], ts[128], hnv[128], tnv[128], red[128];
  hs[i] = hemb[(size_t)b * 128 + i];
  ts[i] = temb[(size_t)b * 128 + i];
  __syncthreads();
  float qv = wqb[i], kv = wkb[i];
  for (int k = 0; k < 128; k++) {
    qv += hs[k] * wqW[k * 128 + i];
    kv += ts[k] * wkW[k * 128 + i];
  }
  float inter = tanhf(qv * kv);
  float hx = hs[i] + inter, tx2 = ts[i] + inter;

  red[i] = hx * hx; __syncthreads();
  for (int s = 64; s > 0; s >>= 1) { if (i < s) red[i] += red[i + s]; __syncthreads(); }
  float hnorm = fmaxf(sqrtf(red[0]), 1e-12f);
  __syncthreads();
  red[i] = tx2 * tx2; __syncthreads();
  for (int s = 64; s > 0; s >>= 1) { if (i < s) red[i] += red[i + s]; __syncthreads(); }
  float tnorm = fmaxf(sqrtf(red[0]), 1e-12f);
  __syncthreads();
  hnv[i] = hx / hnorm; tnv[i] = tx2 / tnorm;
  __syncthreads();

  const float* R = rel_emb + (size_t)rels[b] * 16384 + (size_t)i * 128;
  float dot = 0.f, nrm = 0.f;
  for (int j = 0; j < 128; j++) { float r = R[j]; dot += r * tnv[j]; nrm += r * r; }
  float contrib = hnv[i] * dot / fmaxf(sqrtf(nrm), 1e-12f);
  red[i] = contrib; __syncthreads();
  for (int s = 64; s > 0; s >>= 1) { if (i < s) red[i] += red[i + s]; __syncthreads(); }
  if (i == 0) out[b] = red[0];
}

extern "C" void kernel_launch(void* const* d_in, const int* in_sizes, int n_in,
                              void* d_out, int out_size, void* d_ws, size_t ws_size,
                              hipStream_t stream)
{
  const float* h_x     = (const float*)d_in[0];
  const int*   h_ei    = (const int*)d_in[1];
  const int*   h_batch = (const int*)d_in[2];
  const float* t_x     = (const float*)d_in[3];
  const int*   t_ei    = (const int*)d_in[4];
  const int*   t_batch = (const int*)d_in[5];
  const int*   rels    = (const int*)d_in[6];
  const float* lin0_W  = (const float*)d_in[7];
  const float* lin0_b  = (const float*)d_in[8];
  const float* Wq      = (const float*)d_in[9];
  const float* bq      = (const float*)d_in[10];
  const float* Wk      = (const float*)d_in[11];
  const float* bk      = (const float*)d_in[12];
  const float* Wv      = (const float*)d_in[13];
  const float* bv      = (const float*)d_in[14];
  const float* Ws      = (const float*)d_in[15];
  const float* bs      = (const float*)d_in[16];
  const float* wqW     = (const float*)d_in[17];
  const float* wqb     = (const float*)d_in[18];
  const float* wkW     = (const float*)d_in[19];
  const float* wkb     = (const float*)d_in[20];
  const float* rel_emb = (const float*)d_in[21];

  const int N = in_sizes[2];          // 50000
  const int E = in_sizes[1] / 2;      // 400000
  const int G = in_sizes[6];          // 512
  const int inF = in_sizes[7] / 128;  // 70
  const int nPanels = (N + 127) / 128;

  char* ws = (char*)d_ws;
  size_t off = 0;
  auto alloc = [&](size_t bytes) -> void* {
    void* p = ws + off; off += (bytes + 255) & ~(size_t)255; return p;
  };
  float* hA            = (float*)alloc((size_t)N * 128 * 4);
  unsigned short* hbuf = (unsigned short*)alloc((size_t)nPanels * 16384 * 2);
  unsigned short* qb   = (unsigned short*)alloc((size_t)N * 512 * 2);
  unsigned char* kvbuf = (unsigned char*)alloc((size_t)N * 1536);
  unsigned short* BT   = (unsigned short*)alloc((size_t)3 * 212992 * 2);
  float* biascat       = (float*)alloc((size_t)3 * 1664 * 4);
  int* deg             = (int*)alloc((size_t)(N + 1) * 4);
  int* row_start       = (int*)alloc((size_t)(N + 1) * 4);
  int* cursor          = (int*)alloc((size_t)(N + 1) * 4);
  int* bsums           = (int*)alloc((size_t)1024 * 4);
  int* bsums_scan      = (int*)alloc((size_t)1024 * 4);
  int* csr_src         = (int*)alloc((size_t)E * 4);
  float* hEmb          = (float*)alloc((size_t)G * 128 * 4);
  float* tEmb          = (float*)alloc((size_t)G * 128 * 4);
  (void)ws_size; (void)n_in; (void)out_size;

  const int nScanBlocks = (N + 255) / 256;

  // Convert weights once per call (shared by both graphs)
  wcvt_kernel<<<3 * 1664, 128, 0, stream>>>(Wq, bq, Wk, bk, Wv, bv, Ws, bs, BT, biascat);

  for (int g = 0; g < 2; g++) {
    const float* x     = g ? t_x : h_x;
    const int*   ei    = g ? t_ei : h_ei;
    const int*   batch = g ? t_batch : h_batch;
    float*       emb   = g ? tEmb : hEmb;
    const int* srcp = ei;
    const int* dstp = ei + E;

    // --- build CSR (edges grouped by dst) ---
    hipMemsetAsync(deg, 0, (size_t)(N + 1) * 4, stream);
    hist_kernel<<<(E + 255) / 256, 256, 0, stream>>>(dstp, deg, E);
    scan_block_kernel<<<nScanBlocks, 256, 0, stream>>>(deg, row_start, bsums, N);
    scan_block_kernel<<<1, 256, 0, stream>>>(bsums, bsums_scan, nullptr, nScanBlocks);
    scan_finish_kernel<<<nScanBlocks, 256, 0, stream>>>(row_start, cursor, bsums_scan, N, E);
    scatter_kernel<<<(E + 255) / 256, 256, 0, stream>>>(srcp, dstp, cursor, csr_src, E);

    lin0_kernel<<<N, 128, 0, stream>>>(x, lin0_W, lin0_b, hA, hbuf, N, inF);
    for (int l = 0; l < 3; l++) {
      dim3 pg(nPanels, 13);
      proj_mfma_kernel<<<pg, 256, 0, stream>>>(hbuf,
          BT + (size_t)l * 212992, biascat + (size_t)l * 1664, N,
          qb, kvbuf, hA);
      node_attn_kernel<<<(N + 3) / 4, 256, 0, stream>>>(qb, kvbuf,
          row_start, csr_src, hA, hbuf, N);
    }
    hipMemsetAsync(emb, 0, (size_t)G * 128 * 4, stream);
    pool_kernel<<<(N + 127) / 128, 128, 0, stream>>>(hA, batch, emb, N);
  }

  score_kernel<<<G, 128, 0, stream>>>(hEmb, tEmb, rels, wqW, wqb, wkW, wkb,
                                      rel_emb, (float*)d_out);
}

// Round 2
// 1301.148 us; speedup vs baseline: 1.3601x; 1.2029x over previous
//
#include <hip/hip_runtime.h>
#include <math.h>

#define HID 128

typedef __attribute__((ext_vector_type(8))) short short8;
typedef __attribute__((ext_vector_type(4))) float f32x4;
typedef __attribute__((ext_vector_type(2))) float f32x2;

__device__ __forceinline__ float bf2f(unsigned int u16) {
  union { unsigned int i; float f; } x; x.i = u16 << 16; return x.f;
}
__device__ __forceinline__ unsigned short f2bf(float f) {
  union { float f; unsigned int i; } x; x.f = f;
  unsigned int i = x.i;
  unsigned int r = i + 0x7FFFu + ((i >> 16) & 1u);
  return (unsigned short)(r >> 16);
}

// ---- fp8 e4m3 (OCP) helpers -------------------------------------------------
__device__ __forceinline__ unsigned char f2fp8_sw(float f) {
  union { float f; unsigned int u; } v; v.f = f;
  unsigned int s = (v.u >> 24) & 0x80u;
  v.u &= 0x7FFFFFFFu;
  if (v.f != v.f) return (unsigned char)(s | 0x7Fu);
  if (v.f >= 464.f) return (unsigned char)(s | 0x7Eu);          // saturate 448
  if (v.f < 0.0009765625f) return (unsigned char)s;             // < 2^-10 -> 0
  int ebits = (int)(v.u >> 23);
  if (ebits >= 121) {                                           // normal (exp >= -6)
    unsigned int r = v.u + 0x7FFFFu + ((v.u >> 20) & 1u);       // RNE at bit 20
    int E = (int)(r >> 23) - 127 + 7;
    unsigned int m = (r >> 20) & 7u;
    if (E >= 16) return (unsigned char)(s | 0x7Eu);
    return (unsigned char)(s | ((unsigned int)E << 3) | m);
  } else {                                                      // subnormal
    int M = (int)rintf(v.f * 512.f);
    if (M > 8) M = 8;
    return (unsigned char)(s | (unsigned int)M);
  }
}

__device__ __forceinline__ unsigned int pack4_fp8(float a, float b, float c, float d) {
#if __has_builtin(__builtin_amdgcn_cvt_pk_fp8_f32)
  int w = 0;
  w = __builtin_amdgcn_cvt_pk_fp8_f32(a, b, w, false);
  w = __builtin_amdgcn_cvt_pk_fp8_f32(c, d, w, true);
  return (unsigned int)w;
#else
  return (unsigned int)f2fp8_sw(a) | ((unsigned int)f2fp8_sw(b) << 8)
       | ((unsigned int)f2fp8_sw(c) << 16) | ((unsigned int)f2fp8_sw(d) << 24);
#endif
}

#if !__has_builtin(__builtin_amdgcn_cvt_pk_f32_fp8)
__device__ __forceinline__ float dec1_fp8(unsigned int u) {
  unsigned int s = (u & 0x80u) << 24;
  unsigned int em = u & 0x7Fu;
  union { unsigned int i; float f; } t;
  t.i = s | ((em << 20) + 0x3C000000u);
  float sub = (float)(int)(u & 7u) * ((u & 0x80u) ? -0.001953125f : 0.001953125f);
  return (em >= 8u) ? t.f : sub;
}
#endif

__device__ __forceinline__ void dec8_fp8(uint2 w, float* o) {
#if __has_builtin(__builtin_amdgcn_cvt_pk_f32_fp8)
  f32x2 p;
  p = __builtin_amdgcn_cvt_pk_f32_fp8((int)w.x, false); o[0] = p.x; o[1] = p.y;
  p = __builtin_amdgcn_cvt_pk_f32_fp8((int)w.x, true);  o[2] = p.x; o[3] = p.y;
  p = __builtin_amdgcn_cvt_pk_f32_fp8((int)w.y, false); o[4] = p.x; o[5] = p.y;
  p = __builtin_amdgcn_cvt_pk_f32_fp8((int)w.y, true);  o[6] = p.x; o[7] = p.y;
#else
  o[0] = dec1_fp8(w.x & 0xFFu);        o[1] = dec1_fp8((w.x >> 8) & 0xFFu);
  o[2] = dec1_fp8((w.x >> 16) & 0xFFu); o[3] = dec1_fp8(w.x >> 24);
  o[4] = dec1_fp8(w.y & 0xFFu);        o[5] = dec1_fp8((w.y >> 8) & 0xFFu);
  o[6] = dec1_fp8((w.y >> 16) & 0xFFu); o[7] = dec1_fp8(w.y >> 24);
#endif
}

// k-major panel layout for MFMA A/B sides:
//   panel p = row>>7 (128 rows), chunk J = k>>3 (8 elems), slot = J*128 + (row&127)
//   elem addr = p*16384 + slot*8 + (k&7)

// ---------------- weight convert: k-major panels + biascat ----------------
__global__ __launch_bounds__(128) void wcvt_kernel(
    const float* __restrict__ Wq, const float* __restrict__ bq,
    const float* __restrict__ Wk, const float* __restrict__ bk,
    const float* __restrict__ Wv, const float* __restrict__ bv,
    const float* __restrict__ Ws, const float* __restrict__ bs,
    unsigned short* __restrict__ BT, float* __restrict__ biascat)
{
  int id = blockIdx.x;
  int l = id / 1664;
  int n = id - l * 1664;
  int k = threadIdx.x;
  const float* W; const float* bias; int nl, ldb;
  if (n < 512)       { W = Wq + (size_t)l * 65536; bias = bq + (size_t)l * 512; nl = n;        ldb = 512; }
  else if (n < 1024) { W = Wk + (size_t)l * 65536; bias = bk + (size_t)l * 512; nl = n - 512;  ldb = 512; }
  else if (n < 1536) { W = Wv + (size_t)l * 65536; bias = bv + (size_t)l * 512; nl = n - 1024; ldb = 512; }
  else               { W = Ws + (size_t)l * 16384; bias = bs + (size_t)l * 128; nl = n - 1536; ldb = 128; }
  size_t dst = (size_t)l * 212992 + (size_t)(n >> 7) * 16384
             + (size_t)((k >> 3) * 128 + (n & 127)) * 8 + (k & 7);
  BT[dst] = f2bf(W[(size_t)k * ldb + nl]);
  if (k == 0) biascat[(size_t)l * 1664 + n] = bias[nl];
}

// ---------------- lin0: h = x @ W(70x128) + b (fp32 + k-major bf16) ----------
__global__ __launch_bounds__(128) void lin0_kernel(
    const float* __restrict__ x, const float* __restrict__ W,
    const float* __restrict__ b, float* __restrict__ h,
    unsigned short* __restrict__ hb, int N, int inF)
{
  __shared__ float xs[128];
  int n = blockIdx.x;
  int t = threadIdx.x;
  if (t < inF) xs[t] = x[(size_t)n * inF + t];
  __syncthreads();
  float acc = b[t];
  for (int k = 0; k < inF; k++) acc += xs[k] * W[(size_t)k * 128 + t];
  h[(size_t)n * 128 + t] = acc;
  hb[(size_t)(n >> 7) * 16384 + (size_t)((t >> 3) * 128 + (n & 127)) * 8 + (t & 7)] = f2bf(acc);
}

// ---------------- MFMA projection GEMM ----------------
// grid (ceil(M/128), 13); block 256 = 4 waves; per-wave 64x64 via 4x4 16x16 tiles.
// Outputs: q -> fp8 [N,512]; k -> fp8 into kv row bytes [0,512);
//          v -> fp8 into kv row bytes [512,1024); skip -> fp32 hn.
__global__ __launch_bounds__(256) void proj_mfma_kernel(
    const unsigned short* __restrict__ A, const unsigned short* __restrict__ BT,
    const float* __restrict__ bias, int M,
    unsigned char* __restrict__ qo, unsigned char* __restrict__ kv,
    float* __restrict__ hn)
{
  __shared__ unsigned short lsA[4096];
  __shared__ unsigned short lsB[4096];
  const int t = threadIdx.x;
  const int wv = t >> 6, ln = t & 63;
  const int wx = wv & 1, wy = wv >> 1;
  const int m0 = blockIdx.x * 128;
  const int nc = blockIdx.y;
  const int fr = ln & 15, quad = ln >> 4;

  const unsigned short* Ap = A + (size_t)blockIdx.x * 16384;
  const unsigned short* Bp = BT + (size_t)nc * 16384;

  f32x4 acc[4][4];
#pragma unroll
  for (int i = 0; i < 4; i++)
#pragma unroll
    for (int j = 0; j < 4; j++) acc[i][j] = (f32x4){0.f, 0.f, 0.f, 0.f};

  for (int kb = 0; kb < 4; kb++) {
    __syncthreads();                          // protect prev iter's ds_reads
#pragma unroll
    for (int it = 0; it < 2; it++) {
      const int c = it * 256 + t;             // 16-B chunk id, linear
      __builtin_amdgcn_global_load_lds(
          (const __attribute__((address_space(1))) void*)(Ap + (size_t)kb * 4096 + c * 8),
          (__attribute__((address_space(3))) void*)((char*)lsA + c * 16), 16, 0, 0);
      __builtin_amdgcn_global_load_lds(
          (const __attribute__((address_space(1))) void*)(Bp + (size_t)kb * 4096 + c * 8),
          (__attribute__((address_space(3))) void*)((char*)lsB + c * 16), 16, 0, 0);
    }
    __syncthreads();

    short8 af[4], bf[4];
#pragma unroll
    for (int i = 0; i < 4; i++)
      af[i] = *(const short8*)(&lsA[(size_t)(quad * 128 + wy * 64 + i * 16 + fr) * 8]);
#pragma unroll
    for (int j = 0; j < 4; j++)
      bf[j] = *(const short8*)(&lsB[(size_t)(quad * 128 + wx * 64 + j * 16 + fr) * 8]);
#pragma unroll
    for (int i = 0; i < 4; i++)
#pragma unroll
      for (int j = 0; j < 4; j++)
        acc[i][j] = __builtin_amdgcn_mfma_f32_16x16x32_bf16(bf[j], af[i], acc[i][j], 0, 0, 0);
  }

  // epilogue: lane holds rows m0+wy*64+i*16+fr, cols nc*128+wx*64+j*16+quad*4+(0..3)
  const int region = nc >> 2;                 // 0=q 1=k 2=v 3=skip
#pragma unroll
  for (int j = 0; j < 4; j++) {
    const int colb = nc * 128 + wx * 64 + j * 16 + quad * 4;
    const float4 b4 = *(const float4*)(&bias[colb]);
    const int col = colb - region * 512;
#pragma unroll
    for (int i = 0; i < 4; i++) {
      const int row = m0 + wy * 64 + i * 16 + fr;
      if (row < M) {
        f32x4 c = acc[i][j];
        float v0 = c[0] + b4.x, v1 = c[1] + b4.y, v2 = c[2] + b4.z, v3 = c[3] + b4.w;
        if (region == 0) {
          *(unsigned int*)(qo + (size_t)row * 512 + col) = pack4_fp8(v0, v1, v2, v3);
        } else if (region == 1) {
          *(unsigned int*)(kv + (size_t)row * 1024 + col) = pack4_fp8(v0, v1, v2, v3);
        } else if (region == 2) {
          *(unsigned int*)(kv + (size_t)row * 1024 + 512 + col) = pack4_fp8(v0, v1, v2, v3);
        } else {
          *(float4*)(hn + (size_t)row * 128 + col) = make_float4(v0, v1, v2, v3);
        }
      }
    }
  }
}

// ---------------- CSR build ----------------
__global__ __launch_bounds__(256) void hist_kernel(
    const int* __restrict__ dst, int* __restrict__ deg, int E)
{
  int e = blockIdx.x * 256 + threadIdx.x;
  if (e < E) atomicAdd(&deg[dst[e]], 1);
}

__global__ __launch_bounds__(256) void scan_block_kernel(
    const int* __restrict__ in, int* __restrict__ out, int* __restrict__ bsums, int N)
{
  __shared__ int sm[256];
  int i = blockIdx.x * 256 + threadIdx.x;
  int v = (i < N) ? in[i] : 0;
  sm[threadIdx.x] = v; __syncthreads();
  for (int off = 1; off < 256; off <<= 1) {
    int t = (threadIdx.x >= off) ? sm[threadIdx.x - off] : 0;
    __syncthreads();
    sm[threadIdx.x] += t;
    __syncthreads();
  }
  if (i < N) out[i] = sm[threadIdx.x] - v;   // exclusive
  if (threadIdx.x == 255 && bsums) bsums[blockIdx.x] = sm[255];
}

__global__ __launch_bounds__(256) void scan_finish_kernel(
    int* __restrict__ row_start, int* __restrict__ cursor,
    const int* __restrict__ bsums_scan, int N, int E)
{
  int i = blockIdx.x * 256 + threadIdx.x;
  if (i < N) {
    int val = row_start[i] + bsums_scan[blockIdx.x];
    row_start[i] = val;
    cursor[i] = val;
  }
  if (i == 0) row_start[N] = E;
}

__global__ __launch_bounds__(256) void scatter_kernel(
    const int* __restrict__ src, const int* __restrict__ dst,
    int* __restrict__ cursor, int* __restrict__ csr_src, int E)
{
  int e = blockIdx.x * 256 + threadIdx.x;
  if (e < E) {
    int pos = atomicAdd(&cursor[dst[e]], 1);
    csr_src[pos] = src[e];
  }
}

// ---------------- fused per-node attention (one wave per dst node) ----------
// h[d] = relu(h[d] + mean_h(softmax_e * v[src_e,h,:]));  hb = bf16 k-major panel
// kv row: [512 B fp8 k][512 B fp8 v]; per edge gathers 1 KB contiguous.
// Depth-3 software pipeline over edges (6 gathers in flight).
__global__ __launch_bounds__(256) void node_attn_kernel(
    const unsigned char* __restrict__ q, const unsigned char* __restrict__ kv,
    const int* __restrict__ row_start, const int* __restrict__ csr_src,
    float* __restrict__ hn, unsigned short* __restrict__ hb, int N)
{
  int d = (blockIdx.x * 256 + threadIdx.x) >> 6;
  int lane = threadIdx.x & 63;
  if (d >= N) return;
  int beg = row_start[d], end = row_start[d + 1];

  const float scale = 0.08838834764831845f;  // 1/sqrt(128), folded into q
  const uint2 qw = *(const uint2*)(q + (size_t)d * 512 + lane * 8);
  float qd[8];
  dec8_fp8(qw, qd);
#pragma unroll
  for (int j = 0; j < 8; j++) qd[j] *= scale;

  float num[8] = {0.f,0.f,0.f,0.f,0.f,0.f,0.f,0.f};
  float den = 0.f;

  auto krow = [&](int s) { return *(const uint2*)(kv + (size_t)s * 1024 + lane * 8); };
  auto vrow = [&](int s) { return *(const uint2*)(kv + (size_t)s * 1024 + 512 + lane * 8); };
  auto accum = [&](const uint2& kw, const uint2& vw) {
    float kd[8], vd[8];
    dec8_fp8(kw, kd);
    float p = qd[0] * kd[0] + qd[1] * kd[1] + qd[2] * kd[2] + qd[3] * kd[3]
            + qd[4] * kd[4] + qd[5] * kd[5] + qd[6] * kd[6] + qd[7] * kd[7];
    p += __shfl_xor(p, 1);
    p += __shfl_xor(p, 2);
    p += __shfl_xor(p, 4);
    p += __shfl_xor(p, 8);
    float e = __expf(p);
    den += e;
    dec8_fp8(vw, vd);
#pragma unroll
    for (int j = 0; j < 8; j++) num[j] += e * vd[j];
  };

  if (beg < end) {
    const int last = end - 1;
    int s0 = csr_src[beg];
    int s1 = csr_src[min(beg + 1, last)];
    int s2 = csr_src[min(beg + 2, last)];
    uint2 k0 = krow(s0); uint2 v0 = vrow(s0);
    uint2 k1 = krow(s1); uint2 v1 = vrow(s1);
    uint2 k2 = krow(s2); uint2 v2 = vrow(s2);
    for (int i = beg; i < end; i += 3) {
      int t0 = csr_src[min(i + 3, last)];
      int t1 = csr_src[min(i + 4, last)];
      int t2 = csr_src[min(i + 5, last)];
      uint2 ka = krow(t0); uint2 va = vrow(t0);
      uint2 kb = krow(t1); uint2 vb = vrow(t1);
      uint2 kc = krow(t2); uint2 vc = vrow(t2);
      accum(k0, v0);
      if (i + 1 < end) accum(k1, v1);
      if (i + 2 < end) accum(k2, v2);
      k0 = ka; v0 = va; k1 = kb; v1 = vb; k2 = kc; v2 = vc;
    }
  }

  float inv = (den > 0.f) ? 0.25f / den : 0.f;
#pragma unroll
  for (int j = 0; j < 8; j++) {
    float r = num[j] * inv;
    r += __shfl_xor(r, 16);   // combine 4 heads
    r += __shfl_xor(r, 32);
    num[j] = r;
  }
  if (lane < 16) {
    float* hp = hn + (size_t)d * 128 + lane * 8;
    float4 o0 = *(const float4*)(hp);
    float4 o1 = *(const float4*)(hp + 4);
    o0.x = fmaxf(o0.x + num[0], 0.f);
    o0.y = fmaxf(o0.y + num[1], 0.f);
    o0.z = fmaxf(o0.z + num[2], 0.f);
    o0.w = fmaxf(o0.w + num[3], 0.f);
    o1.x = fmaxf(o1.x + num[4], 0.f);
    o1.y = fmaxf(o1.y + num[5], 0.f);
    o1.z = fmaxf(o1.z + num[6], 0.f);
    o1.w = fmaxf(o1.w + num[7], 0.f);
    *(float4*)(hp) = o0;
    *(float4*)(hp + 4) = o1;
    uint4 hv;
    hv.x = (unsigned int)f2bf(o0.x) | ((unsigned int)f2bf(o0.y) << 16);
    hv.y = (unsigned int)f2bf(o0.z) | ((unsigned int)f2bf(o0.w) << 16);
    hv.z = (unsigned int)f2bf(o1.x) | ((unsigned int)f2bf(o1.y) << 16);
    hv.w = (unsigned int)f2bf(o1.z) | ((unsigned int)f2bf(o1.w) << 16);
    // k-major panel: chunk J = lane, row = d
    *(uint4*)(hb + (size_t)(d >> 7) * 16384 + (size_t)(lane * 128 + (d & 127)) * 8) = hv;
  }
}

// ---------------- pooling: emb[batch[n]] += h[n] (batch sorted) ----------------
__global__ __launch_bounds__(128) void pool_kernel(
    const float* __restrict__ h, const int* __restrict__ batch,
    float* __restrict__ emb, int N)
{
  int d = threadIdx.x;
  int n0 = blockIdx.x * 128;
  int n1 = min(n0 + 128, N);
  float acc = 0.f; int cur = -1;
  for (int n = n0; n < n1; n++) {
    int g = batch[n];
    if (g != cur) {
      if (cur >= 0) atomicAdd(&emb[(size_t)cur * 128 + d], acc);
      cur = g; acc = 0.f;
    }
    acc += h[(size_t)n * 128 + d];
  }
  if (cur >= 0) atomicAdd(&emb[(size_t)cur * 128 + d], acc);
}

// ---------------- final score ----------------
__global__ __launch_bounds__(128) void score_kernel(
    const float* __restrict__ hemb, const float* __restrict__ temb,
    const int* __restrict__ rels,
    const float* __restrict__ wqW, const float* __restrict__ wqb,
    const float* __restrict__ wkW, const float* __restrict__ wkb,
    const float* __restrict__ rel_emb, float* __restrict__ out)
{
  const int b = blockIdx.x, i = threadIdx.x;
  __shared__ float hs[128], ts[128], hnv[128], tnv[128], red[128];
  hs[i] = hemb[(size_t)b * 128 + i];
  ts[i] = temb[(size_t)b * 128 + i];
  __syncthreads();
  float qv = wqb[i], kv = wkb[i];
  for (int k = 0; k < 128; k++) {
    qv += hs[k] * wqW[k * 128 + i];
    kv += ts[k] * wkW[k * 128 + i];
  }
  float inter = tanhf(qv * kv);
  float hx = hs[i] + inter, tx2 = ts[i] + inter;

  red[i] = hx * hx; __syncthreads();
  for (int s = 64; s > 0; s >>= 1) { if (i < s) red[i] += red[i + s]; __syncthreads(); }
  float hnorm = fmaxf(sqrtf(red[0]), 1e-12f);
  __syncthreads();
  red[i] = tx2 * tx2; __syncthreads();
  for (int s = 64; s > 0; s >>= 1) { if (i < s) red[i] += red[i + s]; __syncthreads(); }
  float tnorm = fmaxf(sqrtf(red[0]), 1e-12f);
  __syncthreads();
  hnv[i] = hx / hnorm; tnv[i] = tx2 / tnorm;
  __syncthreads();

  const float* R = rel_emb + (size_t)rels[b] * 16384 + (size_t)i * 128;
  float dot = 0.f, nrm = 0.f;
  for (int j = 0; j < 128; j++) { float r = R[j]; dot += r * tnv[j]; nrm += r * r; }
  float contrib = hnv[i] * dot / fmaxf(sqrtf(nrm), 1e-12f);
  red[i] = contrib; __syncthreads();
  for (int s = 64; s > 0; s >>= 1) { if (i < s) red[i] += red[i + s]; __syncthreads(); }
  if (i == 0) out[b] = red[0];
}

extern "C" void kernel_launch(void* const* d_in, const int* in_sizes, int n_in,
                              void* d_out, int out_size, void* d_ws, size_t ws_size,
                              hipStream_t stream)
{
  const float* h_x     = (const float*)d_in[0];
  const int*   h_ei    = (const int*)d_in[1];
  const int*   h_batch = (const int*)d_in[2];
  const float* t_x     = (const float*)d_in[3];
  const int*   t_ei    = (const int*)d_in[4];
  const int*   t_batch = (const int*)d_in[5];
  const int*   rels    = (const int*)d_in[6];
  const float* lin0_W  = (const float*)d_in[7];
  const float* lin0_b  = (const float*)d_in[8];
  const float* Wq      = (const float*)d_in[9];
  const float* bq      = (const float*)d_in[10];
  const float* Wk      = (const float*)d_in[11];
  const float* bk      = (const float*)d_in[12];
  const float* Wv      = (const float*)d_in[13];
  const float* bv      = (const float*)d_in[14];
  const float* Ws      = (const float*)d_in[15];
  const float* bs      = (const float*)d_in[16];
  const float* wqW     = (const float*)d_in[17];
  const float* wqb     = (const float*)d_in[18];
  const float* wkW     = (const float*)d_in[19];
  const float* wkb     = (const float*)d_in[20];
  const float* rel_emb = (const float*)d_in[21];

  const int N = in_sizes[2];          // 50000
  const int E = in_sizes[1] / 2;      // 400000
  const int G = in_sizes[6];          // 512
  const int inF = in_sizes[7] / 128;  // 70
  const int nPanels = (N + 127) / 128;

  char* ws = (char*)d_ws;
  size_t off = 0;
  auto alloc = [&](size_t bytes) -> void* {
    void* p = ws + off; off += (bytes + 255) & ~(size_t)255; return p;
  };
  float* hA            = (float*)alloc((size_t)N * 128 * 4);
  unsigned short* hbuf = (unsigned short*)alloc((size_t)nPanels * 16384 * 2);
  unsigned char* qb    = (unsigned char*)alloc((size_t)N * 512);
  unsigned char* kvbuf = (unsigned char*)alloc((size_t)N * 1024);
  unsigned short* BT   = (unsigned short*)alloc((size_t)3 * 212992 * 2);
  float* biascat       = (float*)alloc((size_t)3 * 1664 * 4);
  int* deg             = (int*)alloc((size_t)(N + 1) * 4);
  int* row_start       = (int*)alloc((size_t)(N + 1) * 4);
  int* cursor          = (int*)alloc((size_t)(N + 1) * 4);
  int* bsums           = (int*)alloc((size_t)1024 * 4);
  int* bsums_scan      = (int*)alloc((size_t)1024 * 4);
  int* csr_src         = (int*)alloc((size_t)E * 4);
  float* hEmb          = (float*)alloc((size_t)G * 128 * 4);
  float* tEmb          = (float*)alloc((size_t)G * 128 * 4);
  (void)ws_size; (void)n_in; (void)out_size;

  const int nScanBlocks = (N + 255) / 256;

  // Convert weights once per call (shared by both graphs)
  wcvt_kernel<<<3 * 1664, 128, 0, stream>>>(Wq, bq, Wk, bk, Wv, bv, Ws, bs, BT, biascat);

  for (int g = 0; g < 2; g++) {
    const float* x     = g ? t_x : h_x;
    const int*   ei    = g ? t_ei : h_ei;
    const int*   batch = g ? t_batch : h_batch;
    float*       emb   = g ? tEmb : hEmb;
    const int* srcp = ei;
    const int* dstp = ei + E;

    // --- build CSR (edges grouped by dst) ---
    hipMemsetAsync(deg, 0, (size_t)(N + 1) * 4, stream);
    hist_kernel<<<(E + 255) / 256, 256, 0, stream>>>(dstp, deg, E);
    scan_block_kernel<<<nScanBlocks, 256, 0, stream>>>(deg, row_start, bsums, N);
    scan_block_kernel<<<1, 256, 0, stream>>>(bsums, bsums_scan, nullptr, nScanBlocks);
    scan_finish_kernel<<<nScanBlocks, 256, 0, stream>>>(row_start, cursor, bsums_scan, N, E);
    scatter_kernel<<<(E + 255) / 256, 256, 0, stream>>>(srcp, dstp, cursor, csr_src, E);

    lin0_kernel<<<N, 128, 0, stream>>>(x, lin0_W, lin0_b, hA, hbuf, N, inF);
    for (int l = 0; l < 3; l++) {
      dim3 pg(nPanels, 13);
      proj_mfma_kernel<<<pg, 256, 0, stream>>>(hbuf,
          BT + (size_t)l * 212992, biascat + (size_t)l * 1664, N,
          qb, kvbuf, hA);
      node_attn_kernel<<<(N + 3) / 4, 256, 0, stream>>>(qb, kvbuf,
          row_start, csr_src, hA, hbuf, N);
    }
    hipMemsetAsync(emb, 0, (size_t)G * 128 * 4, stream);
    pool_kernel<<<(N + 127) / 128, 128, 0, stream>>>(hA, batch, emb, N);
  }

  score_kernel<<<G, 128, 0, stream>>>(hEmb, tEmb, rels, wqW, wqb, wkW, wkb,
                                      rel_emb, (float*)d_out);
}

// Round 3
// 1191.404 us; speedup vs baseline: 1.4854x; 1.0921x over previous
//
#include <hip/hip_runtime.h>
#include <math.h>

#define HID 128

typedef __attribute__((ext_vector_type(8))) short short8;
typedef __attribute__((ext_vector_type(4))) float f32x4;
typedef __attribute__((ext_vector_type(2))) float f32x2;

__device__ __forceinline__ float bf2f(unsigned int u16) {
  union { unsigned int i; float f; } x; x.i = u16 << 16; return x.f;
}
__device__ __forceinline__ unsigned short f2bf(float f) {
  union { float f; unsigned int i; } x; x.f = f;
  unsigned int i = x.i;
  unsigned int r = i + 0x7FFFu + ((i >> 16) & 1u);
  return (unsigned short)(r >> 16);
}

// ---- fp8 e4m3 (OCP) helpers -------------------------------------------------
__device__ __forceinline__ unsigned char f2fp8_sw(float f) {
  union { float f; unsigned int u; } v; v.f = f;
  unsigned int s = (v.u >> 24) & 0x80u;
  v.u &= 0x7FFFFFFFu;
  if (v.f != v.f) return (unsigned char)(s | 0x7Fu);
  if (v.f >= 464.f) return (unsigned char)(s | 0x7Eu);          // saturate 448
  if (v.f < 0.0009765625f) return (unsigned char)s;             // < 2^-10 -> 0
  int ebits = (int)(v.u >> 23);
  if (ebits >= 121) {                                           // normal (exp >= -6)
    unsigned int r = v.u + 0x7FFFFu + ((v.u >> 20) & 1u);       // RNE at bit 20
    int E = (int)(r >> 23) - 127 + 7;
    unsigned int m = (r >> 20) & 7u;
    if (E >= 16) return (unsigned char)(s | 0x7Eu);
    return (unsigned char)(s | ((unsigned int)E << 3) | m);
  } else {                                                      // subnormal
    int M = (int)rintf(v.f * 512.f);
    if (M > 8) M = 8;
    return (unsigned char)(s | (unsigned int)M);
  }
}

__device__ __forceinline__ unsigned int pack4_fp8(float a, float b, float c, float d) {
#if __has_builtin(__builtin_amdgcn_cvt_pk_fp8_f32)
  int w = 0;
  w = __builtin_amdgcn_cvt_pk_fp8_f32(a, b, w, false);
  w = __builtin_amdgcn_cvt_pk_fp8_f32(c, d, w, true);
  return (unsigned int)w;
#else
  return (unsigned int)f2fp8_sw(a) | ((unsigned int)f2fp8_sw(b) << 8)
       | ((unsigned int)f2fp8_sw(c) << 16) | ((unsigned int)f2fp8_sw(d) << 24);
#endif
}

#if !__has_builtin(__builtin_amdgcn_cvt_pk_f32_fp8)
__device__ __forceinline__ float dec1_fp8(unsigned int u) {
  unsigned int s = (u & 0x80u) << 24;
  unsigned int em = u & 0x7Fu;
  union { unsigned int i; float f; } t;
  t.i = s | ((em << 20) + 0x3C000000u);
  float sub = (float)(int)(u & 7u) * ((u & 0x80u) ? -0.001953125f : 0.001953125f);
  return (em >= 8u) ? t.f : sub;
}
#endif

__device__ __forceinline__ void dec8_fp8(uint2 w, float* o) {
#if __has_builtin(__builtin_amdgcn_cvt_pk_f32_fp8)
  f32x2 p;
  p = __builtin_amdgcn_cvt_pk_f32_fp8((int)w.x, false); o[0] = p.x; o[1] = p.y;
  p = __builtin_amdgcn_cvt_pk_f32_fp8((int)w.x, true);  o[2] = p.x; o[3] = p.y;
  p = __builtin_amdgcn_cvt_pk_f32_fp8((int)w.y, false); o[4] = p.x; o[5] = p.y;
  p = __builtin_amdgcn_cvt_pk_f32_fp8((int)w.y, true);  o[6] = p.x; o[7] = p.y;
#else
  o[0] = dec1_fp8(w.x & 0xFFu);        o[1] = dec1_fp8((w.x >> 8) & 0xFFu);
  o[2] = dec1_fp8((w.x >> 16) & 0xFFu); o[3] = dec1_fp8(w.x >> 24);
  o[4] = dec1_fp8(w.y & 0xFFu);        o[5] = dec1_fp8((w.y >> 8) & 0xFFu);
  o[6] = dec1_fp8((w.y >> 16) & 0xFFu); o[7] = dec1_fp8(w.y >> 24);
#endif
}

// k-major panel layout for MFMA A/B sides:
//   panel p = row>>7 (128 rows), chunk Jg = k>>3 (8 elems), slot = Jg*128 + (row&127)
//   elem addr = p*16384 + slot*8 + (k&7)

// ---------------- weight convert: k-major panels + biascat ----------------
__global__ __launch_bounds__(128) void wcvt_kernel(
    const float* __restrict__ Wq, const float* __restrict__ bq,
    const float* __restrict__ Wk, const float* __restrict__ bk,
    const float* __restrict__ Wv, const float* __restrict__ bv,
    const float* __restrict__ Ws, const float* __restrict__ bs,
    unsigned short* __restrict__ BT, float* __restrict__ biascat)
{
  int id = blockIdx.x;
  int l = id / 1664;
  int n = id - l * 1664;
  int k = threadIdx.x;
  const float* W; const float* bias; int nl, ldb;
  if (n < 512)       { W = Wq + (size_t)l * 65536; bias = bq + (size_t)l * 512; nl = n;        ldb = 512; }
  else if (n < 1024) { W = Wk + (size_t)l * 65536; bias = bk + (size_t)l * 512; nl = n - 512;  ldb = 512; }
  else if (n < 1536) { W = Wv + (size_t)l * 65536; bias = bv + (size_t)l * 512; nl = n - 1024; ldb = 512; }
  else               { W = Ws + (size_t)l * 16384; bias = bs + (size_t)l * 128; nl = n - 1536; ldb = 128; }
  size_t dst = (size_t)l * 212992 + (size_t)(n >> 7) * 16384
             + (size_t)((k >> 3) * 128 + (n & 127)) * 8 + (k & 7);
  BT[dst] = f2bf(W[(size_t)k * ldb + nl]);
  if (k == 0) biascat[(size_t)l * 1664 + n] = bias[nl];
}

// ---------------- lin0 v2: 64 nodes/block, W column in registers ----------
// block 256 = 2 col-groups x 128 cols; x panel staged in LDS (stride 72 for
// aligned f32x4 wave-uniform broadcast reads); W[.][col] lives in 70 VGPRs.
__global__ __launch_bounds__(256) void lin0_kernel(
    const float* __restrict__ x, const float* __restrict__ W,
    const float* __restrict__ b, float* __restrict__ h,
    unsigned short* __restrict__ hb, int N, int inF)
{
  __shared__ float xs[64 * 72];
  const int t = threadIdx.x;
  const int col = t & 127, grp = t >> 7;
  const int n0 = blockIdx.x * 64;
  const int nrows = min(64, N - n0);

  if (inF == 70) {
    // stage x: 35 float2 per row, 4 threads per row
    const float* xp = x + (size_t)n0 * 70;
    const int r = t >> 2, q = t & 3;
    if (r < nrows) {
      for (int c = q; c < 35; c += 4)
        *(float2*)&xs[r * 72 + c * 2] = *(const float2*)&xp[(size_t)r * 70 + c * 2];
    }
    float w[70];
#pragma unroll
    for (int k = 0; k < 70; k++) w[k] = W[(size_t)k * 128 + col];
    const float bias = b[col];
    __syncthreads();
    for (int i = grp; i < nrows; i += 2) {
      const float* xr = &xs[i * 72];
      float acc = bias;
#pragma unroll
      for (int c = 0; c < 17; c++) {
        f32x4 xv = *(const f32x4*)&xr[c * 4];
        acc = fmaf(xv[0], w[c * 4 + 0], acc);
        acc = fmaf(xv[1], w[c * 4 + 1], acc);
        acc = fmaf(xv[2], w[c * 4 + 2], acc);
        acc = fmaf(xv[3], w[c * 4 + 3], acc);
      }
      acc = fmaf(xr[68], w[68], acc);
      acc = fmaf(xr[69], w[69], acc);
      const int n = n0 + i;
      h[(size_t)n * 128 + col] = acc;
      hb[(size_t)(n >> 7) * 16384 + (size_t)((col >> 3) * 128 + (n & 127)) * 8 + (col & 7)] = f2bf(acc);
    }
  } else {
    // generic fallback (not taken in this benchmark)
    const float bias = b[col];
    for (int i = grp; i < nrows; i += 2) {
      const int n = n0 + i;
      float acc = bias;
      for (int k = 0; k < inF; k++) acc += x[(size_t)n * inF + k] * W[(size_t)k * 128 + col];
      h[(size_t)n * 128 + col] = acc;
      hb[(size_t)(n >> 7) * 16384 + (size_t)((col >> 3) * 128 + (n & 127)) * 8 + (col & 7)] = f2bf(acc);
    }
  }
}

// ---------------- MFMA projection GEMM v2 ----------------
// grid = ceil(M/64) 1-D; block 256 = 4 waves; M-tile 64, nc looped 0..12 with
// A half-panel LDS-resident (read once) + double-buffered 8 KB B tiles.
// fp8 epilogues staged through padded LDS -> full-line uint4 stores.
__global__ __launch_bounds__(256) void proj_mfma_kernel(
    const unsigned short* __restrict__ A, const unsigned short* __restrict__ BT,
    const float* __restrict__ bias, int M,
    unsigned char* __restrict__ qo, unsigned char* __restrict__ kv,
    float* __restrict__ hn)
{
  __shared__ unsigned short lsA[8192];       // 16 KB: (Jg*64 + r)*8, Jg=0..15
  __shared__ unsigned short lsB[2][4096];    // 8 KB x2 double buffer
  __shared__ unsigned int   lsS[64 * 33];    // fp8 staging, 132 B rows (pad)

  const int t = threadIdx.x;
  const int wv = t >> 6, ln = t & 63;
  const int fr = ln & 15, quad = ln >> 4;
  const int mb = blockIdx.x;
  const int row0 = mb * 64;
  const int panel = mb >> 1, half = mb & 1;

  const unsigned short* Ap = A + (size_t)panel * 16384;

  // load A half-panel: 1024 x 16B chunks, LDS-linear, coalesced
#pragma unroll
  for (int it = 0; it < 4; it++) {
    const int c = it * 256 + t;
    const int Jg = c >> 6, r = c & 63;
    __builtin_amdgcn_global_load_lds(
        (const __attribute__((address_space(1))) void*)(Ap + (size_t)(Jg * 128 + half * 64 + r) * 8),
        (__attribute__((address_space(3))) void*)((char*)lsA + c * 16), 16, 0, 0);
  }

  auto prefB = [&](int nc, int kb, int buf) {
    const unsigned short* Bp = BT + (size_t)nc * 16384 + (size_t)kb * 4096;
#pragma unroll
    for (int it = 0; it < 2; it++) {
      const int c = it * 256 + t;
      __builtin_amdgcn_global_load_lds(
          (const __attribute__((address_space(1))) void*)(Bp + c * 8),
          (__attribute__((address_space(3))) void*)((char*)lsB[buf] + c * 16), 16, 0, 0);
    }
  };

  prefB(0, 0, 0);
  __syncthreads();                            // drains A + first B

  int p = 0;
  for (int nc = 0; nc < 13; nc++) {
    f32x4 acc[4][2];
#pragma unroll
    for (int i = 0; i < 4; i++)
#pragma unroll
      for (int j = 0; j < 2; j++) acc[i][j] = (f32x4){0.f, 0.f, 0.f, 0.f};

    for (int kb = 0; kb < 4; kb++) {
      if (!(nc == 12 && kb == 3)) {
        const int nkb = (kb + 1) & 3;
        const int nnc = (kb == 3) ? nc + 1 : nc;
        prefB(nnc, nkb, p ^ 1);
      }
      short8 af[4], bf[2];
#pragma unroll
      for (int i = 0; i < 4; i++)
        af[i] = *(const short8*)(&lsA[(size_t)((kb * 4 + quad) * 64 + i * 16 + fr) * 8]);
#pragma unroll
      for (int j = 0; j < 2; j++)
        bf[j] = *(const short8*)(&lsB[p][(size_t)(quad * 128 + wv * 32 + j * 16 + fr) * 8]);
#pragma unroll
      for (int i = 0; i < 4; i++)
#pragma unroll
        for (int j = 0; j < 2; j++)
          acc[i][j] = __builtin_amdgcn_mfma_f32_16x16x32_bf16(bf[j], af[i], acc[i][j], 0, 0, 0);
      __syncthreads();                        // drains prefetch; protects lsB reuse
      p ^= 1;
    }

    const int region = nc >> 2;               // 0=q 1=k 2=v 3=skip
    if (region < 3) {
      // pack fp8 + stage into padded LDS
#pragma unroll
      for (int i = 0; i < 4; i++)
#pragma unroll
        for (int j = 0; j < 2; j++) {
          const int colL = wv * 32 + j * 16 + quad * 4;
          const float4 b4 = *(const float4*)(&bias[nc * 128 + colL]);
          f32x4 c = acc[i][j];
          const unsigned int pk = pack4_fp8(c[0] + b4.x, c[1] + b4.y, c[2] + b4.z, c[3] + b4.w);
          lsS[(i * 16 + fr) * 33 + (colL >> 2)] = pk;
        }
      __syncthreads();
      // dump: 512 x uint4, row-contiguous 128 B runs
      const int ncl = nc & 3;
#pragma unroll
      for (int it = 0; it < 2; it++) {
        const int idx = it * 256 + t;
        const int r = idx >> 3, g = idx & 7;
        const int row = row0 + r;
        if (row < M) {
          uint4 v;
          v.x = lsS[r * 33 + g * 4 + 0];
          v.y = lsS[r * 33 + g * 4 + 1];
          v.z = lsS[r * 33 + g * 4 + 2];
          v.w = lsS[r * 33 + g * 4 + 3];
          unsigned char* dst = (region == 0)
              ? qo + (size_t)row * 512 + ncl * 128 + g * 16
              : kv + (size_t)row * 1024 + (region == 2 ? 512 : 0) + ncl * 128 + g * 16;
          *(uint4*)dst = v;
        }
      }
      __syncthreads();                        // protect lsS before next nc
    } else {
      // hn fp32: direct stores (already full-line)
#pragma unroll
      for (int j = 0; j < 2; j++) {
        const int colL = wv * 32 + j * 16 + quad * 4;
        const float4 b4 = *(const float4*)(&bias[nc * 128 + colL]);
#pragma unroll
        for (int i = 0; i < 4; i++) {
          const int row = row0 + i * 16 + fr;
          if (row < M) {
            f32x4 c = acc[i][j];
            *(float4*)(hn + (size_t)row * 128 + colL) =
                make_float4(c[0] + b4.x, c[1] + b4.y, c[2] + b4.z, c[3] + b4.w);
          }
        }
      }
    }
  }
}

// ---------------- CSR build ----------------
__global__ __launch_bounds__(256) void hist_kernel(
    const int* __restrict__ dst, int* __restrict__ deg, int E)
{
  int e = blockIdx.x * 256 + threadIdx.x;
  if (e < E) atomicAdd(&deg[dst[e]], 1);
}

__global__ __launch_bounds__(256) void scan_block_kernel(
    const int* __restrict__ in, int* __restrict__ out, int* __restrict__ bsums, int N)
{
  __shared__ int sm[256];
  int i = blockIdx.x * 256 + threadIdx.x;
  int v = (i < N) ? in[i] : 0;
  sm[threadIdx.x] = v; __syncthreads();
  for (int off = 1; off < 256; off <<= 1) {
    int t = (threadIdx.x >= off) ? sm[threadIdx.x - off] : 0;
    __syncthreads();
    sm[threadIdx.x] += t;
    __syncthreads();
  }
  if (i < N) out[i] = sm[threadIdx.x] - v;   // exclusive
  if (threadIdx.x == 255 && bsums) bsums[blockIdx.x] = sm[255];
}

__global__ __launch_bounds__(256) void scan_finish_kernel(
    int* __restrict__ row_start, int* __restrict__ cursor,
    const int* __restrict__ bsums_scan, int N, int E)
{
  int i = blockIdx.x * 256 + threadIdx.x;
  if (i < N) {
    int val = row_start[i] + bsums_scan[blockIdx.x];
    row_start[i] = val;
    cursor[i] = val;
  }
  if (i == 0) row_start[N] = E;
}

__global__ __launch_bounds__(256) void scatter_kernel(
    const int* __restrict__ src, const int* __restrict__ dst,
    int* __restrict__ cursor, int* __restrict__ csr_src, int E)
{
  int e = blockIdx.x * 256 + threadIdx.x;
  if (e < E) {
    int pos = atomicAdd(&cursor[dst[e]], 1);
    csr_src[pos] = src[e];
  }
}

// ---------------- fused per-node attention (one wave per dst node) ----------
// h[d] = relu(h[d] + mean_h(softmax_e * v[src_e,h,:]));  hb = bf16 k-major panel
// kv row: [512 B fp8 k][512 B fp8 v]; per edge gathers 1 KB contiguous.
// Depth-3 software pipeline over edges (6 gathers in flight).
__global__ __launch_bounds__(256) void node_attn_kernel(
    const unsigned char* __restrict__ q, const unsigned char* __restrict__ kv,
    const int* __restrict__ row_start, const int* __restrict__ csr_src,
    float* __restrict__ hn, unsigned short* __restrict__ hb, int N)
{
  int d = (blockIdx.x * 256 + threadIdx.x) >> 6;
  int lane = threadIdx.x & 63;
  if (d >= N) return;
  int beg = row_start[d], end = row_start[d + 1];

  const float scale = 0.08838834764831845f;  // 1/sqrt(128), folded into q
  const uint2 qw = *(const uint2*)(q + (size_t)d * 512 + lane * 8);
  float qd[8];
  dec8_fp8(qw, qd);
#pragma unroll
  for (int j = 0; j < 8; j++) qd[j] *= scale;

  float num[8] = {0.f,0.f,0.f,0.f,0.f,0.f,0.f,0.f};
  float den = 0.f;

  auto krow = [&](int s) { return *(const uint2*)(kv + (size_t)s * 1024 + lane * 8); };
  auto vrow = [&](int s) { return *(const uint2*)(kv + (size_t)s * 1024 + 512 + lane * 8); };
  auto accum = [&](const uint2& kw, const uint2& vw) {
    float kd[8], vd[8];
    dec8_fp8(kw, kd);
    float p = qd[0] * kd[0] + qd[1] * kd[1] + qd[2] * kd[2] + qd[3] * kd[3]
            + qd[4] * kd[4] + qd[5] * kd[5] + qd[6] * kd[6] + qd[7] * kd[7];
    p += __shfl_xor(p, 1);
    p += __shfl_xor(p, 2);
    p += __shfl_xor(p, 4);
    p += __shfl_xor(p, 8);
    float e = __expf(p);
    den += e;
    dec8_fp8(vw, vd);
#pragma unroll
    for (int j = 0; j < 8; j++) num[j] += e * vd[j];
  };

  if (beg < end) {
    const int last = end - 1;
    int s0 = csr_src[beg];
    int s1 = csr_src[min(beg + 1, last)];
    int s2 = csr_src[min(beg + 2, last)];
    uint2 k0 = krow(s0); uint2 v0 = vrow(s0);
    uint2 k1 = krow(s1); uint2 v1 = vrow(s1);
    uint2 k2 = krow(s2); uint2 v2 = vrow(s2);
    for (int i = beg; i < end; i += 3) {
      int t0 = csr_src[min(i + 3, last)];
      int t1 = csr_src[min(i + 4, last)];
      int t2 = csr_src[min(i + 5, last)];
      uint2 ka = krow(t0); uint2 va = vrow(t0);
      uint2 kb = krow(t1); uint2 vb = vrow(t1);
      uint2 kc = krow(t2); uint2 vc = vrow(t2);
      accum(k0, v0);
      if (i + 1 < end) accum(k1, v1);
      if (i + 2 < end) accum(k2, v2);
      k0 = ka; v0 = va; k1 = kb; v1 = vb; k2 = kc; v2 = vc;
    }
  }

  float inv = (den > 0.f) ? 0.25f / den : 0.f;
#pragma unroll
  for (int j = 0; j < 8; j++) {
    float r = num[j] * inv;
    r += __shfl_xor(r, 16);   // combine 4 heads
    r += __shfl_xor(r, 32);
    num[j] = r;
  }
  if (lane < 16) {
    float* hp = hn + (size_t)d * 128 + lane * 8;
    float4 o0 = *(const float4*)(hp);
    float4 o1 = *(const float4*)(hp + 4);
    o0.x = fmaxf(o0.x + num[0], 0.f);
    o0.y = fmaxf(o0.y + num[1], 0.f);
    o0.z = fmaxf(o0.z + num[2], 0.f);
    o0.w = fmaxf(o0.w + num[3], 0.f);
    o1.x = fmaxf(o1.x + num[4], 0.f);
    o1.y = fmaxf(o1.y + num[5], 0.f);
    o1.z = fmaxf(o1.z + num[6], 0.f);
    o1.w = fmaxf(o1.w + num[7], 0.f);
    *(float4*)(hp) = o0;
    *(float4*)(hp + 4) = o1;
    uint4 hv;
    hv.x = (unsigned int)f2bf(o0.x) | ((unsigned int)f2bf(o0.y) << 16);
    hv.y = (unsigned int)f2bf(o0.z) | ((unsigned int)f2bf(o0.w) << 16);
    hv.z = (unsigned int)f2bf(o1.x) | ((unsigned int)f2bf(o1.y) << 16);
    hv.w = (unsigned int)f2bf(o1.z) | ((unsigned int)f2bf(o1.w) << 16);
    // k-major panel: chunk J = lane, row = d
    *(uint4*)(hb + (size_t)(d >> 7) * 16384 + (size_t)(lane * 128 + (d & 127)) * 8) = hv;
  }
}

// ---------------- pooling: emb[batch[n]] += h[n] (batch sorted) ----------------
__global__ __launch_bounds__(128) void pool_kernel(
    const float* __restrict__ h, const int* __restrict__ batch,
    float* __restrict__ emb, int N)
{
  int d = threadIdx.x;
  int n0 = blockIdx.x * 128;
  int n1 = min(n0 + 128, N);
  float acc = 0.f; int cur = -1;
  for (int n = n0; n < n1; n++) {
    int g = batch[n];
    if (g != cur) {
      if (cur >= 0) atomicAdd(&emb[(size_t)cur * 128 + d], acc);
      cur = g; acc = 0.f;
    }
    acc += h[(size_t)n * 128 + d];
  }
  if (cur >= 0) atomicAdd(&emb[(size_t)cur * 128 + d], acc);
}

// ---------------- final score ----------------
__global__ __launch_bounds__(128) void score_kernel(
    const float* __restrict__ hemb, const float* __restrict__ temb,
    const int* __restrict__ rels,
    const float* __restrict__ wqW, const float* __restrict__ wqb,
    const float* __restrict__ wkW, const float* __restrict__ wkb,
    const float* __restrict__ rel_emb, float* __restrict__ out)
{
  const int b = blockIdx.x, i = threadIdx.x;
  __shared__ float hs[128], ts[128], hnv[128], tnv[128], red[128];
  hs[i] = hemb[(size_t)b * 128 + i];
  ts[i] = temb[(size_t)b * 128 + i];
  __syncthreads();
  float qv = wqb[i], kv = wkb[i];
  for (int k = 0; k < 128; k++) {
    qv += hs[k] * wqW[k * 128 + i];
    kv += ts[k] * wkW[k * 128 + i];
  }
  float inter = tanhf(qv * kv);
  float hx = hs[i] + inter, tx2 = ts[i] + inter;

  red[i] = hx * hx; __syncthreads();
  for (int s = 64; s > 0; s >>= 1) { if (i < s) red[i] += red[i + s]; __syncthreads(); }
  float hnorm = fmaxf(sqrtf(red[0]), 1e-12f);
  __syncthreads();
  red[i] = tx2 * tx2; __syncthreads();
  for (int s = 64; s > 0; s >>= 1) { if (i < s) red[i] += red[i + s]; __syncthreads(); }
  float tnorm = fmaxf(sqrtf(red[0]), 1e-12f);
  __syncthreads();
  hnv[i] = hx / hnorm; tnv[i] = tx2 / tnorm;
  __syncthreads();

  const float* R = rel_emb + (size_t)rels[b] * 16384 + (size_t)i * 128;
  float dot = 0.f, nrm = 0.f;
  for (int j = 0; j < 128; j++) { float r = R[j]; dot += r * tnv[j]; nrm += r * r; }
  float contrib = hnv[i] * dot / fmaxf(sqrtf(nrm), 1e-12f);
  red[i] = contrib; __syncthreads();
  for (int s = 64; s > 0; s >>= 1) { if (i < s) red[i] += red[i + s]; __syncthreads(); }
  if (i == 0) out[b] = red[0];
}

extern "C" void kernel_launch(void* const* d_in, const int* in_sizes, int n_in,
                              void* d_out, int out_size, void* d_ws, size_t ws_size,
                              hipStream_t stream)
{
  const float* h_x     = (const float*)d_in[0];
  const int*   h_ei    = (const int*)d_in[1];
  const int*   h_batch = (const int*)d_in[2];
  const float* t_x     = (const float*)d_in[3];
  const int*   t_ei    = (const int*)d_in[4];
  const int*   t_batch = (const int*)d_in[5];
  const int*   rels    = (const int*)d_in[6];
  const float* lin0_W  = (const float*)d_in[7];
  const float* lin0_b  = (const float*)d_in[8];
  const float* Wq      = (const float*)d_in[9];
  const float* bq      = (const float*)d_in[10];
  const float* Wk      = (const float*)d_in[11];
  const float* bk      = (const float*)d_in[12];
  const float* Wv      = (const float*)d_in[13];
  const float* bv      = (const float*)d_in[14];
  const float* Ws      = (const float*)d_in[15];
  const float* bs      = (const float*)d_in[16];
  const float* wqW     = (const float*)d_in[17];
  const float* wqb     = (const float*)d_in[18];
  const float* wkW     = (const float*)d_in[19];
  const float* wkb     = (const float*)d_in[20];
  const float* rel_emb = (const float*)d_in[21];

  const int N = in_sizes[2];          // 50000
  const int E = in_sizes[1] / 2;      // 400000
  const int G = in_sizes[6];          // 512
  const int inF = in_sizes[7] / 128;  // 70
  const int nPanels = (N + 127) / 128;
  const int nMB = (N + 63) / 64;

  char* ws = (char*)d_ws;
  size_t off = 0;
  auto alloc = [&](size_t bytes) -> void* {
    void* p = ws + off; off += (bytes + 255) & ~(size_t)255; return p;
  };
  float* hA            = (float*)alloc((size_t)N * 128 * 4);
  unsigned short* hbuf = (unsigned short*)alloc((size_t)nPanels * 16384 * 2);
  unsigned char* qb    = (unsigned char*)alloc((size_t)N * 512);
  unsigned char* kvbuf = (unsigned char*)alloc((size_t)N * 1024);
  unsigned short* BT   = (unsigned short*)alloc((size_t)3 * 212992 * 2);
  float* biascat       = (float*)alloc((size_t)3 * 1664 * 4);
  int* deg             = (int*)alloc((size_t)(N + 1) * 4);
  int* row_start       = (int*)alloc((size_t)(N + 1) * 4);
  int* cursor          = (int*)alloc((size_t)(N + 1) * 4);
  int* bsums           = (int*)alloc((size_t)1024 * 4);
  int* bsums_scan      = (int*)alloc((size_t)1024 * 4);
  int* csr_src         = (int*)alloc((size_t)E * 4);
  float* hEmb          = (float*)alloc((size_t)G * 128 * 4);
  float* tEmb          = (float*)alloc((size_t)G * 128 * 4);
  (void)ws_size; (void)n_in; (void)out_size;

  const int nScanBlocks = (N + 255) / 256;

  // Convert weights once per call (shared by both graphs)
  wcvt_kernel<<<3 * 1664, 128, 0, stream>>>(Wq, bq, Wk, bk, Wv, bv, Ws, bs, BT, biascat);

  for (int g = 0; g < 2; g++) {
    const float* x     = g ? t_x : h_x;
    const int*   ei    = g ? t_ei : h_ei;
    const int*   batch = g ? t_batch : h_batch;
    float*       emb   = g ? tEmb : hEmb;
    const int* srcp = ei;
    const int* dstp = ei + E;

    // --- build CSR (edges grouped by dst) ---
    hipMemsetAsync(deg, 0, (size_t)(N + 1) * 4, stream);
    hist_kernel<<<(E + 255) / 256, 256, 0, stream>>>(dstp, deg, E);
    scan_block_kernel<<<nScanBlocks, 256, 0, stream>>>(deg, row_start, bsums, N);
    scan_block_kernel<<<1, 256, 0, stream>>>(bsums, bsums_scan, nullptr, nScanBlocks);
    scan_finish_kernel<<<nScanBlocks, 256, 0, stream>>>(row_start, cursor, bsums_scan, N, E);
    scatter_kernel<<<(E + 255) / 256, 256, 0, stream>>>(srcp, dstp, cursor, csr_src, E);

    lin0_kernel<<<nMB, 256, 0, stream>>>(x, lin0_W, lin0_b, hA, hbuf, N, inF);
    for (int l = 0; l < 3; l++) {
      proj_mfma_kernel<<<nMB, 256, 0, stream>>>(hbuf,
          BT + (size_t)l * 212992, biascat + (size_t)l * 1664, N,
          qb, kvbuf, hA);
      node_attn_kernel<<<(N + 3) / 4, 256, 0, stream>>>(qb, kvbuf,
          row_start, csr_src, hA, hbuf, N);
    }
    hipMemsetAsync(emb, 0, (size_t)G * 128 * 4, stream);
    pool_kernel<<<(N + 127) / 128, 128, 0, stream>>>(hA, batch, emb, N);
  }

  score_kernel<<<G, 128, 0, stream>>>(hEmb, tEmb, rels, wqW, wqb, wkW, wkb,
                                      rel_emb, (float*)d_out);
}

// Round 5
// 1065.971 us; speedup vs baseline: 1.6602x; 1.1177x over previous
//
#include <hip/hip_runtime.h>
#include <math.h>

#define HID 128

typedef __attribute__((ext_vector_type(8))) short short8;
typedef __attribute__((ext_vector_type(4))) float f32x4;
typedef __attribute__((ext_vector_type(2))) float f32x2;

__device__ __forceinline__ float bf2f(unsigned int u16) {
  union { unsigned int i; float f; } x; x.i = u16 << 16; return x.f;
}
__device__ __forceinline__ unsigned short f2bf(float f) {
  union { float f; unsigned int i; } x; x.f = f;
  unsigned int i = x.i;
  unsigned int r = i + 0x7FFFu + ((i >> 16) & 1u);
  return (unsigned short)(r >> 16);
}

// ---- fp8 e4m3 (OCP) helpers -------------------------------------------------
__device__ __forceinline__ unsigned char f2fp8_sw(float f) {
  union { float f; unsigned int u; } v; v.f = f;
  unsigned int s = (v.u >> 24) & 0x80u;
  v.u &= 0x7FFFFFFFu;
  if (v.f != v.f) return (unsigned char)(s | 0x7Fu);
  if (v.f >= 464.f) return (unsigned char)(s | 0x7Eu);          // saturate 448
  if (v.f < 0.0009765625f) return (unsigned char)s;             // < 2^-10 -> 0
  int ebits = (int)(v.u >> 23);
  if (ebits >= 121) {                                           // normal (exp >= -6)
    unsigned int r = v.u + 0x7FFFFu + ((v.u >> 20) & 1u);       // RNE at bit 20
    int E = (int)(r >> 23) - 127 + 7;
    unsigned int m = (r >> 20) & 7u;
    if (E >= 16) return (unsigned char)(s | 0x7Eu);
    return (unsigned char)(s | ((unsigned int)E << 3) | m);
  } else {                                                      // subnormal
    int M = (int)rintf(v.f * 512.f);
    if (M > 8) M = 8;
    return (unsigned char)(s | (unsigned int)M);
  }
}

__device__ __forceinline__ unsigned int pack4_fp8(float a, float b, float c, float d) {
#if __has_builtin(__builtin_amdgcn_cvt_pk_fp8_f32)
  int w = 0;
  w = __builtin_amdgcn_cvt_pk_fp8_f32(a, b, w, false);
  w = __builtin_amdgcn_cvt_pk_fp8_f32(c, d, w, true);
  return (unsigned int)w;
#else
  return (unsigned int)f2fp8_sw(a) | ((unsigned int)f2fp8_sw(b) << 8)
       | ((unsigned int)f2fp8_sw(c) << 16) | ((unsigned int)f2fp8_sw(d) << 24);
#endif
}

#if !__has_builtin(__builtin_amdgcn_cvt_pk_f32_fp8)
__device__ __forceinline__ float dec1_fp8(unsigned int u) {
  unsigned int s = (u & 0x80u) << 24;
  unsigned int em = u & 0x7Fu;
  union { unsigned int i; float f; } t;
  t.i = s | ((em << 20) + 0x3C000000u);
  float sub = (float)(int)(u & 7u) * ((u & 0x80u) ? -0.001953125f : 0.001953125f);
  return (em >= 8u) ? t.f : sub;
}
#endif

__device__ __forceinline__ void dec8_fp8(uint2 w, float* o) {
#if __has_builtin(__builtin_amdgcn_cvt_pk_f32_fp8)
  f32x2 p;
  p = __builtin_amdgcn_cvt_pk_f32_fp8((int)w.x, false); o[0] = p.x; o[1] = p.y;
  p = __builtin_amdgcn_cvt_pk_f32_fp8((int)w.x, true);  o[2] = p.x; o[3] = p.y;
  p = __builtin_amdgcn_cvt_pk_f32_fp8((int)w.y, false); o[4] = p.x; o[5] = p.y;
  p = __builtin_amdgcn_cvt_pk_f32_fp8((int)w.y, true);  o[6] = p.x; o[7] = p.y;
#else
  o[0] = dec1_fp8(w.x & 0xFFu);        o[1] = dec1_fp8((w.x >> 8) & 0xFFu);
  o[2] = dec1_fp8((w.x >> 16) & 0xFFu); o[3] = dec1_fp8(w.x >> 24);
  o[4] = dec1_fp8(w.y & 0xFFu);        o[5] = dec1_fp8((w.y >> 8) & 0xFFu);
  o[6] = dec1_fp8((w.y >> 16) & 0xFFu); o[7] = dec1_fp8(w.y >> 24);
#endif
}

// k-major panel layout for MFMA A/B sides:
//   panel p = row>>7 (128 rows), chunk Jg = k>>3 (8 elems), slot = Jg*128 + (row&127)
//   elem addr = p*16384 + slot*8 + (k&7)

// ---------------- weight convert: k-major panels + biascat ----------------
__global__ __launch_bounds__(128) void wcvt_kernel(
    const float* __restrict__ Wq, const float* __restrict__ bq,
    const float* __restrict__ Wk, const float* __restrict__ bk,
    const float* __restrict__ Wv, const float* __restrict__ bv,
    const float* __restrict__ Ws, const float* __restrict__ bs,
    unsigned short* __restrict__ BT, float* __restrict__ biascat)
{
  int id = blockIdx.x;
  int l = id / 1664;
  int n = id - l * 1664;
  int k = threadIdx.x;
  const float* W; const float* bias; int nl, ldb;
  if (n < 512)       { W = Wq + (size_t)l * 65536; bias = bq + (size_t)l * 512; nl = n;        ldb = 512; }
  else if (n < 1024) { W = Wk + (size_t)l * 65536; bias = bk + (size_t)l * 512; nl = n - 512;  ldb = 512; }
  else if (n < 1536) { W = Wv + (size_t)l * 65536; bias = bv + (size_t)l * 512; nl = n - 1024; ldb = 512; }
  else               { W = Ws + (size_t)l * 16384; bias = bs + (size_t)l * 128; nl = n - 1536; ldb = 128; }
  size_t dst = (size_t)l * 212992 + (size_t)(n >> 7) * 16384
             + (size_t)((k >> 3) * 128 + (n & 127)) * 8 + (k & 7);
  BT[dst] = f2bf(W[(size_t)k * ldb + nl]);
  if (k == 0) biascat[(size_t)l * 1664 + n] = bias[nl];
}

// ---------------- lin0 v2: 64 nodes/block, W column in registers ----------
__global__ __launch_bounds__(256) void lin0_kernel(
    const float* __restrict__ x, const float* __restrict__ W,
    const float* __restrict__ b, float* __restrict__ h,
    unsigned short* __restrict__ hb, int N, int inF)
{
  __shared__ float xs[64 * 72];
  const int t = threadIdx.x;
  const int col = t & 127, grp = t >> 7;
  const int n0 = blockIdx.x * 64;
  const int nrows = min(64, N - n0);

  if (inF == 70) {
    const float* xp = x + (size_t)n0 * 70;
    const int r = t >> 2, q = t & 3;
    if (r < nrows) {
      for (int c = q; c < 35; c += 4)
        *(float2*)&xs[r * 72 + c * 2] = *(const float2*)&xp[(size_t)r * 70 + c * 2];
    }
    float w[70];
#pragma unroll
    for (int k = 0; k < 70; k++) w[k] = W[(size_t)k * 128 + col];
    const float bias = b[col];
    __syncthreads();
    for (int i = grp; i < nrows; i += 2) {
      const float* xr = &xs[i * 72];
      float acc = bias;
#pragma unroll
      for (int c = 0; c < 17; c++) {
        f32x4 xv = *(const f32x4*)&xr[c * 4];
        acc = fmaf(xv[0], w[c * 4 + 0], acc);
        acc = fmaf(xv[1], w[c * 4 + 1], acc);
        acc = fmaf(xv[2], w[c * 4 + 2], acc);
        acc = fmaf(xv[3], w[c * 4 + 3], acc);
      }
      acc = fmaf(xr[68], w[68], acc);
      acc = fmaf(xr[69], w[69], acc);
      const int n = n0 + i;
      h[(size_t)n * 128 + col] = acc;
      hb[(size_t)(n >> 7) * 16384 + (size_t)((col >> 3) * 128 + (n & 127)) * 8 + (col & 7)] = f2bf(acc);
    }
  } else {
    const float bias = b[col];
    for (int i = grp; i < nrows; i += 2) {
      const int n = n0 + i;
      float acc = bias;
      for (int k = 0; k < inF; k++) acc += x[(size_t)n * inF + k] * W[(size_t)k * 128 + col];
      h[(size_t)n * 128 + col] = acc;
      hb[(size_t)(n >> 7) * 16384 + (size_t)((col >> 3) * 128 + (n & 127)) * 8 + (col & 7)] = f2bf(acc);
    }
  }
}

// ---------------- MFMA projection GEMM v4 ----------------
// grid = ceil(M/64); block 256 = 4 waves; A half-panel LDS-resident (DMA).
// Single 32 KB full B tile in LDS; next tile prefetched to REGISTERS at the
// top of each nc (issue-early) and committed to LDS after barrier1
// (write-late, T14). fp8 epilogue staged via double-buffered padded LDS;
// dump runs at the top of the next iteration so stores retire under MFMAs.
// 2 barriers/nc, neither drains a just-issued load.
__global__ __launch_bounds__(256) void proj_mfma_kernel(
    const unsigned short* __restrict__ A, const unsigned short* __restrict__ BT,
    const float* __restrict__ bias, int M,
    unsigned char* __restrict__ qo, unsigned char* __restrict__ kv,
    float* __restrict__ hn)
{
  __shared__ unsigned short lsA[8192];        // 16 KB: (Jg*64 + r)*8, Jg=0..15
  __shared__ unsigned short lsB[16384];       // 32 KB: full B tile, slot=Jg*128+n
  __shared__ unsigned int   lsS[2][64 * 35];  // fp8 staging x2, stride 35 words

  const int t = threadIdx.x;
  const int wv = t >> 6, ln = t & 63;
  const int fr = ln & 15, quad = ln >> 4;
  const int mb = blockIdx.x;
  const int row0 = mb * 64;
  const int panel = mb >> 1, half = mb & 1;

  const unsigned short* Ap = A + (size_t)panel * 16384;

  // A half-panel DMA: 1024 x 16B chunks, LDS-linear, coalesced
#pragma unroll
  for (int it = 0; it < 4; it++) {
    const int c = it * 256 + t;
    const int Jg = c >> 6, r = c & 63;
    __builtin_amdgcn_global_load_lds(
        (const __attribute__((address_space(1))) void*)(Ap + (size_t)(Jg * 128 + half * 64 + r) * 8),
        (__attribute__((address_space(3))) void*)((char*)lsA + c * 16), 16, 0, 0);
  }

  short8 breg[8];
  // load B tile 0 into registers (2048 chunks x 16 B = 32 KB)
#pragma unroll
  for (int it = 0; it < 8; it++) {
    const int c = it * 256 + t;
    breg[it] = *(const short8*)(BT + (size_t)c * 8);
  }
  __syncthreads();                            // drains A DMA
#pragma unroll
  for (int it = 0; it < 8; it++) {
    const int c = it * 256 + t;
    *(short8*)((char*)lsB + c * 16) = breg[it];
  }
  __syncthreads();                            // lsB tile 0 visible

  for (int nc = 0; nc < 13; nc++) {
    // 1. issue next B tile loads early (retire under the MFMA phase)
    if (nc < 12) {
      const unsigned short* Bn = BT + (size_t)(nc + 1) * 16384;
#pragma unroll
      for (int it = 0; it < 8; it++) {
        const int c = it * 256 + t;
        breg[it] = *(const short8*)(Bn + (size_t)c * 8);
      }
    }

    // 2. dump previous nc's staged fp8 tile (stores retire under MFMAs)
    if (nc > 0) {
      const int pnc = nc - 1;
      const unsigned int* S = lsS[pnc & 1];
      const int pr = pnc >> 2, ncl = pnc & 3;
#pragma unroll
      for (int it = 0; it < 2; it++) {
        const int idx = it * 256 + t;
        const int r = idx >> 3, g = idx & 7;
        const int row = row0 + r;
        if (row < M) {
          uint4 v;
          v.x = S[r * 35 + g * 4 + 0];
          v.y = S[r * 35 + g * 4 + 1];
          v.z = S[r * 35 + g * 4 + 2];
          v.w = S[r * 35 + g * 4 + 3];
          unsigned char* dst = (pr == 0)
              ? qo + (size_t)row * 512 + ncl * 128 + g * 16
              : kv + (size_t)row * 1024 + (pr == 2 ? 512 : 0) + ncl * 128 + g * 16;
          *(uint4*)dst = v;
        }
      }
    }

    // 3. compute: 4 kb sub-steps, barrier-free from stable lsA/lsB
    f32x4 acc[4][2];
#pragma unroll
    for (int i = 0; i < 4; i++)
#pragma unroll
      for (int j = 0; j < 2; j++) acc[i][j] = (f32x4){0.f, 0.f, 0.f, 0.f};

#pragma unroll
    for (int kb = 0; kb < 4; kb++) {
      short8 af[4], bf[2];
#pragma unroll
      for (int i = 0; i < 4; i++)
        af[i] = *(const short8*)(&lsA[(size_t)((kb * 4 + quad) * 64 + i * 16 + fr) * 8]);
#pragma unroll
      for (int j = 0; j < 2; j++)
        bf[j] = *(const short8*)(&lsB[(size_t)((kb * 4 + quad) * 128 + wv * 32 + j * 16 + fr) * 8]);
#pragma unroll
      for (int i = 0; i < 4; i++)
#pragma unroll
        for (int j = 0; j < 2; j++)
          acc[i][j] = __builtin_amdgcn_mfma_f32_16x16x32_bf16(bf[j], af[i], acc[i][j], 0, 0, 0);
    }

    // 4. epilogue
    const int region = nc >> 2;               // 0=q 1=k 2=v 3=skip
    if (region < 3) {
      unsigned int* S = lsS[nc & 1];
#pragma unroll
      for (int i = 0; i < 4; i++)
#pragma unroll
        for (int j = 0; j < 2; j++) {
          const int colL = wv * 32 + j * 16 + quad * 4;
          const float4 b4 = *(const float4*)(&bias[nc * 128 + colL]);
          f32x4 c = acc[i][j];
          S[(i * 16 + fr) * 35 + (colL >> 2)] =
              pack4_fp8(c[0] + b4.x, c[1] + b4.y, c[2] + b4.z, c[3] + b4.w);
        }
    } else {
      // hn fp32: direct full-line stores
#pragma unroll
      for (int j = 0; j < 2; j++) {
        const int colL = wv * 32 + j * 16 + quad * 4;
        const float4 b4 = *(const float4*)(&bias[nc * 128 + colL]);
#pragma unroll
        for (int i = 0; i < 4; i++) {
          const int row = row0 + i * 16 + fr;
          if (row < M) {
            f32x4 c = acc[i][j];
            *(float4*)(hn + (size_t)row * 128 + colL) =
                make_float4(c[0] + b4.x, c[1] + b4.y, c[2] + b4.z, c[3] + b4.w);
          }
        }
      }
    }

    __syncthreads();   // barrier1: frag reads + dump reads + stage writes drained;
                       // breg loads & dump stores fully covered by phase 3

    // 6. commit next B tile to LDS (overwrites tile just consumed)
    if (nc < 12) {
#pragma unroll
      for (int it = 0; it < 8; it++) {
        const int c = it * 256 + t;
        *(short8*)((char*)lsB + c * 16) = breg[it];
      }
    }
    __syncthreads();   // barrier2: cheap lgkm drain; new tile visible
  }
}

// ---------------- CSR build ----------------
__global__ __launch_bounds__(256) void hist_kernel(
    const int* __restrict__ dst, int* __restrict__ deg, int E)
{
  int e = blockIdx.x * 256 + threadIdx.x;
  if (e < E) atomicAdd(&deg[dst[e]], 1);
}

__global__ __launch_bounds__(256) void scan_block_kernel(
    const int* __restrict__ in, int* __restrict__ out, int* __restrict__ bsums, int N)
{
  __shared__ int sm[256];
  int i = blockIdx.x * 256 + threadIdx.x;
  int v = (i < N) ? in[i] : 0;
  sm[threadIdx.x] = v; __syncthreads();
  for (int off = 1; off < 256; off <<= 1) {
    int t = (threadIdx.x >= off) ? sm[threadIdx.x - off] : 0;
    __syncthreads();
    sm[threadIdx.x] += t;
    __syncthreads();
  }
  if (i < N) out[i] = sm[threadIdx.x] - v;   // exclusive
  if (threadIdx.x == 255 && bsums) bsums[blockIdx.x] = sm[255];
}

__global__ __launch_bounds__(256) void scan_finish_kernel(
    int* __restrict__ row_start, int* __restrict__ cursor,
    const int* __restrict__ bsums_scan, int N, int E)
{
  int i = blockIdx.x * 256 + threadIdx.x;
  if (i < N) {
    int val = row_start[i] + bsums_scan[blockIdx.x];
    row_start[i] = val;
    cursor[i] = val;
  }
  if (i == 0) row_start[N] = E;
}

__global__ __launch_bounds__(256) void scatter_kernel(
    const int* __restrict__ src, const int* __restrict__ dst,
    int* __restrict__ cursor, int* __restrict__ csr_src, int E)
{
  int e = blockIdx.x * 256 + threadIdx.x;
  if (e < E) {
    int pos = atomicAdd(&cursor[dst[e]], 1);
    csr_src[pos] = src[e];
  }
}

// ---------------- fused per-node attention (one wave per dst node) ----------
__global__ __launch_bounds__(256) void node_attn_kernel(
    const unsigned char* __restrict__ q, const unsigned char* __restrict__ kv,
    const int* __restrict__ row_start, const int* __restrict__ csr_src,
    float* __restrict__ hn, unsigned short* __restrict__ hb, int N)
{
  int d = (blockIdx.x * 256 + threadIdx.x) >> 6;
  int lane = threadIdx.x & 63;
  if (d >= N) return;
  int beg = row_start[d], end = row_start[d + 1];

  const float scale = 0.08838834764831845f;  // 1/sqrt(128), folded into q
  const uint2 qw = *(const uint2*)(q + (size_t)d * 512 + lane * 8);
  float qd[8];
  dec8_fp8(qw, qd);
#pragma unroll
  for (int j = 0; j < 8; j++) qd[j] *= scale;

  float num[8] = {0.f,0.f,0.f,0.f,0.f,0.f,0.f,0.f};
  float den = 0.f;

  auto krow = [&](int s) { return *(const uint2*)(kv + (size_t)s * 1024 + lane * 8); };
  auto vrow = [&](int s) { return *(const uint2*)(kv + (size_t)s * 1024 + 512 + lane * 8); };
  auto accum = [&](const uint2& kw, const uint2& vw) {
    float kd[8], vd[8];
    dec8_fp8(kw, kd);
    float p = qd[0] * kd[0] + qd[1] * kd[1] + qd[2] * kd[2] + qd[3] * kd[3]
            + qd[4] * kd[4] + qd[5] * kd[5] + qd[6] * kd[6] + qd[7] * kd[7];
    p += __shfl_xor(p, 1);
    p += __shfl_xor(p, 2);
    p += __shfl_xor(p, 4);
    p += __shfl_xor(p, 8);
    float e = __expf(p);
    den += e;
    dec8_fp8(vw, vd);
#pragma unroll
    for (int j = 0; j < 8; j++) num[j] += e * vd[j];
  };

  if (beg < end) {
    const int last = end - 1;
    int s0 = csr_src[beg];
    int s1 = csr_src[min(beg + 1, last)];
    int s2 = csr_src[min(beg + 2, last)];
    uint2 k0 = krow(s0); uint2 v0 = vrow(s0);
    uint2 k1 = krow(s1); uint2 v1 = vrow(s1);
    uint2 k2 = krow(s2); uint2 v2 = vrow(s2);
    for (int i = beg; i < end; i += 3) {
      int t0 = csr_src[min(i + 3, last)];
      int t1 = csr_src[min(i + 4, last)];
      int t2 = csr_src[min(i + 5, last)];
      uint2 ka = krow(t0); uint2 va = vrow(t0);
      uint2 kb = krow(t1); uint2 vb = vrow(t1);
      uint2 kc = krow(t2); uint2 vc = vrow(t2);
      accum(k0, v0);
      if (i + 1 < end) accum(k1, v1);
      if (i + 2 < end) accum(k2, v2);
      k0 = ka; v0 = va; k1 = kb; v1 = vb; k2 = kc; v2 = vc;
    }
  }

  float inv = (den > 0.f) ? 0.25f / den : 0.f;
#pragma unroll
  for (int j = 0; j < 8; j++) {
    float r = num[j] * inv;
    r += __shfl_xor(r, 16);   // combine 4 heads
    r += __shfl_xor(r, 32);
    num[j] = r;
  }
  if (lane < 16) {
    float* hp = hn + (size_t)d * 128 + lane * 8;
    float4 o0 = *(const float4*)(hp);
    float4 o1 = *(const float4*)(hp + 4);
    o0.x = fmaxf(o0.x + num[0], 0.f);
    o0.y = fmaxf(o0.y + num[1], 0.f);
    o0.z = fmaxf(o0.z + num[2], 0.f);
    o0.w = fmaxf(o0.w + num[3], 0.f);
    o1.x = fmaxf(o1.x + num[4], 0.f);
    o1.y = fmaxf(o1.y + num[5], 0.f);
    o1.z = fmaxf(o1.z + num[6], 0.f);
    o1.w = fmaxf(o1.w + num[7], 0.f);
    *(float4*)(hp) = o0;
    *(float4*)(hp + 4) = o1;
    uint4 hv;
    hv.x = (unsigned int)f2bf(o0.x) | ((unsigned int)f2bf(o0.y) << 16);
    hv.y = (unsigned int)f2bf(o0.z) | ((unsigned int)f2bf(o0.w) << 16);
    hv.z = (unsigned int)f2bf(o1.x) | ((unsigned int)f2bf(o1.y) << 16);
    hv.w = (unsigned int)f2bf(o1.z) | ((unsigned int)f2bf(o1.w) << 16);
    // k-major panel: chunk J = lane, row = d
    *(uint4*)(hb + (size_t)(d >> 7) * 16384 + (size_t)(lane * 128 + (d & 127)) * 8) = hv;
  }
}

// ---------------- pooling: emb[batch[n]] += h[n] (batch sorted) ----------------
__global__ __launch_bounds__(128) void pool_kernel(
    const float* __restrict__ h, const int* __restrict__ batch,
    float* __restrict__ emb, int N)
{
  int d = threadIdx.x;
  int n0 = blockIdx.x * 128;
  int n1 = min(n0 + 128, N);
  float acc = 0.f; int cur = -1;
  for (int n = n0; n < n1; n++) {
    int g = batch[n];
    if (g != cur) {
      if (cur >= 0) atomicAdd(&emb[(size_t)cur * 128 + d], acc);
      cur = g; acc = 0.f;
    }
    acc += h[(size_t)n * 128 + d];
  }
  if (cur >= 0) atomicAdd(&emb[(size_t)cur * 128 + d], acc);
}

// ---------------- final score ----------------
__global__ __launch_bounds__(128) void score_kernel(
    const float* __restrict__ hemb, const float* __restrict__ temb,
    const int* __restrict__ rels,
    const float* __restrict__ wqW, const float* __restrict__ wqb,
    const float* __restrict__ wkW, const float* __restrict__ wkb,
    const float* __restrict__ rel_emb, float* __restrict__ out)
{
  const int b = blockIdx.x, i = threadIdx.x;
  __shared__ float hs[128], ts[128], hnv[128], tnv[128], red[128];
  hs[i] = hemb[(size_t)b * 128 + i];
  ts[i] = temb[(size_t)b * 128 + i];
  __syncthreads();
  float qv = wqb[i], kv = wkb[i];
  for (int k = 0; k < 128; k++) {
    qv += hs[k] * wqW[k * 128 + i];
    kv += ts[k] * wkW[k * 128 + i];
  }
  float inter = tanhf(qv * kv);
  float hx = hs[i] + inter, tx2 = ts[i] + inter;

  red[i] = hx * hx; __syncthreads();
  for (int s = 64; s > 0; s >>= 1) { if (i < s) red[i] += red[i + s]; __syncthreads(); }
  float hnorm = fmaxf(sqrtf(red[0]), 1e-12f);
  __syncthreads();
  red[i] = tx2 * tx2; __syncthreads();
  for (int s = 64; s > 0; s >>= 1) { if (i < s) red[i] += red[i + s]; __syncthreads(); }
  float tnorm = fmaxf(sqrtf(red[0]), 1e-12f);
  __syncthreads();
  hnv[i] = hx / hnorm; tnv[i] = tx2 / tnorm;
  __syncthreads();

  const float* R = rel_emb + (size_t)rels[b] * 16384 + (size_t)i * 128;
  float dot = 0.f, nrm = 0.f;
  for (int j = 0; j < 128; j++) { float r = R[j]; dot += r * tnv[j]; nrm += r * r; }
  float contrib = hnv[i] * dot / fmaxf(sqrtf(nrm), 1e-12f);
  red[i] = contrib; __syncthreads();
  for (int s = 64; s > 0; s >>= 1) { if (i < s) red[i] += red[i + s]; __syncthreads(); }
  if (i == 0) out[b] = red[0];
}

extern "C" void kernel_launch(void* const* d_in, const int* in_sizes, int n_in,
                              void* d_out, int out_size, void* d_ws, size_t ws_size,
                              hipStream_t stream)
{
  const float* h_x     = (const float*)d_in[0];
  const int*   h_ei    = (const int*)d_in[1];
  const int*   h_batch = (const int*)d_in[2];
  const float* t_x     = (const float*)d_in[3];
  const int*   t_ei    = (const int*)d_in[4];
  const int*   t_batch = (const int*)d_in[5];
  const int*   rels    = (const int*)d_in[6];
  const float* lin0_W  = (const float*)d_in[7];
  const float* lin0_b  = (const float*)d_in[8];
  const float* Wq      = (const float*)d_in[9];
  const float* bq      = (const float*)d_in[10];
  const float* Wk      = (const float*)d_in[11];
  const float* bk      = (const float*)d_in[12];
  const float* Wv      = (const float*)d_in[13];
  const float* bv      = (const float*)d_in[14];
  const float* Ws      = (const float*)d_in[15];
  const float* bs      = (const float*)d_in[16];
  const float* wqW     = (const float*)d_in[17];
  const float* wqb     = (const float*)d_in[18];
  const float* wkW     = (const float*)d_in[19];
  const float* wkb     = (const float*)d_in[20];
  const float* rel_emb = (const float*)d_in[21];

  const int N = in_sizes[2];          // 50000
  const int E = in_sizes[1] / 2;      // 400000
  const int G = in_sizes[6];          // 512
  const int inF = in_sizes[7] / 128;  // 70
  const int nPanels = (N + 127) / 128;
  const int nMB = (N + 63) / 64;

  char* ws = (char*)d_ws;
  size_t off = 0;
  auto alloc = [&](size_t bytes) -> void* {
    void* p = ws + off; off += (bytes + 255) & ~(size_t)255; return p;
  };
  float* hA            = (float*)alloc((size_t)N * 128 * 4);
  unsigned short* hbuf = (unsigned short*)alloc((size_t)nPanels * 16384 * 2);
  unsigned char* qb    = (unsigned char*)alloc((size_t)N * 512);
  unsigned char* kvbuf = (unsigned char*)alloc((size_t)N * 1024);
  unsigned short* BT   = (unsigned short*)alloc((size_t)3 * 212992 * 2);
  float* biascat       = (float*)alloc((size_t)3 * 1664 * 4);
  int* deg             = (int*)alloc((size_t)(N + 1) * 4);
  int* row_start       = (int*)alloc((size_t)(N + 1) * 4);
  int* cursor          = (int*)alloc((size_t)(N + 1) * 4);
  int* bsums           = (int*)alloc((size_t)1024 * 4);
  int* bsums_scan      = (int*)alloc((size_t)1024 * 4);
  int* csr_src         = (int*)alloc((size_t)E * 4);
  float* hEmb          = (float*)alloc((size_t)G * 128 * 4);
  float* tEmb          = (float*)alloc((size_t)G * 128 * 4);
  (void)ws_size; (void)n_in; (void)out_size;

  const int nScanBlocks = (N + 255) / 256;

  // Convert weights once per call (shared by both graphs)
  wcvt_kernel<<<3 * 1664, 128, 0, stream>>>(Wq, bq, Wk, bk, Wv, bv, Ws, bs, BT, biascat);

  for (int g = 0; g < 2; g++) {
    const float* x     = g ? t_x : h_x;
    const int*   ei    = g ? t_ei : h_ei;
    const int*   batch = g ? t_batch : h_batch;
    float*       emb   = g ? tEmb : hEmb;
    const int* srcp = ei;
    const int* dstp = ei + E;

    // --- build CSR (edges grouped by dst) ---
    hipMemsetAsync(deg, 0, (size_t)(N + 1) * 4, stream);
    hist_kernel<<<(E + 255) / 256, 256, 0, stream>>>(dstp, deg, E);
    scan_block_kernel<<<nScanBlocks, 256, 0, stream>>>(deg, row_start, bsums, N);
    scan_block_kernel<<<1, 256, 0, stream>>>(bsums, bsums_scan, nullptr, nScanBlocks);
    scan_finish_kernel<<<nScanBlocks, 256, 0, stream>>>(row_start, cursor, bsums_scan, N, E);
    scatter_kernel<<<(E + 255) / 256, 256, 0, stream>>>(srcp, dstp, cursor, csr_src, E);

    lin0_kernel<<<nMB, 256, 0, stream>>>(x, lin0_W, lin0_b, hA, hbuf, N, inF);
    for (int l = 0; l < 3; l++) {
      proj_mfma_kernel<<<nMB, 256, 0, stream>>>(hbuf,
          BT + (size_t)l * 212992, biascat + (size_t)l * 1664, N,
          qb, kvbuf, hA);
      node_attn_kernel<<<(N + 3) / 4, 256, 0, stream>>>(qb, kvbuf,
          row_start, csr_src, hA, hbuf, N);
    }
    hipMemsetAsync(emb, 0, (size_t)G * 128 * 4, stream);
    pool_kernel<<<(N + 127) / 128, 128, 0, stream>>>(hA, batch, emb, N);
  }

  score_kernel<<<G, 128, 0, stream>>>(hEmb, tEmb, rels, wqW, wqb, wkW, wkb,
                                      rel_emb, (float*)d_out);
}

// Round 6
// 1054.187 us; speedup vs baseline: 1.6787x; 1.0112x over previous
//
#include <hip/hip_runtime.h>
#include <math.h>

#define HID 128

typedef __attribute__((ext_vector_type(8))) short short8;
typedef __attribute__((ext_vector_type(4))) float f32x4;
typedef __attribute__((ext_vector_type(2))) float f32x2;

__device__ __forceinline__ float bf2f(unsigned int u16) {
  union { unsigned int i; float f; } x; x.i = u16 << 16; return x.f;
}
__device__ __forceinline__ unsigned short f2bf(float f) {
  union { float f; unsigned int i; } x; x.f = f;
  unsigned int i = x.i;
  unsigned int r = i + 0x7FFFu + ((i >> 16) & 1u);
  return (unsigned short)(r >> 16);
}

// ---- fp8 e4m3 (OCP) helpers -------------------------------------------------
__device__ __forceinline__ unsigned char f2fp8_sw(float f) {
  union { float f; unsigned int u; } v; v.f = f;
  unsigned int s = (v.u >> 24) & 0x80u;
  v.u &= 0x7FFFFFFFu;
  if (v.f != v.f) return (unsigned char)(s | 0x7Fu);
  if (v.f >= 464.f) return (unsigned char)(s | 0x7Eu);          // saturate 448
  if (v.f < 0.0009765625f) return (unsigned char)s;             // < 2^-10 -> 0
  int ebits = (int)(v.u >> 23);
  if (ebits >= 121) {                                           // normal (exp >= -6)
    unsigned int r = v.u + 0x7FFFFu + ((v.u >> 20) & 1u);       // RNE at bit 20
    int E = (int)(r >> 23) - 127 + 7;
    unsigned int m = (r >> 20) & 7u;
    if (E >= 16) return (unsigned char)(s | 0x7Eu);
    return (unsigned char)(s | ((unsigned int)E << 3) | m);
  } else {                                                      // subnormal
    int M = (int)rintf(v.f * 512.f);
    if (M > 8) M = 8;
    return (unsigned char)(s | (unsigned int)M);
  }
}

__device__ __forceinline__ unsigned int pack4_fp8(float a, float b, float c, float d) {
#if __has_builtin(__builtin_amdgcn_cvt_pk_fp8_f32)
  int w = 0;
  w = __builtin_amdgcn_cvt_pk_fp8_f32(a, b, w, false);
  w = __builtin_amdgcn_cvt_pk_fp8_f32(c, d, w, true);
  return (unsigned int)w;
#else
  return (unsigned int)f2fp8_sw(a) | ((unsigned int)f2fp8_sw(b) << 8)
       | ((unsigned int)f2fp8_sw(c) << 16) | ((unsigned int)f2fp8_sw(d) << 24);
#endif
}

#if !__has_builtin(__builtin_amdgcn_cvt_pk_f32_fp8)
__device__ __forceinline__ float dec1_fp8(unsigned int u) {
  unsigned int s = (u & 0x80u) << 24;
  unsigned int em = u & 0x7Fu;
  union { unsigned int i; float f; } t;
  t.i = s | ((em << 20) + 0x3C000000u);
  float sub = (float)(int)(u & 7u) * ((u & 0x80u) ? -0.001953125f : 0.001953125f);
  return (em >= 8u) ? t.f : sub;
}
#endif

__device__ __forceinline__ void dec8_fp8(uint2 w, float* o) {
#if __has_builtin(__builtin_amdgcn_cvt_pk_f32_fp8)
  f32x2 p;
  p = __builtin_amdgcn_cvt_pk_f32_fp8((int)w.x, false); o[0] = p.x; o[1] = p.y;
  p = __builtin_amdgcn_cvt_pk_f32_fp8((int)w.x, true);  o[2] = p.x; o[3] = p.y;
  p = __builtin_amdgcn_cvt_pk_f32_fp8((int)w.y, false); o[4] = p.x; o[5] = p.y;
  p = __builtin_amdgcn_cvt_pk_f32_fp8((int)w.y, true);  o[6] = p.x; o[7] = p.y;
#else
  o[0] = dec1_fp8(w.x & 0xFFu);        o[1] = dec1_fp8((w.x >> 8) & 0xFFu);
  o[2] = dec1_fp8((w.x >> 16) & 0xFFu); o[3] = dec1_fp8(w.x >> 24);
  o[4] = dec1_fp8(w.y & 0xFFu);        o[5] = dec1_fp8((w.y >> 8) & 0xFFu);
  o[6] = dec1_fp8((w.y >> 16) & 0xFFu); o[7] = dec1_fp8(w.y >> 24);
#endif
}

// k-major panel layout for MFMA A/B sides:
//   panel p = row>>7 (128 rows), chunk Jg = k>>3 (8 elems), slot = Jg*128 + (row&127)
//   elem addr = p*16384 + slot*8 + (k&7)

// ---------------- weight convert: k-major panels + biascat ----------------
__global__ __launch_bounds__(128) void wcvt_kernel(
    const float* __restrict__ Wq, const float* __restrict__ bq,
    const float* __restrict__ Wk, const float* __restrict__ bk,
    const float* __restrict__ Wv, const float* __restrict__ bv,
    const float* __restrict__ Ws, const float* __restrict__ bs,
    unsigned short* __restrict__ BT, float* __restrict__ biascat)
{
  int id = blockIdx.x;
  int l = id / 1664;
  int n = id - l * 1664;
  int k = threadIdx.x;
  const float* W; const float* bias; int nl, ldb;
  if (n < 512)       { W = Wq + (size_t)l * 65536; bias = bq + (size_t)l * 512; nl = n;        ldb = 512; }
  else if (n < 1024) { W = Wk + (size_t)l * 65536; bias = bk + (size_t)l * 512; nl = n - 512;  ldb = 512; }
  else if (n < 1536) { W = Wv + (size_t)l * 65536; bias = bv + (size_t)l * 512; nl = n - 1024; ldb = 512; }
  else               { W = Ws + (size_t)l * 16384; bias = bs + (size_t)l * 128; nl = n - 1536; ldb = 128; }
  size_t dst = (size_t)l * 212992 + (size_t)(n >> 7) * 16384
             + (size_t)((k >> 3) * 128 + (n & 127)) * 8 + (k & 7);
  BT[dst] = f2bf(W[(size_t)k * ldb + nl]);
  if (k == 0) biascat[(size_t)l * 1664 + n] = bias[nl];
}

// ---------------- lin0: h0 -> bf16 k-major panels only (fp32 copy was dead) --
__global__ __launch_bounds__(256) void lin0_kernel(
    const float* __restrict__ x, const float* __restrict__ W,
    const float* __restrict__ b,
    unsigned short* __restrict__ hb, int N, int inF)
{
  __shared__ float xs[64 * 72];
  const int t = threadIdx.x;
  const int col = t & 127, grp = t >> 7;
  const int n0 = blockIdx.x * 64;
  const int nrows = min(64, N - n0);

  if (inF == 70) {
    const float* xp = x + (size_t)n0 * 70;
    const int r = t >> 2, q = t & 3;
    if (r < nrows) {
      for (int c = q; c < 35; c += 4)
        *(float2*)&xs[r * 72 + c * 2] = *(const float2*)&xp[(size_t)r * 70 + c * 2];
    }
    float w[70];
#pragma unroll
    for (int k = 0; k < 70; k++) w[k] = W[(size_t)k * 128 + col];
    const float bias = b[col];
    __syncthreads();
    for (int i = grp; i < nrows; i += 2) {
      const float* xr = &xs[i * 72];
      float acc = bias;
#pragma unroll
      for (int c = 0; c < 17; c++) {
        f32x4 xv = *(const f32x4*)&xr[c * 4];
        acc = fmaf(xv[0], w[c * 4 + 0], acc);
        acc = fmaf(xv[1], w[c * 4 + 1], acc);
        acc = fmaf(xv[2], w[c * 4 + 2], acc);
        acc = fmaf(xv[3], w[c * 4 + 3], acc);
      }
      acc = fmaf(xr[68], w[68], acc);
      acc = fmaf(xr[69], w[69], acc);
      const int n = n0 + i;
      hb[(size_t)(n >> 7) * 16384 + (size_t)((col >> 3) * 128 + (n & 127)) * 8 + (col & 7)] = f2bf(acc);
    }
  } else {
    const float bias = b[col];
    for (int i = grp; i < nrows; i += 2) {
      const int n = n0 + i;
      float acc = bias;
      for (int k = 0; k < inF; k++) acc += x[(size_t)n * inF + k] * W[(size_t)k * 128 + col];
      hb[(size_t)(n >> 7) * 16384 + (size_t)((col >> 3) * 128 + (n & 127)) * 8 + (col & 7)] = f2bf(acc);
    }
  }
}

// ---------------- MFMA projection GEMM v5 ----------------
// Same schedule as v4 (T14 reg-staged single B tile, 2 barriers/nc).
// Skip region (nc=12) now written as bf16 rows into sb (half the bytes).
__global__ __launch_bounds__(256) void proj_mfma_kernel(
    const unsigned short* __restrict__ A, const unsigned short* __restrict__ BT,
    const float* __restrict__ bias, int M,
    unsigned char* __restrict__ qo, unsigned char* __restrict__ kv,
    unsigned short* __restrict__ sb)
{
  __shared__ unsigned short lsA[8192];        // 16 KB: (Jg*64 + r)*8, Jg=0..15
  __shared__ unsigned short lsB[16384];       // 32 KB: full B tile, slot=Jg*128+n
  __shared__ unsigned int   lsS[2][64 * 35];  // fp8 staging x2, stride 35 words

  const int t = threadIdx.x;
  const int wv = t >> 6, ln = t & 63;
  const int fr = ln & 15, quad = ln >> 4;
  const int mb = blockIdx.x;
  const int row0 = mb * 64;
  const int panel = mb >> 1, half = mb & 1;

  const unsigned short* Ap = A + (size_t)panel * 16384;

  // A half-panel DMA: 1024 x 16B chunks, LDS-linear, coalesced
#pragma unroll
  for (int it = 0; it < 4; it++) {
    const int c = it * 256 + t;
    const int Jg = c >> 6, r = c & 63;
    __builtin_amdgcn_global_load_lds(
        (const __attribute__((address_space(1))) void*)(Ap + (size_t)(Jg * 128 + half * 64 + r) * 8),
        (__attribute__((address_space(3))) void*)((char*)lsA + c * 16), 16, 0, 0);
  }

  short8 breg[8];
  // load B tile 0 into registers (2048 chunks x 16 B = 32 KB)
#pragma unroll
  for (int it = 0; it < 8; it++) {
    const int c = it * 256 + t;
    breg[it] = *(const short8*)(BT + (size_t)c * 8);
  }
  __syncthreads();                            // drains A DMA
#pragma unroll
  for (int it = 0; it < 8; it++) {
    const int c = it * 256 + t;
    *(short8*)((char*)lsB + c * 16) = breg[it];
  }
  __syncthreads();                            // lsB tile 0 visible

  for (int nc = 0; nc < 13; nc++) {
    // 1. issue next B tile loads early (retire under the MFMA phase)
    if (nc < 12) {
      const unsigned short* Bn = BT + (size_t)(nc + 1) * 16384;
#pragma unroll
      for (int it = 0; it < 8; it++) {
        const int c = it * 256 + t;
        breg[it] = *(const short8*)(Bn + (size_t)c * 8);
      }
    }

    // 2. dump previous nc's staged fp8 tile (stores retire under MFMAs)
    if (nc > 0) {
      const int pnc = nc - 1;
      const unsigned int* S = lsS[pnc & 1];
      const int pr = pnc >> 2, ncl = pnc & 3;
#pragma unroll
      for (int it = 0; it < 2; it++) {
        const int idx = it * 256 + t;
        const int r = idx >> 3, g = idx & 7;
        const int row = row0 + r;
        if (row < M) {
          uint4 v;
          v.x = S[r * 35 + g * 4 + 0];
          v.y = S[r * 35 + g * 4 + 1];
          v.z = S[r * 35 + g * 4 + 2];
          v.w = S[r * 35 + g * 4 + 3];
          unsigned char* dst = (pr == 0)
              ? qo + (size_t)row * 512 + ncl * 128 + g * 16
              : kv + (size_t)row * 1024 + (pr == 2 ? 512 : 0) + ncl * 128 + g * 16;
          *(uint4*)dst = v;
        }
      }
    }

    // 3. compute: 4 kb sub-steps, barrier-free from stable lsA/lsB
    f32x4 acc[4][2];
#pragma unroll
    for (int i = 0; i < 4; i++)
#pragma unroll
      for (int j = 0; j < 2; j++) acc[i][j] = (f32x4){0.f, 0.f, 0.f, 0.f};

#pragma unroll
    for (int kb = 0; kb < 4; kb++) {
      short8 af[4], bf[2];
#pragma unroll
      for (int i = 0; i < 4; i++)
        af[i] = *(const short8*)(&lsA[(size_t)((kb * 4 + quad) * 64 + i * 16 + fr) * 8]);
#pragma unroll
      for (int j = 0; j < 2; j++)
        bf[j] = *(const short8*)(&lsB[(size_t)((kb * 4 + quad) * 128 + wv * 32 + j * 16 + fr) * 8]);
#pragma unroll
      for (int i = 0; i < 4; i++)
#pragma unroll
        for (int j = 0; j < 2; j++)
          acc[i][j] = __builtin_amdgcn_mfma_f32_16x16x32_bf16(bf[j], af[i], acc[i][j], 0, 0, 0);
    }

    // 4. epilogue
    const int region = nc >> 2;               // 0=q 1=k 2=v 3=skip
    if (region < 3) {
      unsigned int* S = lsS[nc & 1];
#pragma unroll
      for (int i = 0; i < 4; i++)
#pragma unroll
        for (int j = 0; j < 2; j++) {
          const int colL = wv * 32 + j * 16 + quad * 4;
          const float4 b4 = *(const float4*)(&bias[nc * 128 + colL]);
          f32x4 c = acc[i][j];
          S[(i * 16 + fr) * 35 + (colL >> 2)] =
              pack4_fp8(c[0] + b4.x, c[1] + b4.y, c[2] + b4.z, c[3] + b4.w);
        }
    } else {
      // skip connection: bf16 rows, 8 B per lane-store
#pragma unroll
      for (int j = 0; j < 2; j++) {
        const int colL = wv * 32 + j * 16 + quad * 4;
        const float4 b4 = *(const float4*)(&bias[nc * 128 + colL]);
#pragma unroll
        for (int i = 0; i < 4; i++) {
          const int row = row0 + i * 16 + fr;
          if (row < M) {
            f32x4 c = acc[i][j];
            uint2 pk;
            pk.x = (unsigned int)f2bf(c[0] + b4.x) | ((unsigned int)f2bf(c[1] + b4.y) << 16);
            pk.y = (unsigned int)f2bf(c[2] + b4.z) | ((unsigned int)f2bf(c[3] + b4.w) << 16);
            *(uint2*)(sb + (size_t)row * 128 + colL) = pk;
          }
        }
      }
    }

    __syncthreads();   // barrier1: frag reads + dump reads + stage writes drained

    // 5. commit next B tile to LDS (overwrites tile just consumed)
    if (nc < 12) {
#pragma unroll
      for (int it = 0; it < 8; it++) {
        const int c = it * 256 + t;
        *(short8*)((char*)lsB + c * 16) = breg[it];
      }
    }
    __syncthreads();   // barrier2: cheap lgkm drain; new tile visible
  }
}

// ---------------- CSR build ----------------
__global__ __launch_bounds__(256) void hist_kernel(
    const int* __restrict__ dst, int* __restrict__ deg, int E)
{
  int e = blockIdx.x * 256 + threadIdx.x;
  if (e < E) atomicAdd(&deg[dst[e]], 1);
}

__global__ __launch_bounds__(256) void scan_block_kernel(
    const int* __restrict__ in, int* __restrict__ out, int* __restrict__ bsums, int N)
{
  __shared__ int sm[256];
  int i = blockIdx.x * 256 + threadIdx.x;
  int v = (i < N) ? in[i] : 0;
  sm[threadIdx.x] = v; __syncthreads();
  for (int off = 1; off < 256; off <<= 1) {
    int t = (threadIdx.x >= off) ? sm[threadIdx.x - off] : 0;
    __syncthreads();
    sm[threadIdx.x] += t;
    __syncthreads();
  }
  if (i < N) out[i] = sm[threadIdx.x] - v;   // exclusive
  if (threadIdx.x == 255 && bsums) bsums[blockIdx.x] = sm[255];
}

__global__ __launch_bounds__(256) void scan_finish_kernel(
    int* __restrict__ row_start, int* __restrict__ cursor,
    const int* __restrict__ bsums_scan, int N, int E)
{
  int i = blockIdx.x * 256 + threadIdx.x;
  if (i < N) {
    int val = row_start[i] + bsums_scan[blockIdx.x];
    row_start[i] = val;
    cursor[i] = val;
  }
  if (i == 0) row_start[N] = E;
}

__global__ __launch_bounds__(256) void scatter_kernel(
    const int* __restrict__ src, const int* __restrict__ dst,
    int* __restrict__ cursor, int* __restrict__ csr_src, int E)
{
  int e = blockIdx.x * 256 + threadIdx.x;
  if (e < E) {
    int pos = atomicAdd(&cursor[dst[e]], 1);
    csr_src[pos] = src[e];
  }
}

// ---------------- fused per-node attention (one wave per dst node) ----------
// skip read from bf16 sb; non-last layers write only hb (bf16 panel);
// last layer writes only fp32 hn for pooling.
__global__ __launch_bounds__(256) void node_attn_kernel(
    const unsigned char* __restrict__ q, const unsigned char* __restrict__ kv,
    const int* __restrict__ row_start, const int* __restrict__ csr_src,
    const unsigned short* __restrict__ sb, float* __restrict__ hn,
    unsigned short* __restrict__ hb, int N, int last)
{
  int d = (blockIdx.x * 256 + threadIdx.x) >> 6;
  int lane = threadIdx.x & 63;
  if (d >= N) return;
  int beg = row_start[d], end = row_start[d + 1];

  const float scale = 0.08838834764831845f;  // 1/sqrt(128), folded into q
  const uint2 qw = *(const uint2*)(q + (size_t)d * 512 + lane * 8);
  float qd[8];
  dec8_fp8(qw, qd);
#pragma unroll
  for (int j = 0; j < 8; j++) qd[j] *= scale;

  float num[8] = {0.f,0.f,0.f,0.f,0.f,0.f,0.f,0.f};
  float den = 0.f;

  auto krow = [&](int s) { return *(const uint2*)(kv + (size_t)s * 1024 + lane * 8); };
  auto vrow = [&](int s) { return *(const uint2*)(kv + (size_t)s * 1024 + 512 + lane * 8); };
  auto accum = [&](const uint2& kw, const uint2& vw) {
    float kd[8], vd[8];
    dec8_fp8(kw, kd);
    float p = qd[0] * kd[0] + qd[1] * kd[1] + qd[2] * kd[2] + qd[3] * kd[3]
            + qd[4] * kd[4] + qd[5] * kd[5] + qd[6] * kd[6] + qd[7] * kd[7];
    p += __shfl_xor(p, 1);
    p += __shfl_xor(p, 2);
    p += __shfl_xor(p, 4);
    p += __shfl_xor(p, 8);
    float e = __expf(p);
    den += e;
    dec8_fp8(vw, vd);
#pragma unroll
    for (int j = 0; j < 8; j++) num[j] += e * vd[j];
  };

  if (beg < end) {
    const int last_e = end - 1;
    int s0 = csr_src[beg];
    int s1 = csr_src[min(beg + 1, last_e)];
    int s2 = csr_src[min(beg + 2, last_e)];
    uint2 k0 = krow(s0); uint2 v0 = vrow(s0);
    uint2 k1 = krow(s1); uint2 v1 = vrow(s1);
    uint2 k2 = krow(s2); uint2 v2 = vrow(s2);
    for (int i = beg; i < end; i += 3) {
      int t0 = csr_src[min(i + 3, last_e)];
      int t1 = csr_src[min(i + 4, last_e)];
      int t2 = csr_src[min(i + 5, last_e)];
      uint2 ka = krow(t0); uint2 va = vrow(t0);
      uint2 kb = krow(t1); uint2 vb = vrow(t1);
      uint2 kc = krow(t2); uint2 vc = vrow(t2);
      accum(k0, v0);
      if (i + 1 < end) accum(k1, v1);
      if (i + 2 < end) accum(k2, v2);
      k0 = ka; v0 = va; k1 = kb; v1 = vb; k2 = kc; v2 = vc;
    }
  }

  float inv = (den > 0.f) ? 0.25f / den : 0.f;
#pragma unroll
  for (int j = 0; j < 8; j++) {
    float r = num[j] * inv;
    r += __shfl_xor(r, 16);   // combine 4 heads
    r += __shfl_xor(r, 32);
    num[j] = r;
  }
  if (lane < 16) {
    const uint4 sv = *(const uint4*)(sb + (size_t)d * 128 + lane * 8);
    float o[8];
    o[0] = fmaxf(bf2f(sv.x & 0xFFFFu) + num[0], 0.f);
    o[1] = fmaxf(bf2f(sv.x >> 16)     + num[1], 0.f);
    o[2] = fmaxf(bf2f(sv.y & 0xFFFFu) + num[2], 0.f);
    o[3] = fmaxf(bf2f(sv.y >> 16)     + num[3], 0.f);
    o[4] = fmaxf(bf2f(sv.z & 0xFFFFu) + num[4], 0.f);
    o[5] = fmaxf(bf2f(sv.z >> 16)     + num[5], 0.f);
    o[6] = fmaxf(bf2f(sv.w & 0xFFFFu) + num[6], 0.f);
    o[7] = fmaxf(bf2f(sv.w >> 16)     + num[7], 0.f);
    if (last) {
      float* hp = hn + (size_t)d * 128 + lane * 8;
      *(float4*)(hp)     = make_float4(o[0], o[1], o[2], o[3]);
      *(float4*)(hp + 4) = make_float4(o[4], o[5], o[6], o[7]);
    } else {
      uint4 hv;
      hv.x = (unsigned int)f2bf(o[0]) | ((unsigned int)f2bf(o[1]) << 16);
      hv.y = (unsigned int)f2bf(o[2]) | ((unsigned int)f2bf(o[3]) << 16);
      hv.z = (unsigned int)f2bf(o[4]) | ((unsigned int)f2bf(o[5]) << 16);
      hv.w = (unsigned int)f2bf(o[6]) | ((unsigned int)f2bf(o[7]) << 16);
      // k-major panel: chunk J = lane, row = d
      *(uint4*)(hb + (size_t)(d >> 7) * 16384 + (size_t)(lane * 128 + (d & 127)) * 8) = hv;
    }
  }
}

// ---------------- pooling: emb[batch[n]] += h[n] (batch sorted) ----------------
__global__ __launch_bounds__(128) void pool_kernel(
    const float* __restrict__ h, const int* __restrict__ batch,
    float* __restrict__ emb, int N)
{
  int d = threadIdx.x;
  int n0 = blockIdx.x * 128;
  int n1 = min(n0 + 128, N);
  float acc = 0.f; int cur = -1;
  for (int n = n0; n < n1; n++) {
    int g = batch[n];
    if (g != cur) {
      if (cur >= 0) atomicAdd(&emb[(size_t)cur * 128 + d], acc);
      cur = g; acc = 0.f;
    }
    acc += h[(size_t)n * 128 + d];
  }
  if (cur >= 0) atomicAdd(&emb[(size_t)cur * 128 + d], acc);
}

// ---------------- final score ----------------
__global__ __launch_bounds__(128) void score_kernel(
    const float* __restrict__ hemb, const float* __restrict__ temb,
    const int* __restrict__ rels,
    const float* __restrict__ wqW, const float* __restrict__ wqb,
    const float* __restrict__ wkW, const float* __restrict__ wkb,
    const float* __restrict__ rel_emb, float* __restrict__ out)
{
  const int b = blockIdx.x, i = threadIdx.x;
  __shared__ float hs[128], ts[128], hnv[128], tnv[128], red[128];
  hs[i] = hemb[(size_t)b * 128 + i];
  ts[i] = temb[(size_t)b * 128 + i];
  __syncthreads();
  float qv = wqb[i], kv = wkb[i];
  for (int k = 0; k < 128; k++) {
    qv += hs[k] * wqW[k * 128 + i];
    kv += ts[k] * wkW[k * 128 + i];
  }
  float inter = tanhf(qv * kv);
  float hx = hs[i] + inter, tx2 = ts[i] + inter;

  red[i] = hx * hx; __syncthreads();
  for (int s = 64; s > 0; s >>= 1) { if (i < s) red[i] += red[i + s]; __syncthreads(); }
  float hnorm = fmaxf(sqrtf(red[0]), 1e-12f);
  __syncthreads();
  red[i] = tx2 * tx2; __syncthreads();
  for (int s = 64; s > 0; s >>= 1) { if (i < s) red[i] += red[i + s]; __syncthreads(); }
  float tnorm = fmaxf(sqrtf(red[0]), 1e-12f);
  __syncthreads();
  hnv[i] = hx / hnorm; tnv[i] = tx2 / tnorm;
  __syncthreads();

  const float* R = rel_emb + (size_t)rels[b] * 16384 + (size_t)i * 128;
  float dot = 0.f, nrm = 0.f;
  for (int j = 0; j < 128; j++) { float r = R[j]; dot += r * tnv[j]; nrm += r * r; }
  float contrib = hnv[i] * dot / fmaxf(sqrtf(nrm), 1e-12f);
  red[i] = contrib; __syncthreads();
  for (int s = 64; s > 0; s >>= 1) { if (i < s) red[i] += red[i + s]; __syncthreads(); }
  if (i == 0) out[b] = red[0];
}

extern "C" void kernel_launch(void* const* d_in, const int* in_sizes, int n_in,
                              void* d_out, int out_size, void* d_ws, size_t ws_size,
                              hipStream_t stream)
{
  const float* h_x     = (const float*)d_in[0];
  const int*   h_ei    = (const int*)d_in[1];
  const int*   h_batch = (const int*)d_in[2];
  const float* t_x     = (const float*)d_in[3];
  const int*   t_ei    = (const int*)d_in[4];
  const int*   t_batch = (const int*)d_in[5];
  const int*   rels    = (const int*)d_in[6];
  const float* lin0_W  = (const float*)d_in[7];
  const float* lin0_b  = (const float*)d_in[8];
  const float* Wq      = (const float*)d_in[9];
  const float* bq      = (const float*)d_in[10];
  const float* Wk      = (const float*)d_in[11];
  const float* bk      = (const float*)d_in[12];
  const float* Wv      = (const float*)d_in[13];
  const float* bv      = (const float*)d_in[14];
  const float* Ws      = (const float*)d_in[15];
  const float* bs      = (const float*)d_in[16];
  const float* wqW     = (const float*)d_in[17];
  const float* wqb     = (const float*)d_in[18];
  const float* wkW     = (const float*)d_in[19];
  const float* wkb     = (const float*)d_in[20];
  const float* rel_emb = (const float*)d_in[21];

  const int N = in_sizes[2];          // 50000
  const int E = in_sizes[1] / 2;      // 400000
  const int G = in_sizes[6];          // 512
  const int inF = in_sizes[7] / 128;  // 70
  const int nPanels = (N + 127) / 128;
  const int nMB = (N + 63) / 64;

  char* ws = (char*)d_ws;
  size_t off = 0;
  auto alloc = [&](size_t bytes) -> void* {
    void* p = ws + off; off += (bytes + 255) & ~(size_t)255; return p;
  };
  float* hA            = (float*)alloc((size_t)N * 128 * 4);
  unsigned short* hbuf = (unsigned short*)alloc((size_t)nPanels * 16384 * 2);
  unsigned short* sb   = (unsigned short*)alloc((size_t)N * 128 * 2);
  unsigned char* qb    = (unsigned char*)alloc((size_t)N * 512);
  unsigned char* kvbuf = (unsigned char*)alloc((size_t)N * 1024);
  unsigned short* BT   = (unsigned short*)alloc((size_t)3 * 212992 * 2);
  float* biascat       = (float*)alloc((size_t)3 * 1664 * 4);
  int* deg             = (int*)alloc((size_t)(N + 1) * 4);
  int* row_start       = (int*)alloc((size_t)(N + 1) * 4);
  int* cursor          = (int*)alloc((size_t)(N + 1) * 4);
  int* bsums           = (int*)alloc((size_t)1024 * 4);
  int* bsums_scan      = (int*)alloc((size_t)1024 * 4);
  int* csr_src         = (int*)alloc((size_t)E * 4);
  float* hEmb          = (float*)alloc((size_t)G * 128 * 4);
  float* tEmb          = (float*)alloc((size_t)G * 128 * 4);
  (void)ws_size; (void)n_in; (void)out_size;

  const int nScanBlocks = (N + 255) / 256;

  // Convert weights once per call (shared by both graphs)
  wcvt_kernel<<<3 * 1664, 128, 0, stream>>>(Wq, bq, Wk, bk, Wv, bv, Ws, bs, BT, biascat);

  for (int g = 0; g < 2; g++) {
    const float* x     = g ? t_x : h_x;
    const int*   ei    = g ? t_ei : h_ei;
    const int*   batch = g ? t_batch : h_batch;
    float*       emb   = g ? tEmb : hEmb;
    const int* srcp = ei;
    const int* dstp = ei + E;

    // --- build CSR (edges grouped by dst) ---
    hipMemsetAsync(deg, 0, (size_t)(N + 1) * 4, stream);
    hist_kernel<<<(E + 255) / 256, 256, 0, stream>>>(dstp, deg, E);
    scan_block_kernel<<<nScanBlocks, 256, 0, stream>>>(deg, row_start, bsums, N);
    scan_block_kernel<<<1, 256, 0, stream>>>(bsums, bsums_scan, nullptr, nScanBlocks);
    scan_finish_kernel<<<nScanBlocks, 256, 0, stream>>>(row_start, cursor, bsums_scan, N, E);
    scatter_kernel<<<(E + 255) / 256, 256, 0, stream>>>(srcp, dstp, cursor, csr_src, E);

    lin0_kernel<<<nMB, 256, 0, stream>>>(x, lin0_W, lin0_b, hbuf, N, inF);
    for (int l = 0; l < 3; l++) {
      proj_mfma_kernel<<<nMB, 256, 0, stream>>>(hbuf,
          BT + (size_t)l * 212992, biascat + (size_t)l * 1664, N,
          qb, kvbuf, sb);
      node_attn_kernel<<<(N + 3) / 4, 256, 0, stream>>>(qb, kvbuf,
          row_start, csr_src, sb, hA, hbuf, N, (l == 2) ? 1 : 0);
    }
    hipMemsetAsync(emb, 0, (size_t)G * 128 * 4, stream);
    pool_kernel<<<(N + 127) / 128, 128, 0, stream>>>(hA, batch, emb, N);
  }

  score_kernel<<<G, 128, 0, stream>>>(hEmb, tEmb, rels, wqW, wqb, wkW, wkb,
                                      rel_emb, (float*)d_out);
}

// Round 7
// 944.965 us; speedup vs baseline: 1.8728x; 1.1156x over previous
//
#include <hip/hip_runtime.h>
#include <math.h>

#define HID 128

typedef __attribute__((ext_vector_type(8))) short short8;
typedef __attribute__((ext_vector_type(4))) float f32x4;
typedef __attribute__((ext_vector_type(2))) float f32x2;

__device__ __forceinline__ float bf2f(unsigned int u16) {
  union { unsigned int i; float f; } x; x.i = u16 << 16; return x.f;
}
__device__ __forceinline__ unsigned short f2bf(float f) {
  union { float f; unsigned int i; } x; x.f = f;
  unsigned int i = x.i;
  unsigned int r = i + 0x7FFFu + ((i >> 16) & 1u);
  return (unsigned short)(r >> 16);
}

// ---- fp8 e4m3 (OCP) helpers -------------------------------------------------
__device__ __forceinline__ unsigned char f2fp8_sw(float f) {
  union { float f; unsigned int u; } v; v.f = f;
  unsigned int s = (v.u >> 24) & 0x80u;
  v.u &= 0x7FFFFFFFu;
  if (v.f != v.f) return (unsigned char)(s | 0x7Fu);
  if (v.f >= 464.f) return (unsigned char)(s | 0x7Eu);          // saturate 448
  if (v.f < 0.0009765625f) return (unsigned char)s;             // < 2^-10 -> 0
  int ebits = (int)(v.u >> 23);
  if (ebits >= 121) {                                           // normal (exp >= -6)
    unsigned int r = v.u + 0x7FFFFu + ((v.u >> 20) & 1u);       // RNE at bit 20
    int E = (int)(r >> 23) - 127 + 7;
    unsigned int m = (r >> 20) & 7u;
    if (E >= 16) return (unsigned char)(s | 0x7Eu);
    return (unsigned char)(s | ((unsigned int)E << 3) | m);
  } else {                                                      // subnormal
    int M = (int)rintf(v.f * 512.f);
    if (M > 8) M = 8;
    return (unsigned char)(s | (unsigned int)M);
  }
}

__device__ __forceinline__ unsigned int pack4_fp8(float a, float b, float c, float d) {
#if __has_builtin(__builtin_amdgcn_cvt_pk_fp8_f32)
  int w = 0;
  w = __builtin_amdgcn_cvt_pk_fp8_f32(a, b, w, false);
  w = __builtin_amdgcn_cvt_pk_fp8_f32(c, d, w, true);
  return (unsigned int)w;
#else
  return (unsigned int)f2fp8_sw(a) | ((unsigned int)f2fp8_sw(b) << 8)
       | ((unsigned int)f2fp8_sw(c) << 16) | ((unsigned int)f2fp8_sw(d) << 24);
#endif
}

#if !__has_builtin(__builtin_amdgcn_cvt_pk_f32_fp8)
__device__ __forceinline__ float dec1_fp8(unsigned int u) {
  unsigned int s = (u & 0x80u) << 24;
  unsigned int em = u & 0x7Fu;
  union { unsigned int i; float f; } t;
  t.i = s | ((em << 20) + 0x3C000000u);
  float sub = (float)(int)(u & 7u) * ((u & 0x80u) ? -0.001953125f : 0.001953125f);
  return (em >= 8u) ? t.f : sub;
}
#endif

__device__ __forceinline__ void dec8_fp8(uint2 w, float* o) {
#if __has_builtin(__builtin_amdgcn_cvt_pk_f32_fp8)
  f32x2 p;
  p = __builtin_amdgcn_cvt_pk_f32_fp8((int)w.x, false); o[0] = p.x; o[1] = p.y;
  p = __builtin_amdgcn_cvt_pk_f32_fp8((int)w.x, true);  o[2] = p.x; o[3] = p.y;
  p = __builtin_amdgcn_cvt_pk_f32_fp8((int)w.y, false); o[4] = p.x; o[5] = p.y;
  p = __builtin_amdgcn_cvt_pk_f32_fp8((int)w.y, true);  o[6] = p.x; o[7] = p.y;
#else
  o[0] = dec1_fp8(w.x & 0xFFu);        o[1] = dec1_fp8((w.x >> 8) & 0xFFu);
  o[2] = dec1_fp8((w.x >> 16) & 0xFFu); o[3] = dec1_fp8(w.x >> 24);
  o[4] = dec1_fp8(w.y & 0xFFu);        o[5] = dec1_fp8((w.y >> 8) & 0xFFu);
  o[6] = dec1_fp8((w.y >> 16) & 0xFFu); o[7] = dec1_fp8(w.y >> 24);
#endif
}

// k-major panel layout for MFMA A/B sides:
//   panel p = row>>7 (128 rows), chunk Jg = k>>3 (8 elems), slot = Jg*128 + (row&127)
//   elem addr = p*16384 + slot*8 + (k&7)

// ---------------- weight convert: k-major panels + biascat ----------------
__global__ __launch_bounds__(128) void wcvt_kernel(
    const float* __restrict__ Wq, const float* __restrict__ bq,
    const float* __restrict__ Wk, const float* __restrict__ bk,
    const float* __restrict__ Wv, const float* __restrict__ bv,
    const float* __restrict__ Ws, const float* __restrict__ bs,
    unsigned short* __restrict__ BT, float* __restrict__ biascat)
{
  int id = blockIdx.x;
  int l = id / 1664;
  int n = id - l * 1664;
  int k = threadIdx.x;
  const float* W; const float* bias; int nl, ldb;
  if (n < 512)       { W = Wq + (size_t)l * 65536; bias = bq + (size_t)l * 512; nl = n;        ldb = 512; }
  else if (n < 1024) { W = Wk + (size_t)l * 65536; bias = bk + (size_t)l * 512; nl = n - 512;  ldb = 512; }
  else if (n < 1536) { W = Wv + (size_t)l * 65536; bias = bv + (size_t)l * 512; nl = n - 1024; ldb = 512; }
  else               { W = Ws + (size_t)l * 16384; bias = bs + (size_t)l * 128; nl = n - 1536; ldb = 128; }
  size_t dst = (size_t)l * 212992 + (size_t)(n >> 7) * 16384
             + (size_t)((k >> 3) * 128 + (n & 127)) * 8 + (k & 7);
  BT[dst] = f2bf(W[(size_t)k * ldb + nl]);
  if (k == 0) biascat[(size_t)l * 1664 + n] = bias[nl];
}

// ---------------- lin0 merged: both graphs, 64 nodes/block --------------------
__global__ __launch_bounds__(256) void lin0_kernel(
    const float* __restrict__ hx, const float* __restrict__ tx,
    const float* __restrict__ W, const float* __restrict__ b,
    unsigned short* __restrict__ hb, int N, int N2, int inF)
{
  __shared__ float xs[64 * 72];
  const int t = threadIdx.x;
  const int col = t & 127, grp = t >> 7;
  const int n0 = blockIdx.x * 64;
  const int nrows = min(64, N2 - n0);

  if (inF == 70) {
    const int r = t >> 2, q = t & 3;
    if (r < nrows) {
      const int gn = n0 + r;
      const float* xp = (gn < N) ? (hx + (size_t)gn * 70) : (tx + (size_t)(gn - N) * 70);
      for (int c = q; c < 35; c += 4)
        *(float2*)&xs[r * 72 + c * 2] = *(const float2*)&xp[c * 2];
    }
    float w[70];
#pragma unroll
    for (int k = 0; k < 70; k++) w[k] = W[(size_t)k * 128 + col];
    const float bias = b[col];
    __syncthreads();
    for (int i = grp; i < nrows; i += 2) {
      const float* xr = &xs[i * 72];
      float acc = bias;
#pragma unroll
      for (int c = 0; c < 17; c++) {
        f32x4 xv = *(const f32x4*)&xr[c * 4];
        acc = fmaf(xv[0], w[c * 4 + 0], acc);
        acc = fmaf(xv[1], w[c * 4 + 1], acc);
        acc = fmaf(xv[2], w[c * 4 + 2], acc);
        acc = fmaf(xv[3], w[c * 4 + 3], acc);
      }
      acc = fmaf(xr[68], w[68], acc);
      acc = fmaf(xr[69], w[69], acc);
      const int n = n0 + i;
      hb[(size_t)(n >> 7) * 16384 + (size_t)((col >> 3) * 128 + (n & 127)) * 8 + (col & 7)] = f2bf(acc);
    }
  } else {
    const float bias = b[col];
    for (int i = grp; i < nrows; i += 2) {
      const int n = n0 + i;
      const float* xp = (n < N) ? (hx + (size_t)n * inF) : (tx + (size_t)(n - N) * inF);
      float acc = bias;
      for (int k = 0; k < inF; k++) acc += xp[k] * W[(size_t)k * 128 + col];
      hb[(size_t)(n >> 7) * 16384 + (size_t)((col >> 3) * 128 + (n & 127)) * 8 + (col & 7)] = f2bf(acc);
    }
  }
}

// ---------------- MFMA projection GEMM (v5 schedule, merged M=2N) ----------
__global__ __launch_bounds__(256) void proj_mfma_kernel(
    const unsigned short* __restrict__ A, const unsigned short* __restrict__ BT,
    const float* __restrict__ bias, int M,
    unsigned char* __restrict__ qo, unsigned char* __restrict__ kv,
    unsigned short* __restrict__ sb)
{
  __shared__ unsigned short lsA[8192];        // 16 KB: (Jg*64 + r)*8, Jg=0..15
  __shared__ unsigned short lsB[16384];       // 32 KB: full B tile, slot=Jg*128+n
  __shared__ unsigned int   lsS[2][64 * 35];  // fp8 staging x2, stride 35 words

  const int t = threadIdx.x;
  const int wv = t >> 6, ln = t & 63;
  const int fr = ln & 15, quad = ln >> 4;
  const int mb = blockIdx.x;
  const int row0 = mb * 64;
  const int panel = mb >> 1, half = mb & 1;

  const unsigned short* Ap = A + (size_t)panel * 16384;

  // A half-panel DMA: 1024 x 16B chunks, LDS-linear, coalesced
#pragma unroll
  for (int it = 0; it < 4; it++) {
    const int c = it * 256 + t;
    const int Jg = c >> 6, r = c & 63;
    __builtin_amdgcn_global_load_lds(
        (const __attribute__((address_space(1))) void*)(Ap + (size_t)(Jg * 128 + half * 64 + r) * 8),
        (__attribute__((address_space(3))) void*)((char*)lsA + c * 16), 16, 0, 0);
  }

  short8 breg[8];
#pragma unroll
  for (int it = 0; it < 8; it++) {
    const int c = it * 256 + t;
    breg[it] = *(const short8*)(BT + (size_t)c * 8);
  }
  __syncthreads();                            // drains A DMA
#pragma unroll
  for (int it = 0; it < 8; it++) {
    const int c = it * 256 + t;
    *(short8*)((char*)lsB + c * 16) = breg[it];
  }
  __syncthreads();                            // lsB tile 0 visible

  for (int nc = 0; nc < 13; nc++) {
    // 1. issue next B tile loads early (retire under the MFMA phase)
    if (nc < 12) {
      const unsigned short* Bn = BT + (size_t)(nc + 1) * 16384;
#pragma unroll
      for (int it = 0; it < 8; it++) {
        const int c = it * 256 + t;
        breg[it] = *(const short8*)(Bn + (size_t)c * 8);
      }
    }

    // 2. dump previous nc's staged fp8 tile (stores retire under MFMAs)
    if (nc > 0) {
      const int pnc = nc - 1;
      const unsigned int* S = lsS[pnc & 1];
      const int pr = pnc >> 2, ncl = pnc & 3;
#pragma unroll
      for (int it = 0; it < 2; it++) {
        const int idx = it * 256 + t;
        const int r = idx >> 3, g = idx & 7;
        const int row = row0 + r;
        if (row < M) {
          uint4 v;
          v.x = S[r * 35 + g * 4 + 0];
          v.y = S[r * 35 + g * 4 + 1];
          v.z = S[r * 35 + g * 4 + 2];
          v.w = S[r * 35 + g * 4 + 3];
          unsigned char* dst = (pr == 0)
              ? qo + (size_t)row * 512 + ncl * 128 + g * 16
              : kv + (size_t)row * 1024 + (pr == 2 ? 512 : 0) + ncl * 128 + g * 16;
          *(uint4*)dst = v;
        }
      }
    }

    // 3. compute: 4 kb sub-steps, barrier-free from stable lsA/lsB
    f32x4 acc[4][2];
#pragma unroll
    for (int i = 0; i < 4; i++)
#pragma unroll
      for (int j = 0; j < 2; j++) acc[i][j] = (f32x4){0.f, 0.f, 0.f, 0.f};

#pragma unroll
    for (int kb = 0; kb < 4; kb++) {
      short8 af[4], bf[2];
#pragma unroll
      for (int i = 0; i < 4; i++)
        af[i] = *(const short8*)(&lsA[(size_t)((kb * 4 + quad) * 64 + i * 16 + fr) * 8]);
#pragma unroll
      for (int j = 0; j < 2; j++)
        bf[j] = *(const short8*)(&lsB[(size_t)((kb * 4 + quad) * 128 + wv * 32 + j * 16 + fr) * 8]);
#pragma unroll
      for (int i = 0; i < 4; i++)
#pragma unroll
        for (int j = 0; j < 2; j++)
          acc[i][j] = __builtin_amdgcn_mfma_f32_16x16x32_bf16(bf[j], af[i], acc[i][j], 0, 0, 0);
    }

    // 4. epilogue
    const int region = nc >> 2;               // 0=q 1=k 2=v 3=skip
    if (region < 3) {
      unsigned int* S = lsS[nc & 1];
#pragma unroll
      for (int i = 0; i < 4; i++)
#pragma unroll
        for (int j = 0; j < 2; j++) {
          const int colL = wv * 32 + j * 16 + quad * 4;
          const float4 b4 = *(const float4*)(&bias[nc * 128 + colL]);
          f32x4 c = acc[i][j];
          S[(i * 16 + fr) * 35 + (colL >> 2)] =
              pack4_fp8(c[0] + b4.x, c[1] + b4.y, c[2] + b4.z, c[3] + b4.w);
        }
    } else {
      // skip connection: bf16 rows
#pragma unroll
      for (int j = 0; j < 2; j++) {
        const int colL = wv * 32 + j * 16 + quad * 4;
        const float4 b4 = *(const float4*)(&bias[nc * 128 + colL]);
#pragma unroll
        for (int i = 0; i < 4; i++) {
          const int row = row0 + i * 16 + fr;
          if (row < M) {
            f32x4 c = acc[i][j];
            uint2 pk;
            pk.x = (unsigned int)f2bf(c[0] + b4.x) | ((unsigned int)f2bf(c[1] + b4.y) << 16);
            pk.y = (unsigned int)f2bf(c[2] + b4.z) | ((unsigned int)f2bf(c[3] + b4.w) << 16);
            *(uint2*)(sb + (size_t)row * 128 + colL) = pk;
          }
        }
      }
    }

    __syncthreads();   // barrier1: frag reads + dump reads + stage writes drained

    // 5. commit next B tile to LDS (overwrites tile just consumed)
    if (nc < 12) {
#pragma unroll
      for (int it = 0; it < 8; it++) {
        const int c = it * 256 + t;
        *(short8*)((char*)lsB + c * 16) = breg[it];
      }
    }
    __syncthreads();   // barrier2: cheap lgkm drain; new tile visible
  }
}

// ---------------- CSR build (merged 2-graph) ----------------
__global__ __launch_bounds__(256) void hist2_kernel(
    const int* __restrict__ hdst, const int* __restrict__ tdst,
    int* __restrict__ deg, int E, int N)
{
  int e = blockIdx.x * 256 + threadIdx.x;
  if (e < 2 * E) {
    int dst = (e < E) ? hdst[e] : (tdst[e - E] + N);
    atomicAdd(&deg[dst], 1);
  }
}

__global__ __launch_bounds__(256) void scan_block_kernel(
    const int* __restrict__ in, int* __restrict__ out, int* __restrict__ bsums, int N)
{
  __shared__ int sm[256];
  int i = blockIdx.x * 256 + threadIdx.x;
  int v = (i < N) ? in[i] : 0;
  sm[threadIdx.x] = v; __syncthreads();
  for (int off = 1; off < 256; off <<= 1) {
    int t = (threadIdx.x >= off) ? sm[threadIdx.x - off] : 0;
    __syncthreads();
    sm[threadIdx.x] += t;
    __syncthreads();
  }
  if (i < N) out[i] = sm[threadIdx.x] - v;   // exclusive
  if (threadIdx.x == 255 && bsums) bsums[blockIdx.x] = sm[255];
}

__global__ __launch_bounds__(512) void scan_block512_kernel(
    const int* __restrict__ in, int* __restrict__ out, int N)
{
  __shared__ int sm[512];
  int i = threadIdx.x;
  int v = (i < N) ? in[i] : 0;
  sm[i] = v; __syncthreads();
  for (int off = 1; off < 512; off <<= 1) {
    int t = (i >= off) ? sm[i - off] : 0;
    __syncthreads();
    sm[i] += t;
    __syncthreads();
  }
  if (i < N) out[i] = sm[i] - v;   // exclusive
}

__global__ __launch_bounds__(256) void scan_finish_kernel(
    int* __restrict__ row_start, int* __restrict__ cursor,
    const int* __restrict__ bsums_scan, int N2, int E2)
{
  int i = blockIdx.x * 256 + threadIdx.x;
  if (i < N2) {
    int val = row_start[i] + bsums_scan[blockIdx.x];
    row_start[i] = val;
    cursor[i] = val;
  }
  if (i == 0) row_start[N2] = E2;
}

__global__ __launch_bounds__(256) void scatter2_kernel(
    const int* __restrict__ hsrc, const int* __restrict__ hdst,
    const int* __restrict__ tsrc, const int* __restrict__ tdst,
    int* __restrict__ cursor, int* __restrict__ csr_src, int E, int N)
{
  int e = blockIdx.x * 256 + threadIdx.x;
  if (e < 2 * E) {
    int src, dst;
    if (e < E) { src = hsrc[e]; dst = hdst[e]; }
    else       { src = tsrc[e - E] + N; dst = tdst[e - E] + N; }
    int pos = atomicAdd(&cursor[dst], 1);
    csr_src[pos] = src;
  }
}

// ---------------- fused per-node attention (one wave per dst node) ----------
// non-last layers: write hb (bf16 k-major panel); last layer: write bf16
// row-major IN PLACE into sb (safe: wave reads then writes only its own row).
__global__ __launch_bounds__(256) void node_attn_kernel(
    const unsigned char* __restrict__ q, const unsigned char* __restrict__ kv,
    const int* __restrict__ row_start, const int* __restrict__ csr_src,
    unsigned short* __restrict__ sb,
    unsigned short* __restrict__ hb, int N2, int last)
{
  int d = (blockIdx.x * 256 + threadIdx.x) >> 6;
  int lane = threadIdx.x & 63;
  if (d >= N2) return;
  int beg = row_start[d], end = row_start[d + 1];

  const float scale = 0.08838834764831845f;  // 1/sqrt(128), folded into q
  const uint2 qw = *(const uint2*)(q + (size_t)d * 512 + lane * 8);
  float qd[8];
  dec8_fp8(qw, qd);
#pragma unroll
  for (int j = 0; j < 8; j++) qd[j] *= scale;

  float num[8] = {0.f,0.f,0.f,0.f,0.f,0.f,0.f,0.f};
  float den = 0.f;

  auto krow = [&](int s) { return *(const uint2*)(kv + (size_t)s * 1024 + lane * 8); };
  auto vrow = [&](int s) { return *(const uint2*)(kv + (size_t)s * 1024 + 512 + lane * 8); };
  auto accum = [&](const uint2& kw, const uint2& vw) {
    float kd[8], vd[8];
    dec8_fp8(kw, kd);
    float p = qd[0] * kd[0] + qd[1] * kd[1] + qd[2] * kd[2] + qd[3] * kd[3]
            + qd[4] * kd[4] + qd[5] * kd[5] + qd[6] * kd[6] + qd[7] * kd[7];
    p += __shfl_xor(p, 1);
    p += __shfl_xor(p, 2);
    p += __shfl_xor(p, 4);
    p += __shfl_xor(p, 8);
    float e = __expf(p);
    den += e;
    dec8_fp8(vw, vd);
#pragma unroll
    for (int j = 0; j < 8; j++) num[j] += e * vd[j];
  };

  if (beg < end) {
    const int last_e = end - 1;
    int s0 = csr_src[beg];
    int s1 = csr_src[min(beg + 1, last_e)];
    int s2 = csr_src[min(beg + 2, last_e)];
    uint2 k0 = krow(s0); uint2 v0 = vrow(s0);
    uint2 k1 = krow(s1); uint2 v1 = vrow(s1);
    uint2 k2 = krow(s2); uint2 v2 = vrow(s2);
    for (int i = beg; i < end; i += 3) {
      int t0 = csr_src[min(i + 3, last_e)];
      int t1 = csr_src[min(i + 4, last_e)];
      int t2 = csr_src[min(i + 5, last_e)];
      uint2 ka = krow(t0); uint2 va = vrow(t0);
      uint2 kb = krow(t1); uint2 vb = vrow(t1);
      uint2 kc = krow(t2); uint2 vc = vrow(t2);
      accum(k0, v0);
      if (i + 1 < end) accum(k1, v1);
      if (i + 2 < end) accum(k2, v2);
      k0 = ka; v0 = va; k1 = kb; v1 = vb; k2 = kc; v2 = vc;
    }
  }

  float inv = (den > 0.f) ? 0.25f / den : 0.f;
#pragma unroll
  for (int j = 0; j < 8; j++) {
    float r = num[j] * inv;
    r += __shfl_xor(r, 16);   // combine 4 heads
    r += __shfl_xor(r, 32);
    num[j] = r;
  }
  if (lane < 16) {
    const uint4 sv = *(const uint4*)(sb + (size_t)d * 128 + lane * 8);
    float o[8];
    o[0] = fmaxf(bf2f(sv.x & 0xFFFFu) + num[0], 0.f);
    o[1] = fmaxf(bf2f(sv.x >> 16)     + num[1], 0.f);
    o[2] = fmaxf(bf2f(sv.y & 0xFFFFu) + num[2], 0.f);
    o[3] = fmaxf(bf2f(sv.y >> 16)     + num[3], 0.f);
    o[4] = fmaxf(bf2f(sv.z & 0xFFFFu) + num[4], 0.f);
    o[5] = fmaxf(bf2f(sv.z >> 16)     + num[5], 0.f);
    o[6] = fmaxf(bf2f(sv.w & 0xFFFFu) + num[6], 0.f);
    o[7] = fmaxf(bf2f(sv.w >> 16)     + num[7], 0.f);
    uint4 hv;
    hv.x = (unsigned int)f2bf(o[0]) | ((unsigned int)f2bf(o[1]) << 16);
    hv.y = (unsigned int)f2bf(o[2]) | ((unsigned int)f2bf(o[3]) << 16);
    hv.z = (unsigned int)f2bf(o[4]) | ((unsigned int)f2bf(o[5]) << 16);
    hv.w = (unsigned int)f2bf(o[6]) | ((unsigned int)f2bf(o[7]) << 16);
    if (last) {
      *(uint4*)(sb + (size_t)d * 128 + lane * 8) = hv;   // in place, own row
    } else {
      // k-major panel: chunk J = lane, row = d
      *(uint4*)(hb + (size_t)(d >> 7) * 16384 + (size_t)(lane * 128 + (d & 127)) * 8) = hv;
    }
  }
}

// ---------------- pooling (merged): emb[g(n)] += h[n], bf16 input ------------
__global__ __launch_bounds__(128) void pool_kernel(
    const unsigned short* __restrict__ sb,
    const int* __restrict__ hbatch, const int* __restrict__ tbatch,
    float* __restrict__ emb, int N, int N2, int G)
{
  int d = threadIdx.x;
  int n0 = blockIdx.x * 128;
  int n1 = min(n0 + 128, N2);
  float acc = 0.f; int cur = -1;
  for (int n = n0; n < n1; n++) {
    int g = (n < N) ? hbatch[n] : (tbatch[n - N] + G);
    if (g != cur) {
      if (cur >= 0) atomicAdd(&emb[(size_t)cur * 128 + d], acc);
      cur = g; acc = 0.f;
    }
    acc += bf2f(sb[(size_t)n * 128 + d]);
  }
  if (cur >= 0) atomicAdd(&emb[(size_t)cur * 128 + d], acc);
}

// ---------------- final score ----------------
__global__ __launch_bounds__(128) void score_kernel(
    const float* __restrict__ hemb, const float* __restrict__ temb,
    const int* __restrict__ rels,
    const float* __restrict__ wqW, const float* __restrict__ wqb,
    const float* __restrict__ wkW, const float* __restrict__ wkb,
    const float* __restrict__ rel_emb, float* __restrict__ out)
{
  const int b = blockIdx.x, i = threadIdx.x;
  __shared__ float hs[128], ts[128], hnv[128], tnv[128], red[128];
  hs[i] = hemb[(size_t)b * 128 + i];
  ts[i] = temb[(size_t)b * 128 + i];
  __syncthreads();
  float qv = wqb[i], kv = wkb[i];
  for (int k = 0; k < 128; k++) {
    qv += hs[k] * wqW[k * 128 + i];
    kv += ts[k] * wkW[k * 128 + i];
  }
  float inter = tanhf(qv * kv);
  float hx = hs[i] + inter, tx2 = ts[i] + inter;

  red[i] = hx * hx; __syncthreads();
  for (int s = 64; s > 0; s >>= 1) { if (i < s) red[i] += red[i + s]; __syncthreads(); }
  float hnorm = fmaxf(sqrtf(red[0]), 1e-12f);
  __syncthreads();
  red[i] = tx2 * tx2; __syncthreads();
  for (int s = 64; s > 0; s >>= 1) { if (i < s) red[i] += red[i + s]; __syncthreads(); }
  float tnorm = fmaxf(sqrtf(red[0]), 1e-12f);
  __syncthreads();
  hnv[i] = hx / hnorm; tnv[i] = tx2 / tnorm;
  __syncthreads();

  const float* R = rel_emb + (size_t)rels[b] * 16384 + (size_t)i * 128;
  float dot = 0.f, nrm = 0.f;
  for (int j = 0; j < 128; j++) { float r = R[j]; dot += r * tnv[j]; nrm += r * r; }
  float contrib = hnv[i] * dot / fmaxf(sqrtf(nrm), 1e-12f);
  red[i] = contrib; __syncthreads();
  for (int s = 64; s > 0; s >>= 1) { if (i < s) red[i] += red[i + s]; __syncthreads(); }
  if (i == 0) out[b] = red[0];
}

extern "C" void kernel_launch(void* const* d_in, const int* in_sizes, int n_in,
                              void* d_out, int out_size, void* d_ws, size_t ws_size,
                              hipStream_t stream)
{
  const float* h_x     = (const float*)d_in[0];
  const int*   h_ei    = (const int*)d_in[1];
  const int*   h_batch = (const int*)d_in[2];
  const float* t_x     = (const float*)d_in[3];
  const int*   t_ei    = (const int*)d_in[4];
  const int*   t_batch = (const int*)d_in[5];
  const int*   rels    = (const int*)d_in[6];
  const float* lin0_W  = (const float*)d_in[7];
  const float* lin0_b  = (const float*)d_in[8];
  const float* Wq      = (const float*)d_in[9];
  const float* bq      = (const float*)d_in[10];
  const float* Wk      = (const float*)d_in[11];
  const float* bk      = (const float*)d_in[12];
  const float* Wv      = (const float*)d_in[13];
  const float* bv      = (const float*)d_in[14];
  const float* Ws      = (const float*)d_in[15];
  const float* bs      = (const float*)d_in[16];
  const float* wqW     = (const float*)d_in[17];
  const float* wqb     = (const float*)d_in[18];
  const float* wkW     = (const float*)d_in[19];
  const float* wkb     = (const float*)d_in[20];
  const float* rel_emb = (const float*)d_in[21];

  const int N = in_sizes[2];          // 50000
  const int E = in_sizes[1] / 2;      // 400000
  const int G = in_sizes[6];          // 512
  const int inF = in_sizes[7] / 128;  // 70
  const int N2 = 2 * N, E2 = 2 * E;
  const int nPanels2 = (N2 + 127) / 128;
  const int nMB2 = (N2 + 63) / 64;

  char* ws = (char*)d_ws;
  size_t off = 0;
  auto alloc = [&](size_t bytes) -> void* {
    void* p = ws + off; off += (bytes + 255) & ~(size_t)255; return p;
  };
  unsigned short* hbuf = (unsigned short*)alloc((size_t)nPanels2 * 16384 * 2);
  unsigned short* sb   = (unsigned short*)alloc((size_t)N2 * 128 * 2);
  unsigned char* qb    = (unsigned char*)alloc((size_t)N2 * 512);
  unsigned char* kvbuf = (unsigned char*)alloc((size_t)N2 * 1024);
  unsigned short* BT   = (unsigned short*)alloc((size_t)3 * 212992 * 2);
  float* biascat       = (float*)alloc((size_t)3 * 1664 * 4);
  int* deg             = (int*)alloc((size_t)(N2 + 1) * 4);
  int* row_start       = (int*)alloc((size_t)(N2 + 1) * 4);
  int* cursor          = (int*)alloc((size_t)(N2 + 1) * 4);
  int* bsums           = (int*)alloc((size_t)1024 * 4);
  int* bsums_scan      = (int*)alloc((size_t)1024 * 4);
  int* csr_src         = (int*)alloc((size_t)E2 * 4);
  float* emb           = (float*)alloc((size_t)2 * G * 128 * 4);
  (void)ws_size; (void)n_in; (void)out_size;

  const int nScanBlocks = (N2 + 255) / 256;   // 391 <= 512

  // Convert weights once (shared by both graphs)
  wcvt_kernel<<<3 * 1664, 128, 0, stream>>>(Wq, bq, Wk, bk, Wv, bv, Ws, bs, BT, biascat);

  // --- merged CSR build (edges grouped by global dst; t nodes offset by N) ---
  hipMemsetAsync(deg, 0, (size_t)(N2 + 1) * 4, stream);
  hist2_kernel<<<(E2 + 255) / 256, 256, 0, stream>>>(h_ei + E, t_ei + E, deg, E, N);
  scan_block_kernel<<<nScanBlocks, 256, 0, stream>>>(deg, row_start, bsums, N2);
  scan_block512_kernel<<<1, 512, 0, stream>>>(bsums, bsums_scan, nScanBlocks);
  scan_finish_kernel<<<nScanBlocks, 256, 0, stream>>>(row_start, cursor, bsums_scan, N2, E2);
  scatter2_kernel<<<(E2 + 255) / 256, 256, 0, stream>>>(h_ei, h_ei + E, t_ei, t_ei + E,
                                                        cursor, csr_src, E, N);

  // --- merged encode ---
  lin0_kernel<<<nMB2, 256, 0, stream>>>(h_x, t_x, lin0_W, lin0_b, hbuf, N, N2, inF);
  for (int l = 0; l < 3; l++) {
    proj_mfma_kernel<<<nMB2, 256, 0, stream>>>(hbuf,
        BT + (size_t)l * 212992, biascat + (size_t)l * 1664, N2,
        qb, kvbuf, sb);
    node_attn_kernel<<<(N2 + 3) / 4, 256, 0, stream>>>(qb, kvbuf,
        row_start, csr_src, sb, hbuf, N2, (l == 2) ? 1 : 0);
  }

  hipMemsetAsync(emb, 0, (size_t)2 * G * 128 * 4, stream);
  pool_kernel<<<(N2 + 127) / 128, 128, 0, stream>>>(sb, h_batch, t_batch, emb, N, N2, G);

  score_kernel<<<G, 128, 0, stream>>>(emb, emb + (size_t)G * 128, rels,
                                      wqW, wqb, wkW, wkb, rel_emb, (float*)d_out);
}

// Round 9
// 941.107 us; speedup vs baseline: 1.8804x; 1.0041x over previous
//
#include <hip/hip_runtime.h>
#include <math.h>

#define HID 128

typedef __attribute__((ext_vector_type(8))) short short8;
typedef __attribute__((ext_vector_type(4))) float f32x4;
typedef __attribute__((ext_vector_type(2))) float f32x2;
typedef __attribute__((ext_vector_type(2))) unsigned int u32x2;
typedef __attribute__((ext_vector_type(4))) unsigned int u32x4;

__device__ __forceinline__ float bf2f(unsigned int u16) {
  union { unsigned int i; float f; } x; x.i = u16 << 16; return x.f;
}
__device__ __forceinline__ unsigned short f2bf(float f) {
  union { float f; unsigned int i; } x; x.f = f;
  unsigned int i = x.i;
  unsigned int r = i + 0x7FFFu + ((i >> 16) & 1u);
  return (unsigned short)(r >> 16);
}

// ---- fp8 e4m3 (OCP) helpers -------------------------------------------------
__device__ __forceinline__ unsigned char f2fp8_sw(float f) {
  union { float f; unsigned int u; } v; v.f = f;
  unsigned int s = (v.u >> 24) & 0x80u;
  v.u &= 0x7FFFFFFFu;
  if (v.f != v.f) return (unsigned char)(s | 0x7Fu);
  if (v.f >= 464.f) return (unsigned char)(s | 0x7Eu);          // saturate 448
  if (v.f < 0.0009765625f) return (unsigned char)s;             // < 2^-10 -> 0
  int ebits = (int)(v.u >> 23);
  if (ebits >= 121) {                                           // normal (exp >= -6)
    unsigned int r = v.u + 0x7FFFFu + ((v.u >> 20) & 1u);       // RNE at bit 20
    int E = (int)(r >> 23) - 127 + 7;
    unsigned int m = (r >> 20) & 7u;
    if (E >= 16) return (unsigned char)(s | 0x7Eu);
    return (unsigned char)(s | ((unsigned int)E << 3) | m);
  } else {                                                      // subnormal
    int M = (int)rintf(v.f * 512.f);
    if (M > 8) M = 8;
    return (unsigned char)(s | (unsigned int)M);
  }
}

__device__ __forceinline__ unsigned int pack4_fp8(float a, float b, float c, float d) {
#if __has_builtin(__builtin_amdgcn_cvt_pk_fp8_f32)
  int w = 0;
  w = __builtin_amdgcn_cvt_pk_fp8_f32(a, b, w, false);
  w = __builtin_amdgcn_cvt_pk_fp8_f32(c, d, w, true);
  return (unsigned int)w;
#else
  return (unsigned int)f2fp8_sw(a) | ((unsigned int)f2fp8_sw(b) << 8)
       | ((unsigned int)f2fp8_sw(c) << 16) | ((unsigned int)f2fp8_sw(d) << 24);
#endif
}

#if !__has_builtin(__builtin_amdgcn_cvt_pk_f32_fp8)
__device__ __forceinline__ float dec1_fp8(unsigned int u) {
  unsigned int s = (u & 0x80u) << 24;
  unsigned int em = u & 0x7Fu;
  union { unsigned int i; float f; } t;
  t.i = s | ((em << 20) + 0x3C000000u);
  float sub = (float)(int)(u & 7u) * ((u & 0x80u) ? -0.001953125f : 0.001953125f);
  return (em >= 8u) ? t.f : sub;
}
#endif

__device__ __forceinline__ void dec8_fp8(unsigned int wx, unsigned int wy, float* o) {
#if __has_builtin(__builtin_amdgcn_cvt_pk_f32_fp8)
  f32x2 p;
  p = __builtin_amdgcn_cvt_pk_f32_fp8((int)wx, false); o[0] = p.x; o[1] = p.y;
  p = __builtin_amdgcn_cvt_pk_f32_fp8((int)wx, true);  o[2] = p.x; o[3] = p.y;
  p = __builtin_amdgcn_cvt_pk_f32_fp8((int)wy, false); o[4] = p.x; o[5] = p.y;
  p = __builtin_amdgcn_cvt_pk_f32_fp8((int)wy, true);  o[6] = p.x; o[7] = p.y;
#else
  o[0] = dec1_fp8(wx & 0xFFu);        o[1] = dec1_fp8((wx >> 8) & 0xFFu);
  o[2] = dec1_fp8((wx >> 16) & 0xFFu); o[3] = dec1_fp8(wx >> 24);
  o[4] = dec1_fp8(wy & 0xFFu);        o[5] = dec1_fp8((wy >> 8) & 0xFFu);
  o[6] = dec1_fp8((wy >> 16) & 0xFFu); o[7] = dec1_fp8(wy >> 24);
#endif
}

// k-major panel layout for MFMA A/B sides:
//   panel p = row>>7 (128 rows), chunk Jg = k>>3 (8 elems), slot = Jg*128 + (row&127)
//   elem addr = p*16384 + slot*8 + (k&7)

// ---------------- weight convert: k-major panels + biascat ----------------
__global__ __launch_bounds__(128) void wcvt_kernel(
    const float* __restrict__ Wq, const float* __restrict__ bq,
    const float* __restrict__ Wk, const float* __restrict__ bk,
    const float* __restrict__ Wv, const float* __restrict__ bv,
    const float* __restrict__ Ws, const float* __restrict__ bs,
    unsigned short* __restrict__ BT, float* __restrict__ biascat)
{
  int id = blockIdx.x;
  int l = id / 1664;
  int n = id - l * 1664;
  int k = threadIdx.x;
  const float* W; const float* bias; int nl, ldb;
  if (n < 512)       { W = Wq + (size_t)l * 65536; bias = bq + (size_t)l * 512; nl = n;        ldb = 512; }
  else if (n < 1024) { W = Wk + (size_t)l * 65536; bias = bk + (size_t)l * 512; nl = n - 512;  ldb = 512; }
  else if (n < 1536) { W = Wv + (size_t)l * 65536; bias = bv + (size_t)l * 512; nl = n - 1024; ldb = 512; }
  else               { W = Ws + (size_t)l * 16384; bias = bs + (size_t)l * 128; nl = n - 1536; ldb = 128; }
  size_t dst = (size_t)l * 212992 + (size_t)(n >> 7) * 16384
             + (size_t)((k >> 3) * 128 + (n & 127)) * 8 + (k & 7);
  BT[dst] = f2bf(W[(size_t)k * ldb + nl]);
  if (k == 0) biascat[(size_t)l * 1664 + n] = bias[nl];
}

// ---------------- lin0 merged: both graphs, 64 nodes/block --------------------
__global__ __launch_bounds__(256) void lin0_kernel(
    const float* __restrict__ hx, const float* __restrict__ tx,
    const float* __restrict__ W, const float* __restrict__ b,
    unsigned short* __restrict__ hb, int N, int N2, int inF)
{
  __shared__ float xs[64 * 72];
  const int t = threadIdx.x;
  const int col = t & 127, grp = t >> 7;
  const int n0 = blockIdx.x * 64;
  const int nrows = min(64, N2 - n0);

  if (inF == 70) {
    const int r = t >> 2, q = t & 3;
    if (r < nrows) {
      const int gn = n0 + r;
      const float* xp = (gn < N) ? (hx + (size_t)gn * 70) : (tx + (size_t)(gn - N) * 70);
      for (int c = q; c < 35; c += 4)
        *(float2*)&xs[r * 72 + c * 2] = *(const float2*)&xp[c * 2];
    }
    float w[70];
#pragma unroll
    for (int k = 0; k < 70; k++) w[k] = W[(size_t)k * 128 + col];
    const float bias = b[col];
    __syncthreads();
    for (int i = grp; i < nrows; i += 2) {
      const float* xr = &xs[i * 72];
      float acc = bias;
#pragma unroll
      for (int c = 0; c < 17; c++) {
        f32x4 xv = *(const f32x4*)&xr[c * 4];
        acc = fmaf(xv[0], w[c * 4 + 0], acc);
        acc = fmaf(xv[1], w[c * 4 + 1], acc);
        acc = fmaf(xv[2], w[c * 4 + 2], acc);
        acc = fmaf(xv[3], w[c * 4 + 3], acc);
      }
      acc = fmaf(xr[68], w[68], acc);
      acc = fmaf(xr[69], w[69], acc);
      const int n = n0 + i;
      hb[(size_t)(n >> 7) * 16384 + (size_t)((col >> 3) * 128 + (n & 127)) * 8 + (col & 7)] = f2bf(acc);
    }
  } else {
    const float bias = b[col];
    for (int i = grp; i < nrows; i += 2) {
      const int n = n0 + i;
      const float* xp = (n < N) ? (hx + (size_t)n * inF) : (tx + (size_t)(n - N) * inF);
      float acc = bias;
      for (int k = 0; k < inF; k++) acc += xp[k] * W[(size_t)k * 128 + col];
      hb[(size_t)(n >> 7) * 16384 + (size_t)((col >> 3) * 128 + (n & 127)) * 8 + (col & 7)] = f2bf(acc);
    }
  }
}

// ---------------- MFMA projection GEMM (v5 schedule, merged M=2N) ----------
// q-region dump uses NON-TEMPORAL stores: q is read exactly once downstream,
// keep it out of L3 so the kv gather working set stays resident.
__global__ __launch_bounds__(256) void proj_mfma_kernel(
    const unsigned short* __restrict__ A, const unsigned short* __restrict__ BT,
    const float* __restrict__ bias, int M,
    unsigned char* __restrict__ qo, unsigned char* __restrict__ kv,
    unsigned short* __restrict__ sb)
{
  __shared__ unsigned short lsA[8192];        // 16 KB: (Jg*64 + r)*8, Jg=0..15
  __shared__ unsigned short lsB[16384];       // 32 KB: full B tile, slot=Jg*128+n
  __shared__ unsigned int   lsS[2][64 * 35];  // fp8 staging x2, stride 35 words

  const int t = threadIdx.x;
  const int wv = t >> 6, ln = t & 63;
  const int fr = ln & 15, quad = ln >> 4;
  const int mb = blockIdx.x;
  const int row0 = mb * 64;
  const int panel = mb >> 1, half = mb & 1;

  const unsigned short* Ap = A + (size_t)panel * 16384;

  // A half-panel DMA: 1024 x 16B chunks, LDS-linear, coalesced
#pragma unroll
  for (int it = 0; it < 4; it++) {
    const int c = it * 256 + t;
    const int Jg = c >> 6, r = c & 63;
    __builtin_amdgcn_global_load_lds(
        (const __attribute__((address_space(1))) void*)(Ap + (size_t)(Jg * 128 + half * 64 + r) * 8),
        (__attribute__((address_space(3))) void*)((char*)lsA + c * 16), 16, 0, 0);
  }

  short8 breg[8];
#pragma unroll
  for (int it = 0; it < 8; it++) {
    const int c = it * 256 + t;
    breg[it] = *(const short8*)(BT + (size_t)c * 8);
  }
  __syncthreads();                            // drains A DMA
#pragma unroll
  for (int it = 0; it < 8; it++) {
    const int c = it * 256 + t;
    *(short8*)((char*)lsB + c * 16) = breg[it];
  }
  __syncthreads();                            // lsB tile 0 visible

  for (int nc = 0; nc < 13; nc++) {
    // 1. issue next B tile loads early (retire under the MFMA phase)
    if (nc < 12) {
      const unsigned short* Bn = BT + (size_t)(nc + 1) * 16384;
#pragma unroll
      for (int it = 0; it < 8; it++) {
        const int c = it * 256 + t;
        breg[it] = *(const short8*)(Bn + (size_t)c * 8);
      }
    }

    // 2. dump previous nc's staged fp8 tile (stores retire under MFMAs)
    if (nc > 0) {
      const int pnc = nc - 1;
      const unsigned int* S = lsS[pnc & 1];
      const int pr = pnc >> 2, ncl = pnc & 3;
#pragma unroll
      for (int it = 0; it < 2; it++) {
        const int idx = it * 256 + t;
        const int r = idx >> 3, g = idx & 7;
        const int row = row0 + r;
        if (row < M) {
          u32x4 v;
          v.x = S[r * 35 + g * 4 + 0];
          v.y = S[r * 35 + g * 4 + 1];
          v.z = S[r * 35 + g * 4 + 2];
          v.w = S[r * 35 + g * 4 + 3];
          if (pr == 0) {
            __builtin_nontemporal_store(v,
                (u32x4*)(qo + (size_t)row * 512 + ncl * 128 + g * 16));
          } else {
            *(u32x4*)(kv + (size_t)row * 1024 + (pr == 2 ? 512 : 0) + ncl * 128 + g * 16) = v;
          }
        }
      }
    }

    // 3. compute: 4 kb sub-steps, barrier-free from stable lsA/lsB
    f32x4 acc[4][2];
#pragma unroll
    for (int i = 0; i < 4; i++)
#pragma unroll
      for (int j = 0; j < 2; j++) acc[i][j] = (f32x4){0.f, 0.f, 0.f, 0.f};

#pragma unroll
    for (int kb = 0; kb < 4; kb++) {
      short8 af[4], bf[2];
#pragma unroll
      for (int i = 0; i < 4; i++)
        af[i] = *(const short8*)(&lsA[(size_t)((kb * 4 + quad) * 64 + i * 16 + fr) * 8]);
#pragma unroll
      for (int j = 0; j < 2; j++)
        bf[j] = *(const short8*)(&lsB[(size_t)((kb * 4 + quad) * 128 + wv * 32 + j * 16 + fr) * 8]);
#pragma unroll
      for (int i = 0; i < 4; i++)
#pragma unroll
        for (int j = 0; j < 2; j++)
          acc[i][j] = __builtin_amdgcn_mfma_f32_16x16x32_bf16(bf[j], af[i], acc[i][j], 0, 0, 0);
    }

    // 4. epilogue
    const int region = nc >> 2;               // 0=q 1=k 2=v 3=skip
    if (region < 3) {
      unsigned int* S = lsS[nc & 1];
#pragma unroll
      for (int i = 0; i < 4; i++)
#pragma unroll
        for (int j = 0; j < 2; j++) {
          const int colL = wv * 32 + j * 16 + quad * 4;
          const float4 b4 = *(const float4*)(&bias[nc * 128 + colL]);
          f32x4 c = acc[i][j];
          S[(i * 16 + fr) * 35 + (colL >> 2)] =
              pack4_fp8(c[0] + b4.x, c[1] + b4.y, c[2] + b4.z, c[3] + b4.w);
        }
    } else {
      // skip connection: bf16 rows
#pragma unroll
      for (int j = 0; j < 2; j++) {
        const int colL = wv * 32 + j * 16 + quad * 4;
        const float4 b4 = *(const float4*)(&bias[nc * 128 + colL]);
#pragma unroll
        for (int i = 0; i < 4; i++) {
          const int row = row0 + i * 16 + fr;
          if (row < M) {
            f32x4 c = acc[i][j];
            uint2 pk;
            pk.x = (unsigned int)f2bf(c[0] + b4.x) | ((unsigned int)f2bf(c[1] + b4.y) << 16);
            pk.y = (unsigned int)f2bf(c[2] + b4.z) | ((unsigned int)f2bf(c[3] + b4.w) << 16);
            *(uint2*)(sb + (size_t)row * 128 + colL) = pk;
          }
        }
      }
    }

    __syncthreads();   // barrier1: frag reads + dump reads + stage writes drained

    // 5. commit next B tile to LDS (overwrites tile just consumed)
    if (nc < 12) {
#pragma unroll
      for (int it = 0; it < 8; it++) {
        const int c = it * 256 + t;
        *(short8*)((char*)lsB + c * 16) = breg[it];
      }
    }
    __syncthreads();   // barrier2: cheap lgkm drain; new tile visible
  }
}

// ---------------- CSR build (merged 2-graph) ----------------
__global__ __launch_bounds__(256) void hist2_kernel(
    const int* __restrict__ hdst, const int* __restrict__ tdst,
    int* __restrict__ deg, int E, int N)
{
  int e = blockIdx.x * 256 + threadIdx.x;
  if (e < 2 * E) {
    int dst = (e < E) ? hdst[e] : (tdst[e - E] + N);
    atomicAdd(&deg[dst], 1);
  }
}

__global__ __launch_bounds__(256) void scan_block_kernel(
    const int* __restrict__ in, int* __restrict__ out, int* __restrict__ bsums, int N)
{
  __shared__ int sm[256];
  int i = blockIdx.x * 256 + threadIdx.x;
  int v = (i < N) ? in[i] : 0;
  sm[threadIdx.x] = v; __syncthreads();
  for (int off = 1; off < 256; off <<= 1) {
    int t = (threadIdx.x >= off) ? sm[threadIdx.x - off] : 0;
    __syncthreads();
    sm[threadIdx.x] += t;
    __syncthreads();
  }
  if (i < N) out[i] = sm[threadIdx.x] - v;   // exclusive
  if (threadIdx.x == 255 && bsums) bsums[blockIdx.x] = sm[255];
}

__global__ __launch_bounds__(512) void scan_block512_kernel(
    const int* __restrict__ in, int* __restrict__ out, int N)
{
  __shared__ int sm[512];
  int i = threadIdx.x;
  int v = (i < N) ? in[i] : 0;
  sm[i] = v; __syncthreads();
  for (int off = 1; off < 512; off <<= 1) {
    int t = (i >= off) ? sm[i - off] : 0;
    __syncthreads();
    sm[i] += t;
    __syncthreads();
  }
  if (i < N) out[i] = sm[i] - v;   // exclusive
}

__global__ __launch_bounds__(256) void scan_finish_kernel(
    int* __restrict__ row_start, int* __restrict__ cursor,
    const int* __restrict__ bsums_scan, int N2, int E2)
{
  int i = blockIdx.x * 256 + threadIdx.x;
  if (i < N2) {
    int val = row_start[i] + bsums_scan[blockIdx.x];
    row_start[i] = val;
    cursor[i] = val;
  }
  if (i == 0) row_start[N2] = E2;
}

// csr stores PRE-SCALED byte offsets (src * 1024) for the kv gather.
__global__ __launch_bounds__(256) void scatter2_kernel(
    const int* __restrict__ hsrc, const int* __restrict__ hdst,
    const int* __restrict__ tsrc, const int* __restrict__ tdst,
    int* __restrict__ cursor, int* __restrict__ csr_off, int E, int N)
{
  int e = blockIdx.x * 256 + threadIdx.x;
  if (e < 2 * E) {
    int src, dst;
    if (e < E) { src = hsrc[e]; dst = hdst[e]; }
    else       { src = tsrc[e - E] + N; dst = tdst[e - E] + N; }
    int pos = atomicAdd(&cursor[dst], 1);
    csr_off[pos] = src << 10;               // byte offset into kv
  }
}

// ---------------- fused per-node attention (one wave per dst node) ----------
// q loaded NON-TEMPORALLY (read-once stream, keep L3 for kv).
__global__ __launch_bounds__(256) void node_attn_kernel(
    const unsigned char* __restrict__ q, const unsigned char* __restrict__ kv,
    const int* __restrict__ row_start, const int* __restrict__ csr_off,
    unsigned short* __restrict__ sb,
    unsigned short* __restrict__ hb, int N2, int last)
{
  int d = (blockIdx.x * 256 + threadIdx.x) >> 6;
  int lane = threadIdx.x & 63;
  if (d >= N2) return;
  int beg = row_start[d], end = row_start[d + 1];
  const int laneB = lane * 8;

  const float scale = 0.08838834764831845f;  // 1/sqrt(128), folded into q
  const u32x2 qw = __builtin_nontemporal_load(
      (const u32x2*)(q + (size_t)d * 512 + laneB));
  float qd[8];
  dec8_fp8(qw.x, qw.y, qd);
#pragma unroll
  for (int j = 0; j < 8; j++) qd[j] *= scale;

  float num[8] = {0.f,0.f,0.f,0.f,0.f,0.f,0.f,0.f};
  float den = 0.f;

  auto krow = [&](int off) { return *(const u32x2*)(kv + (size_t)off + laneB); };
  auto vrow = [&](int off) { return *(const u32x2*)(kv + (size_t)off + 512 + laneB); };
  auto accum = [&](const u32x2& kw, const u32x2& vw) {
    float kd[8], vd[8];
    dec8_fp8(kw.x, kw.y, kd);
    float p = qd[0] * kd[0] + qd[1] * kd[1] + qd[2] * kd[2] + qd[3] * kd[3]
            + qd[4] * kd[4] + qd[5] * kd[5] + qd[6] * kd[6] + qd[7] * kd[7];
    p += __shfl_xor(p, 1);
    p += __shfl_xor(p, 2);
    p += __shfl_xor(p, 4);
    p += __shfl_xor(p, 8);
    float e = __expf(p);
    den += e;
    dec8_fp8(vw.x, vw.y, vd);
#pragma unroll
    for (int j = 0; j < 8; j++) num[j] += e * vd[j];
  };

  if (beg < end) {
    const int last_e = end - 1;
    int s0 = csr_off[beg];
    int s1 = csr_off[min(beg + 1, last_e)];
    int s2 = csr_off[min(beg + 2, last_e)];
    u32x2 k0 = krow(s0); u32x2 v0 = vrow(s0);
    u32x2 k1 = krow(s1); u32x2 v1 = vrow(s1);
    u32x2 k2 = krow(s2); u32x2 v2 = vrow(s2);
    for (int i = beg; i < end; i += 3) {
      int t0 = csr_off[min(i + 3, last_e)];
      int t1 = csr_off[min(i + 4, last_e)];
      int t2 = csr_off[min(i + 5, last_e)];
      u32x2 ka = krow(t0); u32x2 va = vrow(t0);
      u32x2 kb = krow(t1); u32x2 vb = vrow(t1);
      u32x2 kc = krow(t2); u32x2 vc = vrow(t2);
      accum(k0, v0);
      if (i + 1 < end) accum(k1, v1);
      if (i + 2 < end) accum(k2, v2);
      k0 = ka; v0 = va; k1 = kb; v1 = vb; k2 = kc; v2 = vc;
    }
  }

  float inv = (den > 0.f) ? 0.25f / den : 0.f;
#pragma unroll
  for (int j = 0; j < 8; j++) {
    float r = num[j] * inv;
    r += __shfl_xor(r, 16);   // combine 4 heads
    r += __shfl_xor(r, 32);
    num[j] = r;
  }
  if (lane < 16) {
    const uint4 sv = *(const uint4*)(sb + (size_t)d * 128 + lane * 8);
    float o[8];
    o[0] = fmaxf(bf2f(sv.x & 0xFFFFu) + num[0], 0.f);
    o[1] = fmaxf(bf2f(sv.x >> 16)     + num[1], 0.f);
    o[2] = fmaxf(bf2f(sv.y & 0xFFFFu) + num[2], 0.f);
    o[3] = fmaxf(bf2f(sv.y >> 16)     + num[3], 0.f);
    o[4] = fmaxf(bf2f(sv.z & 0xFFFFu) + num[4], 0.f);
    o[5] = fmaxf(bf2f(sv.z >> 16)     + num[5], 0.f);
    o[6] = fmaxf(bf2f(sv.w & 0xFFFFu) + num[6], 0.f);
    o[7] = fmaxf(bf2f(sv.w >> 16)     + num[7], 0.f);
    uint4 hv;
    hv.x = (unsigned int)f2bf(o[0]) | ((unsigned int)f2bf(o[1]) << 16);
    hv.y = (unsigned int)f2bf(o[2]) | ((unsigned int)f2bf(o[3]) << 16);
    hv.z = (unsigned int)f2bf(o[4]) | ((unsigned int)f2bf(o[5]) << 16);
    hv.w = (unsigned int)f2bf(o[6]) | ((unsigned int)f2bf(o[7]) << 16);
    if (last) {
      *(uint4*)(sb + (size_t)d * 128 + lane * 8) = hv;   // in place, own row
    } else {
      // k-major panel: chunk J = lane, row = d
      *(uint4*)(hb + (size_t)(d >> 7) * 16384 + (size_t)(lane * 128 + (d & 127)) * 8) = hv;
    }
  }
}

// ---------------- pooling (merged): emb[g(n)] += h[n], bf16 input ------------
__global__ __launch_bounds__(128) void pool_kernel(
    const unsigned short* __restrict__ sb,
    const int* __restrict__ hbatch, const int* __restrict__ tbatch,
    float* __restrict__ emb, int N, int N2, int G)
{
  int d = threadIdx.x;
  int n0 = blockIdx.x * 128;
  int n1 = min(n0 + 128, N2);
  float acc = 0.f; int cur = -1;
  for (int n = n0; n < n1; n++) {
    int g = (n < N) ? hbatch[n] : (tbatch[n - N] + G);
    if (g != cur) {
      if (cur >= 0) atomicAdd(&emb[(size_t)cur * 128 + d], acc);
      cur = g; acc = 0.f;
    }
    acc += bf2f(sb[(size_t)n * 128 + d]);
  }
  if (cur >= 0) atomicAdd(&emb[(size_t)cur * 128 + d], acc);
}

// ---------------- final score ----------------
__global__ __launch_bounds__(128) void score_kernel(
    const float* __restrict__ hemb, const float* __restrict__ temb,
    const int* __restrict__ rels,
    const float* __restrict__ wqW, const float* __restrict__ wqb,
    const float* __restrict__ wkW, const float* __restrict__ wkb,
    const float* __restrict__ rel_emb, float* __restrict__ out)
{
  const int b = blockIdx.x, i = threadIdx.x;
  __shared__ float hs[128], ts[128], hnv[128], tnv[128], red[128];
  hs[i] = hemb[(size_t)b * 128 + i];
  ts[i] = temb[(size_t)b * 128 + i];
  __syncthreads();
  float qv = wqb[i], kv = wkb[i];
  for (int k = 0; k < 128; k++) {
    qv += hs[k] * wqW[k * 128 + i];
    kv += ts[k] * wkW[k * 128 + i];
  }
  float inter = tanhf(qv * kv);
  float hx = hs[i] + inter, tx2 = ts[i] + inter;

  red[i] = hx * hx; __syncthreads();
  for (int s = 64; s > 0; s >>= 1) { if (i < s) red[i] += red[i + s]; __syncthreads(); }
  float hnorm = fmaxf(sqrtf(red[0]), 1e-12f);
  __syncthreads();
  red[i] = tx2 * tx2; __syncthreads();
  for (int s = 64; s > 0; s >>= 1) { if (i < s) red[i] += red[i + s]; __syncthreads(); }
  float tnorm = fmaxf(sqrtf(red[0]), 1e-12f);
  __syncthreads();
  hnv[i] = hx / hnorm; tnv[i] = tx2 / tnorm;
  __syncthreads();

  const float* R = rel_emb + (size_t)rels[b] * 16384 + (size_t)i * 128;
  float dot = 0.f, nrm = 0.f;
  for (int j = 0; j < 128; j++) { float r = R[j]; dot += r * tnv[j]; nrm += r * r; }
  float contrib = hnv[i] * dot / fmaxf(sqrtf(nrm), 1e-12f);
  red[i] = contrib; __syncthreads();
  for (int s = 64; s > 0; s >>= 1) { if (i < s) red[i] += red[i + s]; __syncthreads(); }
  if (i == 0) out[b] = red[0];
}

extern "C" void kernel_launch(void* const* d_in, const int* in_sizes, int n_in,
                              void* d_out, int out_size, void* d_ws, size_t ws_size,
                              hipStream_t stream)
{
  const float* h_x     = (const float*)d_in[0];
  const int*   h_ei    = (const int*)d_in[1];
  const int*   h_batch = (const int*)d_in[2];
  const float* t_x     = (const float*)d_in[3];
  const int*   t_ei    = (const int*)d_in[4];
  const int*   t_batch = (const int*)d_in[5];
  const int*   rels    = (const int*)d_in[6];
  const float* lin0_W  = (const float*)d_in[7];
  const float* lin0_b  = (const float*)d_in[8];
  const float* Wq      = (const float*)d_in[9];
  const float* bq      = (const float*)d_in[10];
  const float* Wk      = (const float*)d_in[11];
  const float* bk      = (const float*)d_in[12];
  const float* Wv      = (const float*)d_in[13];
  const float* bv      = (const float*)d_in[14];
  const float* Ws      = (const float*)d_in[15];
  const float* bs      = (const float*)d_in[16];
  const float* wqW     = (const float*)d_in[17];
  const float* wqb     = (const float*)d_in[18];
  const float* wkW     = (const float*)d_in[19];
  const float* wkb     = (const float*)d_in[20];
  const float* rel_emb = (const float*)d_in[21];

  const int N = in_sizes[2];          // 50000
  const int E = in_sizes[1] / 2;      // 400000
  const int G = in_sizes[6];          // 512
  const int inF = in_sizes[7] / 128;  // 70
  const int N2 = 2 * N, E2 = 2 * E;
  const int nPanels2 = (N2 + 127) / 128;
  const int nMB2 = (N2 + 63) / 64;

  char* ws = (char*)d_ws;
  size_t off = 0;
  auto alloc = [&](size_t bytes) -> void* {
    void* p = ws + off; off += (bytes + 255) & ~(size_t)255; return p;
  };
  unsigned short* hbuf = (unsigned short*)alloc((size_t)nPanels2 * 16384 * 2);
  unsigned short* sb   = (unsigned short*)alloc((size_t)N2 * 128 * 2);
  unsigned char* qb    = (unsigned char*)alloc((size_t)N2 * 512);
  unsigned char* kvbuf = (unsigned char*)alloc((size_t)N2 * 1024);
  unsigned short* BT   = (unsigned short*)alloc((size_t)3 * 212992 * 2);
  float* biascat       = (float*)alloc((size_t)3 * 1664 * 4);
  int* deg             = (int*)alloc((size_t)(N2 + 1) * 4);
  int* row_start       = (int*)alloc((size_t)(N2 + 1) * 4);
  int* cursor          = (int*)alloc((size_t)(N2 + 1) * 4);
  int* bsums           = (int*)alloc((size_t)1024 * 4);
  int* bsums_scan      = (int*)alloc((size_t)1024 * 4);
  int* csr_off         = (int*)alloc((size_t)E2 * 4);
  float* emb           = (float*)alloc((size_t)2 * G * 128 * 4);
  (void)ws_size; (void)n_in; (void)out_size;

  const int nScanBlocks = (N2 + 255) / 256;   // 391 <= 512

  // Convert weights once (shared by both graphs)
  wcvt_kernel<<<3 * 1664, 128, 0, stream>>>(Wq, bq, Wk, bk, Wv, bv, Ws, bs, BT, biascat);

  // --- merged CSR build (edges grouped by global dst; t nodes offset by N) ---
  hipMemsetAsync(deg, 0, (size_t)(N2 + 1) * 4, stream);
  hist2_kernel<<<(E2 + 255) / 256, 256, 0, stream>>>(h_ei + E, t_ei + E, deg, E, N);
  scan_block_kernel<<<nScanBlocks, 256, 0, stream>>>(deg, row_start, bsums, N2);
  scan_block512_kernel<<<1, 512, 0, stream>>>(bsums, bsums_scan, nScanBlocks);
  scan_finish_kernel<<<nScanBlocks, 256, 0, stream>>>(row_start, cursor, bsums_scan, N2, E2);
  scatter2_kernel<<<(E2 + 255) / 256, 256, 0, stream>>>(h_ei, h_ei + E, t_ei, t_ei + E,
                                                        cursor, csr_off, E, N);

  // --- merged encode ---
  lin0_kernel<<<nMB2, 256, 0, stream>>>(h_x, t_x, lin0_W, lin0_b, hbuf, N, N2, inF);
  for (int l = 0; l < 3; l++) {
    proj_mfma_kernel<<<nMB2, 256, 0, stream>>>(hbuf,
        BT + (size_t)l * 212992, biascat + (size_t)l * 1664, N2,
        qb, kvbuf, sb);
    node_attn_kernel<<<(N2 + 3) / 4, 256, 0, stream>>>(qb, kvbuf,
        row_start, csr_off, sb, hbuf, N2, (l == 2) ? 1 : 0);
  }

  hipMemsetAsync(emb, 0, (size_t)2 * G * 128 * 4, stream);
  pool_kernel<<<(N2 + 127) / 128, 128, 0, stream>>>(sb, h_batch, t_batch, emb, N, N2, G);

  score_kernel<<<G, 128, 0, stream>>>(emb, emb + (size_t)G * 128, rels,
                                      wqW, wqb, wkW, wkb, rel_emb, (float*)d_out);
}